// Round 1
// baseline (920.022 us; speedup 1.0000x reference)
//
#include <hip/hip_runtime.h>
#include <climits>

#define NPTS 50000
#define NE   800000
#define MS   25000
#define KN   15
#define HD   128

// ---------------- helpers ----------------
__device__ __forceinline__ float wave_sum(float v) {
#pragma unroll
    for (int o = 32; o > 0; o >>= 1) v += __shfl_xor(v, o, 64);
    return v;
}

// ---------------- K0: fold Wcat@Wout, pack Wq|Wk ----------------
__launch_bounds__(256)
__global__ void prep_kernel(const float* __restrict__ Wq, const float* __restrict__ bq,
                            const float* __restrict__ Wk, const float* __restrict__ bk,
                            const float* __restrict__ Wcat, const float* __restrict__ bcat,
                            const float* __restrict__ Wout, const float* __restrict__ bout,
                            float* __restrict__ Wqk, float* __restrict__ biasQK,
                            float* __restrict__ Wco128, float* __restrict__ w3, float* __restrict__ bco) {
    int tid = threadIdx.x;
    for (int i = tid; i < 128 * 128; i += 256) {
        int k = i >> 7, c = i & 127;
        Wqk[i] = (c < 64) ? Wq[k * 64 + c] : Wk[k * 64 + (c - 64)];
    }
    if (tid < 128) biasQK[tid] = (tid < 64) ? bq[tid] : bk[tid - 64];
    for (int i = tid; i < 131 * 3; i += 256) {
        int r = i / 3, j = i - r * 3;
        float s = 0.f;
        for (int t = 0; t < 131; ++t) s = fmaf(Wcat[r * 131 + t], Wout[t * 3 + j], s);
        if (r < 128) Wco128[r * 3 + j] = s; else w3[(r - 128) * 3 + j] = s;
    }
    if (tid < 3) {
        float s = 0.f;
        for (int t = 0; t < 131; ++t) s = fmaf(bcat[t], Wout[t * 3 + tid], s);
        bco[tid] = s + bout[tid];
    }
}

// ---------------- K1: y1 = points@W1 + b1, with column stats partials ----------------
__launch_bounds__(128)
__global__ void lin1_kernel(const float* __restrict__ pts, const float* __restrict__ W1,
                            const float* __restrict__ b1, float* __restrict__ y1,
                            float* __restrict__ psum, float* __restrict__ psq) {
    int c = threadIdx.x;            // 0..127
    int b = blockIdx.x;             // 0..511
    float w0 = W1[c], w1 = W1[128 + c], w2 = W1[256 + c], bb = b1[c];
    float s = 0.f, s2 = 0.f;
    int r0 = b * 98, r1 = r0 + 98; if (r1 > NPTS) r1 = NPTS;
    for (int r = r0; r < r1; ++r) {
        float p0 = pts[r * 3], p1 = pts[r * 3 + 1], p2 = pts[r * 3 + 2];
        float y = fmaf(p0, w0, fmaf(p1, w1, fmaf(p2, w2, bb)));
        y1[r * HD + c] = y;
        s += y; s2 = fmaf(y, y, s2);
    }
    psum[b * 128 + c] = s;
    psq[b * 128 + c] = s2;
}

// ---------------- BN finalize: partials -> affine (a, c) ----------------
__launch_bounds__(128)
__global__ void bn_fin_kernel(const float* __restrict__ psum, const float* __restrict__ psq, int nb,
                              const float* __restrict__ g, const float* __restrict__ beta,
                              float* __restrict__ tp) {
    int c = threadIdx.x;
    float S = 0.f, S2 = 0.f;
    for (int b = 0; b < nb; ++b) { S += psum[b * 128 + c]; S2 += psq[b * 128 + c]; }
    const float invN = 1.f / (float)NPTS;
    float mean = S * invN;
    float var = S2 * invN - mean * mean;
    float a = g[c] * rsqrtf(var + 1e-5f);
    tp[c] = a;
    tp[128 + c] = beta[c] - mean * a;
}

// ---------------- GEMM [nrows,128]@[128,128], tile 48x64, fused BN+ReLU on A ----------------
template <bool TRANS, bool STATS, bool WRX>
__launch_bounds__(256)
__global__ void gemm_bn(const float* __restrict__ A, int nrows, int rowBlocks,
                        const float* __restrict__ W, const float* __restrict__ bias,
                        const float* __restrict__ tp,
                        float* __restrict__ Out, float* __restrict__ Xout,
                        float* __restrict__ psum, float* __restrict__ psq) {
    __shared__ float As[48][128];   // 24 KB
    __shared__ float Ws[128][64];   // 32 KB
    int tid = threadIdx.x;
    int cb = blockIdx.x & 1, rb = blockIdx.x >> 1;
    int r0 = rb * 48;
    (void)rowBlocks;

    for (int i = tid; i < 48 * 128; i += 256) {
        int r = i >> 7, c = i & 127;
        int gr = r0 + r;
        float v = (gr < nrows) ? A[gr * HD + c] : 0.f;
        if (TRANS) v = fmaxf(fmaf(tp[c], v, tp[128 + c]), 0.f);
        if (WRX) { if (cb == 0 && gr < nrows) Xout[gr * HD + c] = v; }
        As[r][c] = v;
    }
    for (int i = tid; i < 128 * 64; i += 256) {
        int k = i >> 6, c = i & 63;
        Ws[k][c] = W[k * 128 + (cb << 6) + c];
    }
    __syncthreads();

    int tc = tid & 15, tr = tid >> 4;
    int tr3 = tr * 3;
    float acc[3][4] = {};
#pragma unroll 2
    for (int k = 0; k < 128; ++k) {
        const float4 wv = *reinterpret_cast<const float4*>(&Ws[k][tc << 2]);
        const float a0 = As[tr3][k], a1 = As[tr3 + 1][k], a2 = As[tr3 + 2][k];
        acc[0][0] = fmaf(a0, wv.x, acc[0][0]); acc[0][1] = fmaf(a0, wv.y, acc[0][1]);
        acc[0][2] = fmaf(a0, wv.z, acc[0][2]); acc[0][3] = fmaf(a0, wv.w, acc[0][3]);
        acc[1][0] = fmaf(a1, wv.x, acc[1][0]); acc[1][1] = fmaf(a1, wv.y, acc[1][1]);
        acc[1][2] = fmaf(a1, wv.z, acc[1][2]); acc[1][3] = fmaf(a1, wv.w, acc[1][3]);
        acc[2][0] = fmaf(a2, wv.x, acc[2][0]); acc[2][1] = fmaf(a2, wv.y, acc[2][1]);
        acc[2][2] = fmaf(a2, wv.z, acc[2][2]); acc[2][3] = fmaf(a2, wv.w, acc[2][3]);
    }

    int c0 = (cb << 6) + (tc << 2);
    float b0 = bias[c0], b1v = bias[c0 + 1], b2v = bias[c0 + 2], b3v = bias[c0 + 3];
    float cs[4] = {}, cq[4] = {};
#pragma unroll
    for (int i = 0; i < 3; ++i) {
        int gr = r0 + tr3 + i;
        float v0 = acc[i][0] + b0, v1 = acc[i][1] + b1v, v2 = acc[i][2] + b2v, v3 = acc[i][3] + b3v;
        if (gr < nrows) {
            *reinterpret_cast<float4*>(&Out[gr * HD + c0]) = make_float4(v0, v1, v2, v3);
            if (STATS) {
                cs[0] += v0; cs[1] += v1; cs[2] += v2; cs[3] += v3;
                cq[0] = fmaf(v0, v0, cq[0]); cq[1] = fmaf(v1, v1, cq[1]);
                cq[2] = fmaf(v2, v2, cq[2]); cq[3] = fmaf(v3, v3, cq[3]);
            }
        }
    }
    if (STATS) {
        float* red = &As[0][0];      // reuse 24 KB scratch
        __syncthreads();
        *reinterpret_cast<float4*>(&red[tr * 64 + (tc << 2)]) = make_float4(cs[0], cs[1], cs[2], cs[3]);
        __syncthreads();
        if (tid < 64) {
            float s = 0.f;
            for (int t = 0; t < 16; ++t) s += red[t * 64 + tid];
            psum[rb * 128 + (cb << 6) + tid] = s;
        }
        __syncthreads();
        *reinterpret_cast<float4*>(&red[tr * 64 + (tc << 2)]) = make_float4(cq[0], cq[1], cq[2], cq[3]);
        __syncthreads();
        if (tid < 64) {
            float s = 0.f;
            for (int t = 0; t < 16; ++t) s += red[t * 64 + tid];
            psq[rb * 128 + (cb << 6) + tid] = s;
        }
    }
}

// ---------------- K6a: init inv / cnt / cursor ----------------
__launch_bounds__(256)
__global__ void init_kernel(int* __restrict__ inv, int* __restrict__ cnt, int* __restrict__ cursor) {
    int i = blockIdx.x * 256 + threadIdx.x;
    if (i < NPTS) inv[i] = INT_MAX;
    if (i < MS) { cnt[i] = 0; cursor[i] = 0; }
}

// ---------------- K6b: representative map (min m per node; handles duplicates) ----------------
__launch_bounds__(256)
__global__ void invset_kernel(const int* __restrict__ smp, int* __restrict__ inv) {
    int m = blockIdx.x * 256 + threadIdx.x;
    if (m < MS) atomicMin(&inv[smp[m]], m);
}

// ---------------- K6c: count edges per sampled representative ----------------
__launch_bounds__(256)
__global__ void count_kernel(const int* __restrict__ ei, const int* __restrict__ inv,
                             int* __restrict__ cnt) {
    int e = blockIdx.x * 256 + threadIdx.x;
    if (e < NE) {
        int mr = inv[ei[NE + e]];
        if (mr < MS) atomicAdd(&cnt[mr], 1);
    }
}

// ---------------- K6d: exclusive scan over cnt[MS] -> offs ----------------
__launch_bounds__(1024)
__global__ void scan_kernel(const int* __restrict__ cnt, int* __restrict__ offs) {
    const int C = 25;               // 25*1024 = 25600 >= MS
    __shared__ int buf[1024];
    int tid = threadIdx.x;
    int loc[C];
    int run = 0;
    int base = tid * C;
#pragma unroll
    for (int i = 0; i < C; ++i) {
        int idx = base + i;
        int v = (idx < MS) ? cnt[idx] : 0;
        loc[i] = run; run += v;
    }
    buf[tid] = run;
    __syncthreads();
    for (int off = 1; off < 1024; off <<= 1) {
        int t = (tid >= off) ? buf[tid - off] : 0;
        __syncthreads();
        buf[tid] += t;
        __syncthreads();
    }
    int excl = buf[tid] - run;
#pragma unroll
    for (int i = 0; i < C; ++i) {
        int idx = base + i;
        if (idx < MS) offs[idx] = excl + loc[i];
    }
    if (tid == 1023) offs[MS] = buf[tid];
}

// ---------------- K6e: scatter src into CSR ----------------
__launch_bounds__(256)
__global__ void scatter_kernel(const int* __restrict__ ei, const int* __restrict__ inv,
                               const int* __restrict__ offs, int* __restrict__ cursor,
                               int* __restrict__ elist) {
    int e = blockIdx.x * 256 + threadIdx.x;
    if (e < NE) {
        int mr = inv[ei[NE + e]];
        if (mr < MS) {
            int pos = atomicAdd(&cursor[mr], 1);
            elist[offs[mr] + pos] = ei[e];
        }
    }
}

// ---------------- K7: per-sampled-row segment-mean + (x2@Wc+bc+agg), ReLU, sx/p3/sp ----------------
__launch_bounds__(256)
__global__ void agg_mv_kernel(const int* __restrict__ smp, const int* __restrict__ inv,
                              const int* __restrict__ offs, const int* __restrict__ elist,
                              const float* __restrict__ msg, const float* __restrict__ x2,
                              const float* __restrict__ Wc, const float* __restrict__ bc,
                              const float* __restrict__ Wco128, const float* __restrict__ pts,
                              float* __restrict__ sx, float* __restrict__ p3, float* __restrict__ sp) {
    __shared__ float xb[4][4][HD];  // 8 KB: [wave][row][k]
    int tid = threadIdx.x, wid = tid >> 6, lane = tid & 63;
    int c0 = lane << 1;
    float bc0 = bc[c0], bc1 = bc[c0 + 1];
    float wa0 = Wco128[c0 * 3], wa1 = Wco128[c0 * 3 + 1], wa2 = Wco128[c0 * 3 + 2];
    float wb0 = Wco128[(c0 + 1) * 3], wb1 = Wco128[(c0 + 1) * 3 + 1], wb2 = Wco128[(c0 + 1) * 3 + 2];

    for (int it = 0; it < 2; ++it) {                 // 1024 blocks * 16 rows = 16384/iter
        int m0 = it * 16384 + blockIdx.x * 16 + wid * 4;
        float ag0[4], ag1[4];
        int dd[4];
#pragma unroll
        for (int r = 0; r < 4; ++r) {
            int m = m0 + r;
            if (m < MS) {
                int d = smp[m]; dd[r] = d;
                int mr = inv[d];
                int e0 = offs[mr], e1 = offs[mr + 1];
                float s0 = 0.f, s1 = 0.f, t0 = 0.f, t1 = 0.f;
                int e = e0;
                for (; e + 1 < e1; e += 2) {         // 2 loads in flight
                    int sA = elist[e], sB = elist[e + 1];
                    const float2 vA = *reinterpret_cast<const float2*>(&msg[sA * HD + c0]);
                    const float2 vB = *reinterpret_cast<const float2*>(&msg[sB * HD + c0]);
                    s0 += vA.x; s1 += vA.y; t0 += vB.x; t1 += vB.y;
                }
                if (e < e1) {
                    const float2 v = *reinterpret_cast<const float2*>(&msg[elist[e] * HD + c0]);
                    s0 += v.x; s1 += v.y;
                }
                s0 += t0; s1 += t1;
                float rs = 1.f / fmaxf((float)(e1 - e0), 1.f);
                ag0[r] = s0 * rs; ag1[r] = s1 * rs;
                const float2 xv = *reinterpret_cast<const float2*>(&x2[d * HD + c0]);
                xb[wid][r][c0] = xv.x; xb[wid][r][c0 + 1] = xv.y;
            } else {
                dd[r] = 0; ag0[r] = 0.f; ag1[r] = 0.f;
                xb[wid][r][c0] = 0.f; xb[wid][r][c0 + 1] = 0.f;
            }
        }
        // wave-local LDS use; CDNA wave is lockstep, compiler orders ds_write->ds_read
        float o0[4] = {0.f, 0.f, 0.f, 0.f}, o1[4] = {0.f, 0.f, 0.f, 0.f};
#pragma unroll 4
        for (int k = 0; k < HD; ++k) {
            const float2 wv = *reinterpret_cast<const float2*>(&Wc[k * HD + c0]);
#pragma unroll
            for (int r = 0; r < 4; ++r) {
                float xk = xb[wid][r][k];
                o0[r] = fmaf(xk, wv.x, o0[r]);
                o1[r] = fmaf(xk, wv.y, o1[r]);
            }
        }
#pragma unroll
        for (int r = 0; r < 4; ++r) {
            int m = m0 + r;
            if (m < MS) {
                float v0 = fmaxf(o0[r] + bc0 + ag0[r], 0.f);
                float v1 = fmaxf(o1[r] + bc1 + ag1[r], 0.f);
                *reinterpret_cast<float2*>(&sx[m * HD + c0]) = make_float2(v0, v1);
                float q0 = fmaf(v0, wa0, v1 * wb0);
                float q1 = fmaf(v0, wa1, v1 * wb1);
                float q2 = fmaf(v0, wa2, v1 * wb2);
                q0 = wave_sum(q0); q1 = wave_sum(q1); q2 = wave_sum(q2);
                if (lane == 0) { p3[m * 3] = q0; p3[m * 3 + 1] = q1; p3[m * 3 + 2] = q2; }
                if (lane < 3) sp[m * 3 + lane] = pts[dd[r] * 3 + lane];
            }
        }
    }
}

// ---------------- K9: attention + folded output tail ----------------
__launch_bounds__(256)
__global__ void attn_kernel(const float* __restrict__ qk, const int* __restrict__ nbr,
                            const float* __restrict__ p3, const float* __restrict__ sp,
                            const float* __restrict__ w3, const float* __restrict__ bco,
                            float* __restrict__ refined) {
    int wid = threadIdx.x >> 6, lane = threadIdx.x & 63;
    int m = blockIdx.x * 4 + wid;
    if (m >= MS) return;
    float ql = qk[m * HD + lane];
    int nbv[KN];
    float s[KN];
#pragma unroll
    for (int j = 0; j < KN; ++j) nbv[j] = nbr[m * KN + j];
#pragma unroll
    for (int j = 0; j < KN; ++j) {
        float t = ql * qk[nbv[j] * HD + 64 + lane];
        t = wave_sum(t);
        s[j] = (nbv[j] != 0) ? t * (1.f / 8.000001f) : 0.f;
    }
    float mx = s[0];
#pragma unroll
    for (int j = 1; j < KN; ++j) mx = fmaxf(mx, s[j]);
    float den = 0.f;
#pragma unroll
    for (int j = 0; j < KN; ++j) { s[j] = __expf(s[j] - mx); den += s[j]; }
    float invd = 1.f / den;
    float sp0 = sp[m * 3], sp1 = sp[m * 3 + 1], sp2 = sp[m * 3 + 2];
    float a0 = 0.f, a1 = 0.f, a2 = 0.f;
#pragma unroll
    for (int j = 0; j < KN; ++j) {
        int nb = nbv[j];
        float wgt = s[j] * invd;
        float r0 = sp[nb * 3] - sp0, r1 = sp[nb * 3 + 1] - sp1, r2 = sp[nb * 3 + 2] - sp2;
        float g0 = p3[nb * 3]     + r0 * w3[0] + r1 * w3[3] + r2 * w3[6];
        float g1 = p3[nb * 3 + 1] + r0 * w3[1] + r1 * w3[4] + r2 * w3[7];
        float g2 = p3[nb * 3 + 2] + r0 * w3[2] + r1 * w3[5] + r2 * w3[8];
        a0 = fmaf(wgt, g0, a0); a1 = fmaf(wgt, g1, a1); a2 = fmaf(wgt, g2, a2);
    }
    if (lane == 0) {
        refined[m * 3]     = sp0 + a0 + bco[0];
        refined[m * 3 + 1] = sp1 + a1 + bco[1];
        refined[m * 3 + 2] = sp2 + a2 + bco[2];
    }
}

// ---------------- launch ----------------
extern "C" void kernel_launch(void* const* d_in, const int* in_sizes, int n_in,
                              void* d_out, int out_size, void* d_ws, size_t ws_size,
                              hipStream_t stream) {
    const float* pts   = (const float*)d_in[0];
    const int*   ei    = (const int*)d_in[1];
    const int*   smp   = (const int*)d_in[2];
    const int*   nbr   = (const int*)d_in[3];
    const float* W1    = (const float*)d_in[4];
    const float* b1    = (const float*)d_in[5];
    const float* g1    = (const float*)d_in[6];
    const float* beta1 = (const float*)d_in[7];
    const float* W2    = (const float*)d_in[8];
    const float* b2    = (const float*)d_in[9];
    const float* g2    = (const float*)d_in[10];
    const float* beta2 = (const float*)d_in[11];
    const float* Wc    = (const float*)d_in[12];
    const float* bc    = (const float*)d_in[13];
    const float* Wn    = (const float*)d_in[14];
    const float* bn_b  = (const float*)d_in[15];
    const float* Wq    = (const float*)d_in[16];
    const float* bq    = (const float*)d_in[17];
    const float* Wk    = (const float*)d_in[18];
    const float* bk    = (const float*)d_in[19];
    const float* Wcat  = (const float*)d_in[20];
    const float* bcat  = (const float*)d_in[21];
    const float* Wout  = (const float*)d_in[22];
    const float* bout  = (const float*)d_in[23];
    (void)in_sizes; (void)n_in; (void)out_size; (void)ws_size;

    float* w = (float*)d_ws;
    size_t o = 0;
    float* y1     = w + o;              // also reused as x2
    float* x2     = y1;
    o += 6400000;
    float* y2     = w + o; o += 6400000;
    float* msgb   = w + o; o += 6400000;
    float* qkb    = w + o; o += 3200000;
    float* psum   = w + o; o += 133376;
    float* psq    = w + o; o += 133376;
    float* tp1    = w + o; o += 256;
    float* tp2    = w + o; o += 256;
    float* Wqk    = w + o; o += 16384;
    float* biasQK = w + o; o += 128;
    float* Wco128 = w + o; o += 384;
    float* w3     = w + o; o += 16;
    float* bco    = w + o; o += 16;
    float* p3     = w + o; o += 75008;
    float* sp     = w + o; o += 75008;
    int* ip    = (int*)(w + o);
    int* inv   = ip;            ip += NPTS;
    int* cnt   = ip;            ip += MS;
    int* cursor= ip;            ip += MS;
    int* offs  = ip;            ip += MS + 4;
    int* elist = ip;

    float* refined = (float*)d_out;
    float* sx      = (float*)d_out + 75000;

    prep_kernel<<<1, 256, 0, stream>>>(Wq, bq, Wk, bk, Wcat, bcat, Wout, bout,
                                       Wqk, biasQK, Wco128, w3, bco);
    lin1_kernel<<<512, 128, 0, stream>>>(pts, W1, b1, y1, psum, psq);
    bn_fin_kernel<<<1, 128, 0, stream>>>(psum, psq, 512, g1, beta1, tp1);
    gemm_bn<true, true, false><<<2084, 256, 0, stream>>>(y1, NPTS, 1042, W2, b2, tp1,
                                                         y2, nullptr, psum, psq);
    bn_fin_kernel<<<1, 128, 0, stream>>>(psum, psq, 1042, g2, beta2, tp2);
    gemm_bn<true, false, true><<<2084, 256, 0, stream>>>(y2, NPTS, 1042, Wn, bn_b, tp2,
                                                         msgb, x2, nullptr, nullptr);
    init_kernel<<<196, 256, 0, stream>>>(inv, cnt, cursor);
    invset_kernel<<<98, 256, 0, stream>>>(smp, inv);
    count_kernel<<<3125, 256, 0, stream>>>(ei, inv, cnt);
    scan_kernel<<<1, 1024, 0, stream>>>(cnt, offs);
    scatter_kernel<<<3125, 256, 0, stream>>>(ei, inv, offs, cursor, elist);
    agg_mv_kernel<<<1024, 256, 0, stream>>>(smp, inv, offs, elist, msgb, x2, Wc, bc,
                                            Wco128, pts, sx, p3, sp);
    gemm_bn<false, false, false><<<1042, 256, 0, stream>>>(sx, MS, 521, Wqk, biasQK, nullptr,
                                                           qkb, nullptr, nullptr, nullptr);
    attn_kernel<<<6250, 256, 0, stream>>>(qkb, nbr, p3, sp, w3, bco, refined);
}

// Round 2
// 536.153 us; speedup vs baseline: 1.7160x; 1.7160x over previous
//
#include <hip/hip_runtime.h>
#include <climits>

#define NPTS 50000
#define NE   800000
#define MS   25000
#define KN   15
#define HD   128

// ---------------- helpers ----------------
__device__ __forceinline__ float wave_sum(float v) {
#pragma unroll
    for (int o = 32; o > 0; o >>= 1) v += __shfl_xor(v, o, 64);
    return v;
}

// ---------------- K0: fold Wcat@Wout, pack Wq|Wk ----------------
__launch_bounds__(256)
__global__ void prep_kernel(const float* __restrict__ Wq, const float* __restrict__ bq,
                            const float* __restrict__ Wk, const float* __restrict__ bk,
                            const float* __restrict__ Wcat, const float* __restrict__ bcat,
                            const float* __restrict__ Wout, const float* __restrict__ bout,
                            float* __restrict__ Wqk, float* __restrict__ biasQK,
                            float* __restrict__ Wco128, float* __restrict__ w3, float* __restrict__ bco) {
    int tid = threadIdx.x;
    for (int i = tid; i < 128 * 128; i += 256) {
        int k = i >> 7, c = i & 127;
        Wqk[i] = (c < 64) ? Wq[k * 64 + c] : Wk[k * 64 + (c - 64)];
    }
    if (tid < 128) biasQK[tid] = (tid < 64) ? bq[tid] : bk[tid - 64];
    for (int i = tid; i < 131 * 3; i += 256) {
        int r = i / 3, j = i - r * 3;
        float s = 0.f;
        for (int t = 0; t < 131; ++t) s = fmaf(Wcat[r * 131 + t], Wout[t * 3 + j], s);
        if (r < 128) Wco128[r * 3 + j] = s; else w3[(r - 128) * 3 + j] = s;
    }
    if (tid < 3) {
        float s = 0.f;
        for (int t = 0; t < 131; ++t) s = fmaf(bcat[t], Wout[t * 3 + tid], s);
        bco[tid] = s + bout[tid];
    }
}

// ---------------- K1: y1 = points@W1 + b1, with column stats partials ----------------
__launch_bounds__(128)
__global__ void lin1_kernel(const float* __restrict__ pts, const float* __restrict__ W1,
                            const float* __restrict__ b1, float* __restrict__ y1,
                            float* __restrict__ psum, float* __restrict__ psq) {
    int c = threadIdx.x;            // 0..127
    int b = blockIdx.x;             // 0..511
    float w0 = W1[c], w1 = W1[128 + c], w2 = W1[256 + c], bb = b1[c];
    float s = 0.f, s2 = 0.f;
    int r0 = b * 98, r1 = r0 + 98; if (r1 > NPTS) r1 = NPTS;
    for (int r = r0; r < r1; ++r) {
        float p0 = pts[r * 3], p1 = pts[r * 3 + 1], p2 = pts[r * 3 + 2];
        float y = fmaf(p0, w0, fmaf(p1, w1, fmaf(p2, w2, bb)));
        y1[r * HD + c] = y;
        s += y; s2 = fmaf(y, y, s2);
    }
    psum[b * 128 + c] = s;
    psq[b * 128 + c] = s2;
}

// ---------------- BN finalize (PARALLEL): one block per column ----------------
__launch_bounds__(256)
__global__ void bn_fin_par(const float* __restrict__ psum, const float* __restrict__ psq, int nb,
                           const float* __restrict__ g, const float* __restrict__ beta,
                           float* __restrict__ tp) {
    int c = blockIdx.x;             // 0..127
    int t = threadIdx.x;
    float S = 0.f, S2 = 0.f;
    for (int b = t; b < nb; b += 256) {
        S += psum[b * 128 + c];
        S2 += psq[b * 128 + c];
    }
    S = wave_sum(S); S2 = wave_sum(S2);
    __shared__ float sA[4], sB[4];
    int wid = t >> 6, lane = t & 63;
    if (lane == 0) { sA[wid] = S; sB[wid] = S2; }
    __syncthreads();
    if (t == 0) {
        float Sa = sA[0] + sA[1] + sA[2] + sA[3];
        float Sb = sB[0] + sB[1] + sB[2] + sB[3];
        const float invN = 1.f / (float)NPTS;
        float mean = Sa * invN;
        float var = Sb * invN - mean * mean;
        float a = g[c] * rsqrtf(var + 1e-5f);
        tp[c] = a;
        tp[128 + c] = beta[c] - mean * a;
    }
}

// ---------------- GEMM [nrows,128]@[128,128], tile 48x64, fused BN+ReLU on A ----------------
template <bool TRANS, bool STATS, bool WRX>
__launch_bounds__(256)
__global__ void gemm_bn(const float* __restrict__ A, int nrows, int rowBlocks,
                        const float* __restrict__ W, const float* __restrict__ bias,
                        const float* __restrict__ tp,
                        float* __restrict__ Out, float* __restrict__ Xout,
                        float* __restrict__ psum, float* __restrict__ psq) {
    __shared__ float As[48][128];   // 24 KB
    __shared__ float Ws[128][64];   // 32 KB
    int tid = threadIdx.x;
    int cb = blockIdx.x & 1, rb = blockIdx.x >> 1;
    int r0 = rb * 48;
    (void)rowBlocks;

    for (int i = tid; i < 48 * 128; i += 256) {
        int r = i >> 7, c = i & 127;
        int gr = r0 + r;
        float v = (gr < nrows) ? A[gr * HD + c] : 0.f;
        if (TRANS) v = fmaxf(fmaf(tp[c], v, tp[128 + c]), 0.f);
        if (WRX) { if (cb == 0 && gr < nrows) Xout[gr * HD + c] = v; }
        As[r][c] = v;
    }
    for (int i = tid; i < 128 * 64; i += 256) {
        int k = i >> 6, c = i & 63;
        Ws[k][c] = W[k * 128 + (cb << 6) + c];
    }
    __syncthreads();

    int tc = tid & 15, tr = tid >> 4;
    int tr3 = tr * 3;
    float acc[3][4] = {};
#pragma unroll 2
    for (int k = 0; k < 128; ++k) {
        const float4 wv = *reinterpret_cast<const float4*>(&Ws[k][tc << 2]);
        const float a0 = As[tr3][k], a1 = As[tr3 + 1][k], a2 = As[tr3 + 2][k];
        acc[0][0] = fmaf(a0, wv.x, acc[0][0]); acc[0][1] = fmaf(a0, wv.y, acc[0][1]);
        acc[0][2] = fmaf(a0, wv.z, acc[0][2]); acc[0][3] = fmaf(a0, wv.w, acc[0][3]);
        acc[1][0] = fmaf(a1, wv.x, acc[1][0]); acc[1][1] = fmaf(a1, wv.y, acc[1][1]);
        acc[1][2] = fmaf(a1, wv.z, acc[1][2]); acc[1][3] = fmaf(a1, wv.w, acc[1][3]);
        acc[2][0] = fmaf(a2, wv.x, acc[2][0]); acc[2][1] = fmaf(a2, wv.y, acc[2][1]);
        acc[2][2] = fmaf(a2, wv.z, acc[2][2]); acc[2][3] = fmaf(a2, wv.w, acc[2][3]);
    }

    int c0 = (cb << 6) + (tc << 2);
    float b0 = bias[c0], b1v = bias[c0 + 1], b2v = bias[c0 + 2], b3v = bias[c0 + 3];
    float cs[4] = {}, cq[4] = {};
#pragma unroll
    for (int i = 0; i < 3; ++i) {
        int gr = r0 + tr3 + i;
        float v0 = acc[i][0] + b0, v1 = acc[i][1] + b1v, v2 = acc[i][2] + b2v, v3 = acc[i][3] + b3v;
        if (gr < nrows) {
            *reinterpret_cast<float4*>(&Out[gr * HD + c0]) = make_float4(v0, v1, v2, v3);
            if (STATS) {
                cs[0] += v0; cs[1] += v1; cs[2] += v2; cs[3] += v3;
                cq[0] = fmaf(v0, v0, cq[0]); cq[1] = fmaf(v1, v1, cq[1]);
                cq[2] = fmaf(v2, v2, cq[2]); cq[3] = fmaf(v3, v3, cq[3]);
            }
        }
    }
    if (STATS) {
        float* red = &As[0][0];      // reuse 24 KB scratch
        __syncthreads();
        *reinterpret_cast<float4*>(&red[tr * 64 + (tc << 2)]) = make_float4(cs[0], cs[1], cs[2], cs[3]);
        __syncthreads();
        if (tid < 64) {
            float s = 0.f;
            for (int t = 0; t < 16; ++t) s += red[t * 64 + tid];
            psum[rb * 128 + (cb << 6) + tid] = s;
        }
        __syncthreads();
        *reinterpret_cast<float4*>(&red[tr * 64 + (tc << 2)]) = make_float4(cq[0], cq[1], cq[2], cq[3]);
        __syncthreads();
        if (tid < 64) {
            float s = 0.f;
            for (int t = 0; t < 16; ++t) s += red[t * 64 + tid];
            psq[rb * 128 + (cb << 6) + tid] = s;
        }
    }
}

// ---------------- K6a: init inv / cnt / cursor ----------------
__launch_bounds__(256)
__global__ void init_kernel(int* __restrict__ inv, int* __restrict__ cnt, int* __restrict__ cursor) {
    int i = blockIdx.x * 256 + threadIdx.x;
    if (i < NPTS) inv[i] = INT_MAX;
    if (i < MS) { cnt[i] = 0; cursor[i] = 0; }
}

// ---------------- K6b: representative map (min m per node; handles duplicates) ----------------
__launch_bounds__(256)
__global__ void invset_kernel(const int* __restrict__ smp, int* __restrict__ inv) {
    int m = blockIdx.x * 256 + threadIdx.x;
    if (m < MS) atomicMin(&inv[smp[m]], m);
}

// ---------------- K6c: count edges per sampled representative ----------------
__launch_bounds__(256)
__global__ void count_kernel(const int* __restrict__ ei, const int* __restrict__ inv,
                             int* __restrict__ cnt) {
    int e = blockIdx.x * 256 + threadIdx.x;
    if (e < NE) {
        int mr = inv[ei[NE + e]];
        if (mr < MS) atomicAdd(&cnt[mr], 1);
    }
}

// ---------------- K6d: exclusive scan over cnt[MS] -> offs ----------------
__launch_bounds__(1024)
__global__ void scan_kernel(const int* __restrict__ cnt, int* __restrict__ offs) {
    const int C = 25;               // 25*1024 = 25600 >= MS
    __shared__ int buf[1024];
    int tid = threadIdx.x;
    int loc[C];
    int run = 0;
    int base = tid * C;
#pragma unroll
    for (int i = 0; i < C; ++i) {
        int idx = base + i;
        int v = (idx < MS) ? cnt[idx] : 0;
        loc[i] = run; run += v;
    }
    buf[tid] = run;
    __syncthreads();
    for (int off = 1; off < 1024; off <<= 1) {
        int t = (tid >= off) ? buf[tid - off] : 0;
        __syncthreads();
        buf[tid] += t;
        __syncthreads();
    }
    int excl = buf[tid] - run;
#pragma unroll
    for (int i = 0; i < C; ++i) {
        int idx = base + i;
        if (idx < MS) offs[idx] = excl + loc[i];
    }
    if (tid == 1023) offs[MS] = buf[tid];
}

// ---------------- K6e: scatter src into CSR ----------------
__launch_bounds__(256)
__global__ void scatter_kernel(const int* __restrict__ ei, const int* __restrict__ inv,
                               const int* __restrict__ offs, int* __restrict__ cursor,
                               int* __restrict__ elist) {
    int e = blockIdx.x * 256 + threadIdx.x;
    if (e < NE) {
        int mr = inv[ei[NE + e]];
        if (mr < MS) {
            int pos = atomicAdd(&cursor[mr], 1);
            elist[offs[mr] + pos] = ei[e];
        }
    }
}

// ---------------- K7: per-sampled-row segment-mean + (x2@Wc+bc+agg), ReLU, sx/p3/sp ----------------
__launch_bounds__(256)
__global__ void agg_mv_kernel(const int* __restrict__ smp, const int* __restrict__ inv,
                              const int* __restrict__ offs, const int* __restrict__ elist,
                              const float* __restrict__ msg, const float* __restrict__ x2,
                              const float* __restrict__ Wc, const float* __restrict__ bc,
                              const float* __restrict__ Wco128, const float* __restrict__ pts,
                              float* __restrict__ sx, float* __restrict__ p3, float* __restrict__ sp) {
    __shared__ float xb[4][4][HD];  // 8 KB: [wave][row][k]
    int tid = threadIdx.x, wid = tid >> 6, lane = tid & 63;
    int c0 = lane << 1;
    float bc0 = bc[c0], bc1 = bc[c0 + 1];
    float wa0 = Wco128[c0 * 3], wa1 = Wco128[c0 * 3 + 1], wa2 = Wco128[c0 * 3 + 2];
    float wb0 = Wco128[(c0 + 1) * 3], wb1 = Wco128[(c0 + 1) * 3 + 1], wb2 = Wco128[(c0 + 1) * 3 + 2];

    for (int it = 0; it < 2; ++it) {                 // 1024 blocks * 16 rows = 16384/iter
        int m0 = it * 16384 + blockIdx.x * 16 + wid * 4;
        float ag0[4], ag1[4];
        int dd[4];
#pragma unroll
        for (int r = 0; r < 4; ++r) {
            int m = m0 + r;
            if (m < MS) {
                int d = smp[m]; dd[r] = d;
                int mr = inv[d];
                int e0 = offs[mr], e1 = offs[mr + 1];
                float s0 = 0.f, s1 = 0.f, t0 = 0.f, t1 = 0.f;
                int e = e0;
                for (; e + 1 < e1; e += 2) {         // 2 loads in flight
                    int sA = elist[e], sB = elist[e + 1];
                    const float2 vA = *reinterpret_cast<const float2*>(&msg[sA * HD + c0]);
                    const float2 vB = *reinterpret_cast<const float2*>(&msg[sB * HD + c0]);
                    s0 += vA.x; s1 += vA.y; t0 += vB.x; t1 += vB.y;
                }
                if (e < e1) {
                    const float2 v = *reinterpret_cast<const float2*>(&msg[elist[e] * HD + c0]);
                    s0 += v.x; s1 += v.y;
                }
                s0 += t0; s1 += t1;
                float rs = 1.f / fmaxf((float)(e1 - e0), 1.f);
                ag0[r] = s0 * rs; ag1[r] = s1 * rs;
                const float2 xv = *reinterpret_cast<const float2*>(&x2[d * HD + c0]);
                xb[wid][r][c0] = xv.x; xb[wid][r][c0 + 1] = xv.y;
            } else {
                dd[r] = 0; ag0[r] = 0.f; ag1[r] = 0.f;
                xb[wid][r][c0] = 0.f; xb[wid][r][c0 + 1] = 0.f;
            }
        }
        // wave-local LDS use; CDNA wave is lockstep, compiler orders ds_write->ds_read
        float o0[4] = {0.f, 0.f, 0.f, 0.f}, o1[4] = {0.f, 0.f, 0.f, 0.f};
#pragma unroll 4
        for (int k = 0; k < HD; ++k) {
            const float2 wv = *reinterpret_cast<const float2*>(&Wc[k * HD + c0]);
#pragma unroll
            for (int r = 0; r < 4; ++r) {
                float xk = xb[wid][r][k];
                o0[r] = fmaf(xk, wv.x, o0[r]);
                o1[r] = fmaf(xk, wv.y, o1[r]);
            }
        }
#pragma unroll
        for (int r = 0; r < 4; ++r) {
            int m = m0 + r;
            if (m < MS) {
                float v0 = fmaxf(o0[r] + bc0 + ag0[r], 0.f);
                float v1 = fmaxf(o1[r] + bc1 + ag1[r], 0.f);
                *reinterpret_cast<float2*>(&sx[m * HD + c0]) = make_float2(v0, v1);
                float q0 = fmaf(v0, wa0, v1 * wb0);
                float q1 = fmaf(v0, wa1, v1 * wb1);
                float q2 = fmaf(v0, wa2, v1 * wb2);
                q0 = wave_sum(q0); q1 = wave_sum(q1); q2 = wave_sum(q2);
                if (lane == 0) { p3[m * 3] = q0; p3[m * 3 + 1] = q1; p3[m * 3 + 2] = q2; }
                if (lane < 3) sp[m * 3 + lane] = pts[dd[r] * 3 + lane];
            }
        }
    }
}

// ---------------- K9: attention + folded output tail ----------------
__launch_bounds__(256)
__global__ void attn_kernel(const float* __restrict__ qk, const int* __restrict__ nbr,
                            const float* __restrict__ p3, const float* __restrict__ sp,
                            const float* __restrict__ w3, const float* __restrict__ bco,
                            float* __restrict__ refined) {
    int wid = threadIdx.x >> 6, lane = threadIdx.x & 63;
    int m = blockIdx.x * 4 + wid;
    if (m >= MS) return;
    float ql = qk[m * HD + lane];
    int nbv[KN];
    float s[KN];
#pragma unroll
    for (int j = 0; j < KN; ++j) nbv[j] = nbr[m * KN + j];
#pragma unroll
    for (int j = 0; j < KN; ++j) {
        float t = ql * qk[nbv[j] * HD + 64 + lane];
        t = wave_sum(t);
        s[j] = (nbv[j] != 0) ? t * (1.f / 8.000001f) : 0.f;
    }
    float mx = s[0];
#pragma unroll
    for (int j = 1; j < KN; ++j) mx = fmaxf(mx, s[j]);
    float den = 0.f;
#pragma unroll
    for (int j = 0; j < KN; ++j) { s[j] = __expf(s[j] - mx); den += s[j]; }
    float invd = 1.f / den;
    float sp0 = sp[m * 3], sp1 = sp[m * 3 + 1], sp2 = sp[m * 3 + 2];
    float a0 = 0.f, a1 = 0.f, a2 = 0.f;
#pragma unroll
    for (int j = 0; j < KN; ++j) {
        int nb = nbv[j];
        float wgt = s[j] * invd;
        float r0 = sp[nb * 3] - sp0, r1 = sp[nb * 3 + 1] - sp1, r2 = sp[nb * 3 + 2] - sp2;
        float g0 = p3[nb * 3]     + r0 * w3[0] + r1 * w3[3] + r2 * w3[6];
        float g1 = p3[nb * 3 + 1] + r0 * w3[1] + r1 * w3[4] + r2 * w3[7];
        float g2 = p3[nb * 3 + 2] + r0 * w3[2] + r1 * w3[5] + r2 * w3[8];
        a0 = fmaf(wgt, g0, a0); a1 = fmaf(wgt, g1, a1); a2 = fmaf(wgt, g2, a2);
    }
    if (lane == 0) {
        refined[m * 3]     = sp0 + a0 + bco[0];
        refined[m * 3 + 1] = sp1 + a1 + bco[1];
        refined[m * 3 + 2] = sp2 + a2 + bco[2];
    }
}

// ---------------- launch ----------------
extern "C" void kernel_launch(void* const* d_in, const int* in_sizes, int n_in,
                              void* d_out, int out_size, void* d_ws, size_t ws_size,
                              hipStream_t stream) {
    const float* pts   = (const float*)d_in[0];
    const int*   ei    = (const int*)d_in[1];
    const int*   smp   = (const int*)d_in[2];
    const int*   nbr   = (const int*)d_in[3];
    const float* W1    = (const float*)d_in[4];
    const float* b1    = (const float*)d_in[5];
    const float* g1    = (const float*)d_in[6];
    const float* beta1 = (const float*)d_in[7];
    const float* W2    = (const float*)d_in[8];
    const float* b2    = (const float*)d_in[9];
    const float* g2    = (const float*)d_in[10];
    const float* beta2 = (const float*)d_in[11];
    const float* Wc    = (const float*)d_in[12];
    const float* bc    = (const float*)d_in[13];
    const float* Wn    = (const float*)d_in[14];
    const float* bn_b  = (const float*)d_in[15];
    const float* Wq    = (const float*)d_in[16];
    const float* bq    = (const float*)d_in[17];
    const float* Wk    = (const float*)d_in[18];
    const float* bk    = (const float*)d_in[19];
    const float* Wcat  = (const float*)d_in[20];
    const float* bcat  = (const float*)d_in[21];
    const float* Wout  = (const float*)d_in[22];
    const float* bout  = (const float*)d_in[23];
    (void)in_sizes; (void)n_in; (void)out_size; (void)ws_size;

    float* w = (float*)d_ws;
    size_t o = 0;
    float* y1     = w + o;              // also reused as x2
    float* x2     = y1;
    o += 6400000;
    float* y2     = w + o; o += 6400000;
    float* msgb   = w + o; o += 6400000;
    float* qkb    = w + o; o += 3200000;
    float* psum   = w + o; o += 133376;
    float* psq    = w + o; o += 133376;
    float* tp1    = w + o; o += 256;
    float* tp2    = w + o; o += 256;
    float* Wqk    = w + o; o += 16384;
    float* biasQK = w + o; o += 128;
    float* Wco128 = w + o; o += 384;
    float* w3     = w + o; o += 16;
    float* bco    = w + o; o += 16;
    float* p3     = w + o; o += 75008;
    float* sp     = w + o; o += 75008;
    int* ip    = (int*)(w + o);
    int* inv   = ip;            ip += NPTS;
    int* cnt   = ip;            ip += MS;
    int* cursor= ip;            ip += MS;
    int* offs  = ip;            ip += MS + 4;
    int* elist = ip;

    float* refined = (float*)d_out;
    float* sx      = (float*)d_out + 75000;

    prep_kernel<<<1, 256, 0, stream>>>(Wq, bq, Wk, bk, Wcat, bcat, Wout, bout,
                                       Wqk, biasQK, Wco128, w3, bco);
    lin1_kernel<<<512, 128, 0, stream>>>(pts, W1, b1, y1, psum, psq);
    bn_fin_par<<<128, 256, 0, stream>>>(psum, psq, 512, g1, beta1, tp1);
    gemm_bn<true, true, false><<<2084, 256, 0, stream>>>(y1, NPTS, 1042, W2, b2, tp1,
                                                         y2, nullptr, psum, psq);
    bn_fin_par<<<128, 256, 0, stream>>>(psum, psq, 1042, g2, beta2, tp2);
    gemm_bn<true, false, true><<<2084, 256, 0, stream>>>(y2, NPTS, 1042, Wn, bn_b, tp2,
                                                         msgb, x2, nullptr, nullptr);
    init_kernel<<<196, 256, 0, stream>>>(inv, cnt, cursor);
    invset_kernel<<<98, 256, 0, stream>>>(smp, inv);
    count_kernel<<<3125, 256, 0, stream>>>(ei, inv, cnt);
    scan_kernel<<<1, 1024, 0, stream>>>(cnt, offs);
    scatter_kernel<<<3125, 256, 0, stream>>>(ei, inv, offs, cursor, elist);
    agg_mv_kernel<<<1024, 256, 0, stream>>>(smp, inv, offs, elist, msgb, x2, Wc, bc,
                                            Wco128, pts, sx, p3, sp);
    gemm_bn<false, false, false><<<1042, 256, 0, stream>>>(sx, MS, 521, Wqk, biasQK, nullptr,
                                                           qkb, nullptr, nullptr, nullptr);
    attn_kernel<<<6250, 256, 0, stream>>>(qkb, nbr, p3, sp, w3, bco, refined);
}

// Round 3
// 516.666 us; speedup vs baseline: 1.7807x; 1.0377x over previous
//
#include <hip/hip_runtime.h>
#include <climits>

#define NPTS 50000
#define NE   800000
#define MS   25000
#define KN   15
#define HD   128

// ---------------- helpers ----------------
__device__ __forceinline__ float wave_sum(float v) {
#pragma unroll
    for (int o = 32; o > 0; o >>= 1) v += __shfl_xor(v, o, 64);
    return v;
}

// ---------------- K0: fold Wcat@Wout, pack Wq|Wk, pack [Wc;Wn] ----------------
__launch_bounds__(256)
__global__ void prep_kernel(const float* __restrict__ Wq, const float* __restrict__ bq,
                            const float* __restrict__ Wk, const float* __restrict__ bk,
                            const float* __restrict__ Wcat, const float* __restrict__ bcat,
                            const float* __restrict__ Wout, const float* __restrict__ bout,
                            const float* __restrict__ Wc, const float* __restrict__ Wn,
                            float* __restrict__ Wqk, float* __restrict__ biasQK,
                            float* __restrict__ WcWn,
                            float* __restrict__ Wco128, float* __restrict__ w3, float* __restrict__ bco) {
    int tid = threadIdx.x;
    for (int i = tid; i < 128 * 128; i += 256) {
        int k = i >> 7, c = i & 127;
        Wqk[i] = (c < 64) ? Wq[k * 64 + c] : Wk[k * 64 + (c - 64)];
    }
    for (int i = tid; i < 256 * 128; i += 256) {
        int k = i >> 7, c = i & 127;
        WcWn[i] = (k < 128) ? Wc[k * 128 + c] : Wn[(k - 128) * 128 + c];
    }
    if (tid < 128) biasQK[tid] = (tid < 64) ? bq[tid] : bk[tid - 64];
    for (int i = tid; i < 131 * 3; i += 256) {
        int r = i / 3, j = i - r * 3;
        float s = 0.f;
        for (int t = 0; t < 131; ++t) s = fmaf(Wcat[r * 131 + t], Wout[t * 3 + j], s);
        if (r < 128) Wco128[r * 3 + j] = s; else w3[(r - 128) * 3 + j] = s;
    }
    if (tid < 3) {
        float s = 0.f;
        for (int t = 0; t < 131; ++t) s = fmaf(bcat[t], Wout[t * 3 + tid], s);
        bco[tid] = s + bout[tid];
    }
}

// ---------------- K1: y1 = points@W1 + b1, with column stats partials ----------------
__launch_bounds__(256)
__global__ void lin1_kernel(const float* __restrict__ pts, const float* __restrict__ W1,
                            const float* __restrict__ b1, float* __restrict__ y1,
                            float* __restrict__ psum, float* __restrict__ psq) {
    int c = threadIdx.x & 127;
    int half = threadIdx.x >> 7;
    int part = blockIdx.x * 2 + half;   // 0..1999
    float w0 = W1[c], w1 = W1[128 + c], w2 = W1[256 + c], bb = b1[c];
    float s = 0.f, s2 = 0.f;
    int r0 = part * 25, r1 = r0 + 25; if (r1 > NPTS) r1 = NPTS;
    for (int r = r0; r < r1; ++r) {
        float p0 = pts[r * 3], p1 = pts[r * 3 + 1], p2 = pts[r * 3 + 2];
        float y = fmaf(p0, w0, fmaf(p1, w1, fmaf(p2, w2, bb)));
        y1[r * HD + c] = y;
        s += y; s2 = fmaf(y, y, s2);
    }
    psum[part * 128 + c] = s;
    psq[part * 128 + c] = s2;
}

// ---------------- BN finalize (parallel): one block per column ----------------
__launch_bounds__(256)
__global__ void bn_fin_par(const float* __restrict__ psum, const float* __restrict__ psq, int nb,
                           const float* __restrict__ g, const float* __restrict__ beta,
                           float* __restrict__ tp) {
    int c = blockIdx.x;
    int t = threadIdx.x;
    float S = 0.f, S2 = 0.f;
    for (int b = t; b < nb; b += 256) {
        S += psum[b * 128 + c];
        S2 += psq[b * 128 + c];
    }
    S = wave_sum(S); S2 = wave_sum(S2);
    __shared__ float sA[4], sB[4];
    int wid = t >> 6, lane = t & 63;
    if (lane == 0) { sA[wid] = S; sB[wid] = S2; }
    __syncthreads();
    if (t == 0) {
        float Sa = sA[0] + sA[1] + sA[2] + sA[3];
        float Sb = sB[0] + sB[1] + sB[2] + sB[3];
        const float invN = 1.f / (float)NPTS;
        float mean = Sa * invN;
        float var = Sb * invN - mean * mean;
        float a = g[c] * rsqrtf(var + 1e-5f);
        tp[c] = a;
        tp[128 + c] = beta[c] - mean * a;
    }
}

// ---------------- GEMM [nrows,128]@[128,128], tile 48x64, fused BN+ReLU on A ----------------
template <bool TRANS, bool STATS>
__launch_bounds__(256)
__global__ void gemm_bn(const float* __restrict__ A, int nrows,
                        const float* __restrict__ W, const float* __restrict__ bias,
                        const float* __restrict__ tp,
                        float* __restrict__ Out,
                        float* __restrict__ psum, float* __restrict__ psq) {
    __shared__ float As[48][132];   // stride 132: 16B-aligned rows, bank-spread
    __shared__ float Ws[128][64];
    int tid = threadIdx.x;
    int cb = blockIdx.x & 1, rb = blockIdx.x >> 1;
    int r0 = rb * 48;

    for (int i = tid; i < 48 * 128; i += 256) {
        int r = i >> 7, c = i & 127;
        int gr = r0 + r;
        float v = (gr < nrows) ? A[gr * HD + c] : 0.f;
        if (TRANS) v = fmaxf(fmaf(tp[c], v, tp[128 + c]), 0.f);
        As[r][c] = v;
    }
    for (int i = tid; i < 128 * 64; i += 256) {
        int k = i >> 6, c = i & 63;
        Ws[k][c] = W[k * 128 + (cb << 6) + c];
    }
    __syncthreads();

    int tc = tid & 15, tr = tid >> 4;
    int tr3 = tr * 3;
    float acc[3][4] = {};
#pragma unroll 2
    for (int k = 0; k < 128; k += 4) {
        const float4 a0 = *reinterpret_cast<const float4*>(&As[tr3][k]);
        const float4 a1 = *reinterpret_cast<const float4*>(&As[tr3 + 1][k]);
        const float4 a2 = *reinterpret_cast<const float4*>(&As[tr3 + 2][k]);
        const float4 w0 = *reinterpret_cast<const float4*>(&Ws[k][tc << 2]);
        const float4 w1 = *reinterpret_cast<const float4*>(&Ws[k + 1][tc << 2]);
        const float4 w2 = *reinterpret_cast<const float4*>(&Ws[k + 2][tc << 2]);
        const float4 w3v = *reinterpret_cast<const float4*>(&Ws[k + 3][tc << 2]);
#define FMA4(ai, wv) \
        acc[ai][0] = fmaf(av, wv.x, acc[ai][0]); acc[ai][1] = fmaf(av, wv.y, acc[ai][1]); \
        acc[ai][2] = fmaf(av, wv.z, acc[ai][2]); acc[ai][3] = fmaf(av, wv.w, acc[ai][3]);
        { float av = a0.x; FMA4(0, w0) } { float av = a0.y; FMA4(0, w1) }
        { float av = a0.z; FMA4(0, w2) } { float av = a0.w; FMA4(0, w3v) }
        { float av = a1.x; FMA4(1, w0) } { float av = a1.y; FMA4(1, w1) }
        { float av = a1.z; FMA4(1, w2) } { float av = a1.w; FMA4(1, w3v) }
        { float av = a2.x; FMA4(2, w0) } { float av = a2.y; FMA4(2, w1) }
        { float av = a2.z; FMA4(2, w2) } { float av = a2.w; FMA4(2, w3v) }
#undef FMA4
    }

    int c0 = (cb << 6) + (tc << 2);
    float b0 = bias[c0], b1v = bias[c0 + 1], b2v = bias[c0 + 2], b3v = bias[c0 + 3];
    float cs[4] = {}, cq[4] = {};
#pragma unroll
    for (int i = 0; i < 3; ++i) {
        int gr = r0 + tr3 + i;
        float v0 = acc[i][0] + b0, v1 = acc[i][1] + b1v, v2 = acc[i][2] + b2v, v3 = acc[i][3] + b3v;
        if (gr < nrows) {
            *reinterpret_cast<float4*>(&Out[gr * HD + c0]) = make_float4(v0, v1, v2, v3);
            if (STATS) {
                cs[0] += v0; cs[1] += v1; cs[2] += v2; cs[3] += v3;
                cq[0] = fmaf(v0, v0, cq[0]); cq[1] = fmaf(v1, v1, cq[1]);
                cq[2] = fmaf(v2, v2, cq[2]); cq[3] = fmaf(v3, v3, cq[3]);
            }
        }
    }
    if (STATS) {
        float* red = &As[0][0];
        __syncthreads();
        *reinterpret_cast<float4*>(&red[tr * 64 + (tc << 2)]) = make_float4(cs[0], cs[1], cs[2], cs[3]);
        __syncthreads();
        if (tid < 64) {
            float s = 0.f;
            for (int t = 0; t < 16; ++t) s += red[t * 64 + tid];
            psum[rb * 128 + (cb << 6) + tid] = s;
        }
        __syncthreads();
        *reinterpret_cast<float4*>(&red[tr * 64 + (tc << 2)]) = make_float4(cq[0], cq[1], cq[2], cq[3]);
        __syncthreads();
        if (tid < 64) {
            float s = 0.f;
            for (int t = 0; t < 16; ++t) s += red[t * 64 + tid];
            psq[rb * 128 + (cb << 6) + tid] = s;
        }
    }
}

// ---------------- CSR build ----------------
__launch_bounds__(256)
__global__ void init_kernel(int* __restrict__ inv, int* __restrict__ cnt, int* __restrict__ cursor) {
    int i = blockIdx.x * 256 + threadIdx.x;
    if (i < NPTS) inv[i] = INT_MAX;
    if (i < MS) { cnt[i] = 0; cursor[i] = 0; }
}

__launch_bounds__(256)
__global__ void invset_kernel(const int* __restrict__ smp, int* __restrict__ inv) {
    int m = blockIdx.x * 256 + threadIdx.x;
    if (m < MS) atomicMin(&inv[smp[m]], m);
}

__launch_bounds__(256)
__global__ void count_kernel(const int* __restrict__ ei, const int* __restrict__ inv,
                             int* __restrict__ cnt) {
    int e = blockIdx.x * 256 + threadIdx.x;
    if (e < NE) {
        int mr = inv[ei[NE + e]];
        if (mr < MS) atomicAdd(&cnt[mr], 1);
    }
}

__launch_bounds__(1024)
__global__ void scan_kernel(const int* __restrict__ cnt, int* __restrict__ offs) {
    const int C = 25;
    __shared__ int buf[1024];
    int tid = threadIdx.x;
    int loc[C];
    int run = 0;
    int base = tid * C;
#pragma unroll
    for (int i = 0; i < C; ++i) {
        int idx = base + i;
        int v = (idx < MS) ? cnt[idx] : 0;
        loc[i] = run; run += v;
    }
    buf[tid] = run;
    __syncthreads();
    for (int off = 1; off < 1024; off <<= 1) {
        int t = (tid >= off) ? buf[tid - off] : 0;
        __syncthreads();
        buf[tid] += t;
        __syncthreads();
    }
    int excl = buf[tid] - run;
#pragma unroll
    for (int i = 0; i < C; ++i) {
        int idx = base + i;
        if (idx < MS) offs[idx] = excl + loc[i];
    }
    if (tid == 1023) offs[MS] = buf[tid];
}

__launch_bounds__(256)
__global__ void scatter_kernel(const int* __restrict__ ei, const int* __restrict__ inv,
                               const int* __restrict__ offs, int* __restrict__ cursor,
                               int* __restrict__ elist) {
    int e = blockIdx.x * 256 + threadIdx.x;
    if (e < NE) {
        int mr = inv[ei[NE + e]];
        if (mr < MS) {
            int pos = atomicAdd(&cursor[mr], 1);
            elist[offs[mr] + pos] = ei[e];
        }
    }
}

// ---------------- K7: representative-only gather-mean of bnrelu(y2[src]) ----------------
__launch_bounds__(256)
__global__ void agg_kernel(const int* __restrict__ smp, const int* __restrict__ inv,
                           const int* __restrict__ offs, const int* __restrict__ elist,
                           const float* __restrict__ y2, const float* __restrict__ tp2,
                           float* __restrict__ aggX, float* __restrict__ hasE) {
    int tid = threadIdx.x, wid = tid >> 6, lane = tid & 63;
    int c0 = lane << 1;
    float ta0 = tp2[c0], ta1 = tp2[c0 + 1];
    float tb0 = tp2[128 + c0], tb1 = tp2[128 + c0 + 1];
    int p = blockIdx.x * 4 + wid;
    int m0 = p * 2;
#pragma unroll
    for (int r = 0; r < 2; ++r) {
        int m = m0 + r;
        if (m >= MS) continue;
        int d = smp[m];
        if (inv[d] != m) continue;          // only representatives
        int e0 = offs[m], e1 = offs[m + 1];
        float a0 = 0.f, a1 = 0.f, b0 = 0.f, b1 = 0.f;
        float cx = 0.f, cy = 0.f, dx = 0.f, dy = 0.f;
        int e = e0;
        for (; e + 3 < e1; e += 4) {        // 4 row-loads in flight
            int sA = elist[e], sB = elist[e + 1], sC = elist[e + 2], sD = elist[e + 3];
            const float2 vA = *reinterpret_cast<const float2*>(&y2[sA * HD + c0]);
            const float2 vB = *reinterpret_cast<const float2*>(&y2[sB * HD + c0]);
            const float2 vC = *reinterpret_cast<const float2*>(&y2[sC * HD + c0]);
            const float2 vD = *reinterpret_cast<const float2*>(&y2[sD * HD + c0]);
            a0 += fmaxf(fmaf(ta0, vA.x, tb0), 0.f); a1 += fmaxf(fmaf(ta1, vA.y, tb1), 0.f);
            b0 += fmaxf(fmaf(ta0, vB.x, tb0), 0.f); b1 += fmaxf(fmaf(ta1, vB.y, tb1), 0.f);
            cx += fmaxf(fmaf(ta0, vC.x, tb0), 0.f); cy += fmaxf(fmaf(ta1, vC.y, tb1), 0.f);
            dx += fmaxf(fmaf(ta0, vD.x, tb0), 0.f); dy += fmaxf(fmaf(ta1, vD.y, tb1), 0.f);
        }
        for (; e < e1; ++e) {
            const float2 v = *reinterpret_cast<const float2*>(&y2[elist[e] * HD + c0]);
            a0 += fmaxf(fmaf(ta0, v.x, tb0), 0.f); a1 += fmaxf(fmaf(ta1, v.y, tb1), 0.f);
        }
        float s0 = (a0 + b0) + (cx + dx);
        float s1 = (a1 + b1) + (cy + dy);
        float rs = 1.f / fmaxf((float)(e1 - e0), 1.f);
        *reinterpret_cast<float2*>(&aggX[m * HD + c0]) = make_float2(s0 * rs, s1 * rs);
        if (lane == 0) hasE[m] = (e1 > e0) ? 1.f : 0.f;
    }
}

// ---------------- K8: sx = relu([bnrelu(y2[smp]) | aggX[mr]] @ [Wc;Wn] + bc + f*bn_b) ----------------
__launch_bounds__(256)
__global__ void gemm_sx(const float* __restrict__ y2, const float* __restrict__ aggX,
                        const float* __restrict__ hasE,
                        const int* __restrict__ smp, const int* __restrict__ inv,
                        const float* __restrict__ WcWn,
                        const float* __restrict__ bc, const float* __restrict__ bn_b,
                        const float* __restrict__ tp2,
                        float* __restrict__ sx) {
    __shared__ float As[48][132];
    __shared__ float Ws[128][64];
    int tid = threadIdx.x;
    int cb = blockIdx.x & 1, rb = blockIdx.x >> 1;
    int r0 = rb * 48;
    int tc = tid & 15, tr = tid >> 4;
    int tr3 = tr * 3;
    float acc[3][4] = {};

    for (int kk = 0; kk < 2; ++kk) {
        if (kk) __syncthreads();
        for (int i = tid; i < 48 * 128; i += 256) {
            int r = i >> 7, c = i & 127;
            int gr = r0 + r;
            float v = 0.f;
            if (gr < MS) {
                int d = smp[gr];
                if (kk == 0) {
                    v = y2[d * HD + c];
                    v = fmaxf(fmaf(tp2[c], v, tp2[128 + c]), 0.f);
                } else {
                    v = aggX[inv[d] * HD + c];
                }
            }
            As[r][c] = v;
        }
        for (int i = tid; i < 128 * 64; i += 256) {
            int k = i >> 6, c = i & 63;
            Ws[k][c] = WcWn[(kk * 128 + k) * 128 + (cb << 6) + c];
        }
        __syncthreads();
#pragma unroll 2
        for (int k = 0; k < 128; k += 4) {
            const float4 a0 = *reinterpret_cast<const float4*>(&As[tr3][k]);
            const float4 a1 = *reinterpret_cast<const float4*>(&As[tr3 + 1][k]);
            const float4 a2 = *reinterpret_cast<const float4*>(&As[tr3 + 2][k]);
            const float4 w0 = *reinterpret_cast<const float4*>(&Ws[k][tc << 2]);
            const float4 w1 = *reinterpret_cast<const float4*>(&Ws[k + 1][tc << 2]);
            const float4 w2 = *reinterpret_cast<const float4*>(&Ws[k + 2][tc << 2]);
            const float4 w3v = *reinterpret_cast<const float4*>(&Ws[k + 3][tc << 2]);
#define FMA4(ai, wv) \
            acc[ai][0] = fmaf(av, wv.x, acc[ai][0]); acc[ai][1] = fmaf(av, wv.y, acc[ai][1]); \
            acc[ai][2] = fmaf(av, wv.z, acc[ai][2]); acc[ai][3] = fmaf(av, wv.w, acc[ai][3]);
            { float av = a0.x; FMA4(0, w0) } { float av = a0.y; FMA4(0, w1) }
            { float av = a0.z; FMA4(0, w2) } { float av = a0.w; FMA4(0, w3v) }
            { float av = a1.x; FMA4(1, w0) } { float av = a1.y; FMA4(1, w1) }
            { float av = a1.z; FMA4(1, w2) } { float av = a1.w; FMA4(1, w3v) }
            { float av = a2.x; FMA4(2, w0) } { float av = a2.y; FMA4(2, w1) }
            { float av = a2.z; FMA4(2, w2) } { float av = a2.w; FMA4(2, w3v) }
#undef FMA4
        }
    }

    int c0 = (cb << 6) + (tc << 2);
    float4 bcv = *reinterpret_cast<const float4*>(&bc[c0]);
    float4 bnv = *reinterpret_cast<const float4*>(&bn_b[c0]);
#pragma unroll
    for (int i = 0; i < 3; ++i) {
        int gr = r0 + tr3 + i;
        if (gr < MS) {
            float f = hasE[inv[smp[gr]]];
            float v0 = fmaxf(acc[i][0] + bcv.x + f * bnv.x, 0.f);
            float v1 = fmaxf(acc[i][1] + bcv.y + f * bnv.y, 0.f);
            float v2 = fmaxf(acc[i][2] + bcv.z + f * bnv.z, 0.f);
            float v3 = fmaxf(acc[i][3] + bcv.w + f * bnv.w, 0.f);
            *reinterpret_cast<float4*>(&sx[gr * HD + c0]) = make_float4(v0, v1, v2, v3);
        }
    }
}

// ---------------- K8b: p3 = sx@Wco128, sp = pts[smp] ----------------
__launch_bounds__(256)
__global__ void p3_kernel(const float* __restrict__ sx, const float* __restrict__ Wco128,
                          const int* __restrict__ smp, const float* __restrict__ pts,
                          float* __restrict__ p3, float* __restrict__ sp) {
    int wid = threadIdx.x >> 6, lane = threadIdx.x & 63;
    int m = blockIdx.x * 4 + wid;
    if (m >= MS) return;
    int c0 = lane << 1;
    const float2 v = *reinterpret_cast<const float2*>(&sx[m * HD + c0]);
    float q0 = v.x * Wco128[c0 * 3]     + v.y * Wco128[(c0 + 1) * 3];
    float q1 = v.x * Wco128[c0 * 3 + 1] + v.y * Wco128[(c0 + 1) * 3 + 1];
    float q2 = v.x * Wco128[c0 * 3 + 2] + v.y * Wco128[(c0 + 1) * 3 + 2];
    q0 = wave_sum(q0); q1 = wave_sum(q1); q2 = wave_sum(q2);
    int d = smp[m];
    if (lane == 0) { p3[m * 3] = q0; p3[m * 3 + 1] = q1; p3[m * 3 + 2] = q2; }
    if (lane < 3) sp[m * 3 + lane] = pts[d * 3 + lane];
}

// ---------------- K9: attention + folded output tail ----------------
__launch_bounds__(256)
__global__ void attn_kernel(const float* __restrict__ qk, const int* __restrict__ nbr,
                            const float* __restrict__ p3, const float* __restrict__ sp,
                            const float* __restrict__ w3, const float* __restrict__ bco,
                            float* __restrict__ refined) {
    int wid = threadIdx.x >> 6, lane = threadIdx.x & 63;
    int m = blockIdx.x * 4 + wid;
    if (m >= MS) return;
    float ql = qk[m * HD + lane];
    int nbv[KN];
    float s[KN];
#pragma unroll
    for (int j = 0; j < KN; ++j) nbv[j] = nbr[m * KN + j];
#pragma unroll
    for (int j = 0; j < KN; ++j) {
        float t = ql * qk[nbv[j] * HD + 64 + lane];
        t = wave_sum(t);
        s[j] = (nbv[j] != 0) ? t * (1.f / 8.000001f) : 0.f;
    }
    float mx = s[0];
#pragma unroll
    for (int j = 1; j < KN; ++j) mx = fmaxf(mx, s[j]);
    float den = 0.f;
#pragma unroll
    for (int j = 0; j < KN; ++j) { s[j] = __expf(s[j] - mx); den += s[j]; }
    float invd = 1.f / den;
    float sp0 = sp[m * 3], sp1 = sp[m * 3 + 1], sp2 = sp[m * 3 + 2];
    float a0 = 0.f, a1 = 0.f, a2 = 0.f;
#pragma unroll
    for (int j = 0; j < KN; ++j) {
        int nb = nbv[j];
        float wgt = s[j] * invd;
        float r0 = sp[nb * 3] - sp0, r1 = sp[nb * 3 + 1] - sp1, r2 = sp[nb * 3 + 2] - sp2;
        float g0 = p3[nb * 3]     + r0 * w3[0] + r1 * w3[3] + r2 * w3[6];
        float g1 = p3[nb * 3 + 1] + r0 * w3[1] + r1 * w3[4] + r2 * w3[7];
        float g2 = p3[nb * 3 + 2] + r0 * w3[2] + r1 * w3[5] + r2 * w3[8];
        a0 = fmaf(wgt, g0, a0); a1 = fmaf(wgt, g1, a1); a2 = fmaf(wgt, g2, a2);
    }
    if (lane == 0) {
        refined[m * 3]     = sp0 + a0 + bco[0];
        refined[m * 3 + 1] = sp1 + a1 + bco[1];
        refined[m * 3 + 2] = sp2 + a2 + bco[2];
    }
}

// ---------------- launch ----------------
extern "C" void kernel_launch(void* const* d_in, const int* in_sizes, int n_in,
                              void* d_out, int out_size, void* d_ws, size_t ws_size,
                              hipStream_t stream) {
    const float* pts   = (const float*)d_in[0];
    const int*   ei    = (const int*)d_in[1];
    const int*   smp   = (const int*)d_in[2];
    const int*   nbr   = (const int*)d_in[3];
    const float* W1    = (const float*)d_in[4];
    const float* b1    = (const float*)d_in[5];
    const float* g1    = (const float*)d_in[6];
    const float* beta1 = (const float*)d_in[7];
    const float* W2    = (const float*)d_in[8];
    const float* b2    = (const float*)d_in[9];
    const float* g2    = (const float*)d_in[10];
    const float* beta2 = (const float*)d_in[11];
    const float* Wc    = (const float*)d_in[12];
    const float* bc    = (const float*)d_in[13];
    const float* Wn    = (const float*)d_in[14];
    const float* bn_b  = (const float*)d_in[15];
    const float* Wq    = (const float*)d_in[16];
    const float* bq    = (const float*)d_in[17];
    const float* Wk    = (const float*)d_in[18];
    const float* bk    = (const float*)d_in[19];
    const float* Wcat  = (const float*)d_in[20];
    const float* bcat  = (const float*)d_in[21];
    const float* Wout  = (const float*)d_in[22];
    const float* bout  = (const float*)d_in[23];
    (void)in_sizes; (void)n_in; (void)out_size; (void)ws_size;

    float* w = (float*)d_ws;
    size_t o = 0;
    float* y1     = w + o; o += 6400000;
    float* y2     = w + o; o += 6400000;
    float* aggX   = w + o; o += 3200000;
    float* qkb    = w + o; o += 3200000;
    float* psum   = w + o; o += 262144;
    float* psq    = w + o; o += 262144;
    float* tp1    = w + o; o += 256;
    float* tp2    = w + o; o += 256;
    float* Wqk    = w + o; o += 16384;
    float* biasQK = w + o; o += 128;
    float* WcWn   = w + o; o += 32768;
    float* Wco128 = w + o; o += 384;
    float* w3     = w + o; o += 16;
    float* bco    = w + o; o += 16;
    float* p3     = w + o; o += 75008;
    float* sp     = w + o; o += 75008;
    float* hasE   = w + o; o += 25008;
    int* ip    = (int*)(w + o);
    int* inv   = ip;            ip += NPTS;
    int* cnt   = ip;            ip += MS;
    int* cursor= ip;            ip += MS;
    int* offs  = ip;            ip += MS + 4;
    int* elist = ip;

    float* refined = (float*)d_out;
    float* sx      = (float*)d_out + 75000;

    prep_kernel<<<1, 256, 0, stream>>>(Wq, bq, Wk, bk, Wcat, bcat, Wout, bout, Wc, Wn,
                                       Wqk, biasQK, WcWn, Wco128, w3, bco);
    lin1_kernel<<<1000, 256, 0, stream>>>(pts, W1, b1, y1, psum, psq);
    bn_fin_par<<<128, 256, 0, stream>>>(psum, psq, 2000, g1, beta1, tp1);
    gemm_bn<true, true><<<2084, 256, 0, stream>>>(y1, NPTS, W2, b2, tp1, y2, psum, psq);
    bn_fin_par<<<128, 256, 0, stream>>>(psum, psq, 1042, g2, beta2, tp2);
    init_kernel<<<196, 256, 0, stream>>>(inv, cnt, cursor);
    invset_kernel<<<98, 256, 0, stream>>>(smp, inv);
    count_kernel<<<3125, 256, 0, stream>>>(ei, inv, cnt);
    scan_kernel<<<1, 1024, 0, stream>>>(cnt, offs);
    scatter_kernel<<<3125, 256, 0, stream>>>(ei, inv, offs, cursor, elist);
    agg_kernel<<<3125, 256, 0, stream>>>(smp, inv, offs, elist, y2, tp2, aggX, hasE);
    gemm_sx<<<1042, 256, 0, stream>>>(y2, aggX, hasE, smp, inv, WcWn, bc, bn_b, tp2, sx);
    p3_kernel<<<6250, 256, 0, stream>>>(sx, Wco128, smp, pts, p3, sp);
    gemm_bn<false, false><<<1042, 256, 0, stream>>>(sx, MS, Wqk, biasQK, nullptr, qkb,
                                                    nullptr, nullptr);
    attn_kernel<<<6250, 256, 0, stream>>>(qkb, nbr, p3, sp, w3, bco, refined);
}

// Round 4
// 394.764 us; speedup vs baseline: 2.3306x; 1.3088x over previous
//
#include <hip/hip_runtime.h>
#include <climits>

#define NPTS 50000
#define NE   800000
#define MS   25000
#define KN   15
#define HD   128

// ---------------- helpers ----------------
__device__ __forceinline__ float wave_sum(float v) {
#pragma unroll
    for (int o = 32; o > 0; o >>= 1) v += __shfl_xor(v, o, 64);
    return v;
}

// ---------------- K0: fold Wcat@Wout, pack Wq|Wk, pack [Wc;Wn] ----------------
__launch_bounds__(256)
__global__ void prep_kernel(const float* __restrict__ Wq, const float* __restrict__ bq,
                            const float* __restrict__ Wk, const float* __restrict__ bk,
                            const float* __restrict__ Wcat, const float* __restrict__ bcat,
                            const float* __restrict__ Wout, const float* __restrict__ bout,
                            const float* __restrict__ Wc, const float* __restrict__ Wn,
                            float* __restrict__ Wqk, float* __restrict__ biasQK,
                            float* __restrict__ WcWn,
                            float* __restrict__ Wco128, float* __restrict__ w3, float* __restrict__ bco) {
    int tid = threadIdx.x;
    for (int i = tid; i < 128 * 128; i += 256) {
        int k = i >> 7, c = i & 127;
        Wqk[i] = (c < 64) ? Wq[k * 64 + c] : Wk[k * 64 + (c - 64)];
    }
    for (int i = tid; i < 256 * 128; i += 256) {
        int k = i >> 7, c = i & 127;
        WcWn[i] = (k < 128) ? Wc[k * 128 + c] : Wn[(k - 128) * 128 + c];
    }
    if (tid < 128) biasQK[tid] = (tid < 64) ? bq[tid] : bk[tid - 64];
    for (int i = tid; i < 131 * 3; i += 256) {
        int r = i / 3, j = i - r * 3;
        float s = 0.f;
        for (int t = 0; t < 131; ++t) s = fmaf(Wcat[r * 131 + t], Wout[t * 3 + j], s);
        if (r < 128) Wco128[r * 3 + j] = s; else w3[(r - 128) * 3 + j] = s;
    }
    if (tid < 3) {
        float s = 0.f;
        for (int t = 0; t < 131; ++t) s = fmaf(bcat[t], Wout[t * 3 + tid], s);
        bco[tid] = s + bout[tid];
    }
}

// ---------------- K1: y1 = points@W1 + b1, with column stats partials ----------------
__launch_bounds__(256)
__global__ void lin1_kernel(const float* __restrict__ pts, const float* __restrict__ W1,
                            const float* __restrict__ b1, float* __restrict__ y1,
                            float* __restrict__ psum, float* __restrict__ psq) {
    int c = threadIdx.x & 127;
    int half = threadIdx.x >> 7;
    int part = blockIdx.x * 2 + half;   // 0..1999
    float w0 = W1[c], w1 = W1[128 + c], w2 = W1[256 + c], bb = b1[c];
    float s = 0.f, s2 = 0.f;
    int r0 = part * 25, r1 = r0 + 25; if (r1 > NPTS) r1 = NPTS;
    for (int r = r0; r < r1; ++r) {
        float p0 = pts[r * 3], p1 = pts[r * 3 + 1], p2 = pts[r * 3 + 2];
        float y = fmaf(p0, w0, fmaf(p1, w1, fmaf(p2, w2, bb)));
        y1[r * HD + c] = y;
        s += y; s2 = fmaf(y, y, s2);
    }
    psum[part * 128 + c] = s;
    psq[part * 128 + c] = s2;
}

// ---------------- BN finalize (parallel): one block per column ----------------
__launch_bounds__(256)
__global__ void bn_fin_par(const float* __restrict__ psum, const float* __restrict__ psq, int nb,
                           const float* __restrict__ g, const float* __restrict__ beta,
                           float* __restrict__ tp) {
    int c = blockIdx.x;
    int t = threadIdx.x;
    float S = 0.f, S2 = 0.f;
    for (int b = t; b < nb; b += 256) {
        S += psum[b * 128 + c];
        S2 += psq[b * 128 + c];
    }
    S = wave_sum(S); S2 = wave_sum(S2);
    __shared__ float sA[4], sB[4];
    int wid = t >> 6, lane = t & 63;
    if (lane == 0) { sA[wid] = S; sB[wid] = S2; }
    __syncthreads();
    if (t == 0) {
        float Sa = sA[0] + sA[1] + sA[2] + sA[3];
        float Sb = sB[0] + sB[1] + sB[2] + sB[3];
        const float invN = 1.f / (float)NPTS;
        float mean = Sa * invN;
        float var = Sb * invN - mean * mean;
        float a = g[c] * rsqrtf(var + 1e-5f);
        tp[c] = a;
        tp[128 + c] = beta[c] - mean * a;
    }
}

#define FMA_BLOCK \
        { float av = a0.x; FMA4(0, w0) } { float av = a0.y; FMA4(0, w1) } \
        { float av = a0.z; FMA4(0, w2) } { float av = a0.w; FMA4(0, w3v) } \
        { float av = a1.x; FMA4(1, w0) } { float av = a1.y; FMA4(1, w1) } \
        { float av = a1.z; FMA4(1, w2) } { float av = a1.w; FMA4(1, w3v) } \
        { float av = a2.x; FMA4(2, w0) } { float av = a2.y; FMA4(2, w1) } \
        { float av = a2.z; FMA4(2, w2) } { float av = a2.w; FMA4(2, w3v) }
#define FMA4(ai, wv) \
        acc[ai][0] = fmaf(av, wv.x, acc[ai][0]); acc[ai][1] = fmaf(av, wv.y, acc[ai][1]); \
        acc[ai][2] = fmaf(av, wv.z, acc[ai][2]); acc[ai][3] = fmaf(av, wv.w, acc[ai][3]);

// ---------------- GEMM [nrows,128]@[128,128], tile 48x64, K-chunk 64 (29 KB LDS) ----------------
template <bool TRANS, bool STATS>
__launch_bounds__(256)
__global__ void gemm_bn(const float* __restrict__ A, int nrows,
                        const float* __restrict__ W, const float* __restrict__ bias,
                        const float* __restrict__ tp,
                        float* __restrict__ Out,
                        float* __restrict__ psum, float* __restrict__ psq) {
    __shared__ float As[48][68];    // 13 KB
    __shared__ float Ws[64][64];    // 16 KB
    int tid = threadIdx.x;
    int cb = blockIdx.x & 1, rb = blockIdx.x >> 1;
    int r0 = rb * 48;
    int tc = tid & 15, tr = tid >> 4;
    int tr3 = tr * 3;
    float acc[3][4] = {};

    for (int k0 = 0; k0 < 128; k0 += 64) {
        if (k0) __syncthreads();
        for (int i = tid; i < 48 * 16; i += 256) {
            int r = i >> 4, c4 = (i & 15) << 2;
            int gr = r0 + r;
            float4 v = make_float4(0.f, 0.f, 0.f, 0.f);
            if (gr < nrows) {
                v = *reinterpret_cast<const float4*>(&A[gr * HD + k0 + c4]);
                if (TRANS) {
                    int gc = k0 + c4;
                    v.x = fmaxf(fmaf(tp[gc],     v.x, tp[128 + gc]),     0.f);
                    v.y = fmaxf(fmaf(tp[gc + 1], v.y, tp[128 + gc + 1]), 0.f);
                    v.z = fmaxf(fmaf(tp[gc + 2], v.z, tp[128 + gc + 2]), 0.f);
                    v.w = fmaxf(fmaf(tp[gc + 3], v.w, tp[128 + gc + 3]), 0.f);
                }
            }
            *reinterpret_cast<float4*>(&As[r][c4]) = v;
        }
        for (int i = tid; i < 64 * 16; i += 256) {
            int k = i >> 4, c4 = (i & 15) << 2;
            *reinterpret_cast<float4*>(&Ws[k][c4]) =
                *reinterpret_cast<const float4*>(&W[(k0 + k) * 128 + (cb << 6) + c4]);
        }
        __syncthreads();
#pragma unroll 2
        for (int k = 0; k < 64; k += 4) {
            const float4 a0 = *reinterpret_cast<const float4*>(&As[tr3][k]);
            const float4 a1 = *reinterpret_cast<const float4*>(&As[tr3 + 1][k]);
            const float4 a2 = *reinterpret_cast<const float4*>(&As[tr3 + 2][k]);
            const float4 w0 = *reinterpret_cast<const float4*>(&Ws[k][tc << 2]);
            const float4 w1 = *reinterpret_cast<const float4*>(&Ws[k + 1][tc << 2]);
            const float4 w2 = *reinterpret_cast<const float4*>(&Ws[k + 2][tc << 2]);
            const float4 w3v = *reinterpret_cast<const float4*>(&Ws[k + 3][tc << 2]);
            FMA_BLOCK
        }
    }

    int c0 = (cb << 6) + (tc << 2);
    float b0 = bias[c0], b1v = bias[c0 + 1], b2v = bias[c0 + 2], b3v = bias[c0 + 3];
    float cs[4] = {}, cq[4] = {};
#pragma unroll
    for (int i = 0; i < 3; ++i) {
        int gr = r0 + tr3 + i;
        float v0 = acc[i][0] + b0, v1 = acc[i][1] + b1v, v2 = acc[i][2] + b2v, v3 = acc[i][3] + b3v;
        if (gr < nrows) {
            *reinterpret_cast<float4*>(&Out[gr * HD + c0]) = make_float4(v0, v1, v2, v3);
            if (STATS) {
                cs[0] += v0; cs[1] += v1; cs[2] += v2; cs[3] += v3;
                cq[0] = fmaf(v0, v0, cq[0]); cq[1] = fmaf(v1, v1, cq[1]);
                cq[2] = fmaf(v2, v2, cq[2]); cq[3] = fmaf(v3, v3, cq[3]);
            }
        }
    }
    if (STATS) {
        float* red = &As[0][0];     // 4 KB scratch inside As
        __syncthreads();
        *reinterpret_cast<float4*>(&red[tr * 64 + (tc << 2)]) = make_float4(cs[0], cs[1], cs[2], cs[3]);
        __syncthreads();
        if (tid < 64) {
            float s = 0.f;
            for (int t = 0; t < 16; ++t) s += red[t * 64 + tid];
            psum[rb * 128 + (cb << 6) + tid] = s;
        }
        __syncthreads();
        *reinterpret_cast<float4*>(&red[tr * 64 + (tc << 2)]) = make_float4(cq[0], cq[1], cq[2], cq[3]);
        __syncthreads();
        if (tid < 64) {
            float s = 0.f;
            for (int t = 0; t < 16; ++t) s += red[t * 64 + tid];
            psq[rb * 128 + (cb << 6) + tid] = s;
        }
    }
}

// ---------------- CSR build ----------------
__launch_bounds__(256)
__global__ void init_kernel(int* __restrict__ inv, int* __restrict__ cnt, int* __restrict__ cursor) {
    int i = blockIdx.x * 256 + threadIdx.x;
    if (i < NPTS) inv[i] = INT_MAX;
    if (i < MS) { cnt[i] = 0; cursor[i] = 0; }
}

__launch_bounds__(256)
__global__ void invset_kernel(const int* __restrict__ smp, int* __restrict__ inv) {
    int m = blockIdx.x * 256 + threadIdx.x;
    if (m < MS) atomicMin(&inv[smp[m]], m);
}

__launch_bounds__(256)
__global__ void count_kernel(const int* __restrict__ ei, const int* __restrict__ inv,
                             int* __restrict__ cnt) {
    int e = blockIdx.x * 256 + threadIdx.x;
    if (e < NE) {
        int mr = inv[ei[NE + e]];
        if (mr < MS) atomicAdd(&cnt[mr], 1);
    }
}

__launch_bounds__(1024)
__global__ void scan_kernel(const int* __restrict__ cnt, int* __restrict__ offs) {
    const int C = 25;
    __shared__ int buf[1024];
    int tid = threadIdx.x;
    int loc[C];
    int run = 0;
    int base = tid * C;
#pragma unroll
    for (int i = 0; i < C; ++i) {
        int idx = base + i;
        int v = (idx < MS) ? cnt[idx] : 0;
        loc[i] = run; run += v;
    }
    buf[tid] = run;
    __syncthreads();
    for (int off = 1; off < 1024; off <<= 1) {
        int t = (tid >= off) ? buf[tid - off] : 0;
        __syncthreads();
        buf[tid] += t;
        __syncthreads();
    }
    int excl = buf[tid] - run;
#pragma unroll
    for (int i = 0; i < C; ++i) {
        int idx = base + i;
        if (idx < MS) offs[idx] = excl + loc[i];
    }
    if (tid == 1023) offs[MS] = buf[tid];
}

__launch_bounds__(256)
__global__ void scatter_kernel(const int* __restrict__ ei, const int* __restrict__ inv,
                               const int* __restrict__ offs, int* __restrict__ cursor,
                               int* __restrict__ elist) {
    int e = blockIdx.x * 256 + threadIdx.x;
    if (e < NE) {
        int mr = inv[ei[NE + e]];
        if (mr < MS) {
            int pos = atomicAdd(&cursor[mr], 1);
            elist[offs[mr] + pos] = ei[e];
        }
    }
}

// ---------------- K7: representative-only gather-mean, 1 rep/wave, 8-deep MLP ----------------
__launch_bounds__(256)
__global__ void agg_kernel(const int* __restrict__ smp, const int* __restrict__ inv,
                           const int* __restrict__ offs, const int* __restrict__ elist,
                           const float* __restrict__ y2, const float* __restrict__ tp2,
                           float* __restrict__ aggX, float* __restrict__ hasE) {
    int tid = threadIdx.x, wid = tid >> 6, lane = tid & 63;
    int m = blockIdx.x * 4 + wid;
    if (m >= MS) return;
    int d = smp[m];
    if (inv[d] != m) return;            // representatives only
    int c0 = lane << 1;
    float ta0 = tp2[c0], ta1 = tp2[c0 + 1];
    float tb0 = tp2[128 + c0], tb1 = tp2[128 + c0 + 1];
    int e0 = offs[m], e1 = offs[m + 1];
    float sx0[8] = {}, sx1[8] = {};
    int e = e0;
    for (; e + 7 < e1; e += 8) {        // 8 row-loads in flight
        float2 v[8];
#pragma unroll
        for (int j = 0; j < 8; ++j)
            v[j] = *reinterpret_cast<const float2*>(&y2[elist[e + j] * HD + c0]);
#pragma unroll
        for (int j = 0; j < 8; ++j) {
            sx0[j] += fmaxf(fmaf(ta0, v[j].x, tb0), 0.f);
            sx1[j] += fmaxf(fmaf(ta1, v[j].y, tb1), 0.f);
        }
    }
    for (; e < e1; ++e) {
        const float2 v = *reinterpret_cast<const float2*>(&y2[elist[e] * HD + c0]);
        sx0[0] += fmaxf(fmaf(ta0, v.x, tb0), 0.f);
        sx1[0] += fmaxf(fmaf(ta1, v.y, tb1), 0.f);
    }
    float s0 = ((sx0[0] + sx0[1]) + (sx0[2] + sx0[3])) + ((sx0[4] + sx0[5]) + (sx0[6] + sx0[7]));
    float s1 = ((sx1[0] + sx1[1]) + (sx1[2] + sx1[3])) + ((sx1[4] + sx1[5]) + (sx1[6] + sx1[7]));
    float rs = 1.f / fmaxf((float)(e1 - e0), 1.f);
    *reinterpret_cast<float2*>(&aggX[m * HD + c0]) = make_float2(s0 * rs, s1 * rs);
    if (lane == 0) hasE[m] = (e1 > e0) ? 1.f : 0.f;
}

// ---------------- K8: sx = relu([bnrelu(y2[smp]) | aggX[mr]] @ [Wc;Wn] + bc + f*bn_b) ----------------
__launch_bounds__(256)
__global__ void gemm_sx(const float* __restrict__ y2, const float* __restrict__ aggX,
                        const float* __restrict__ hasE,
                        const int* __restrict__ smp, const int* __restrict__ inv,
                        const float* __restrict__ WcWn,
                        const float* __restrict__ bc, const float* __restrict__ bn_b,
                        const float* __restrict__ tp2,
                        float* __restrict__ sx) {
    __shared__ float As[48][68];
    __shared__ float Ws[64][64];
    int tid = threadIdx.x;
    int cb = blockIdx.x & 1, rb = blockIdx.x >> 1;
    int r0 = rb * 48;
    int tc = tid & 15, tr = tid >> 4;
    int tr3 = tr * 3;
    float acc[3][4] = {};

    for (int kk = 0; kk < 4; ++kk) {    // K = 256 in chunks of 64
        if (kk) __syncthreads();
        for (int i = tid; i < 48 * 16; i += 256) {
            int r = i >> 4, c4 = (i & 15) << 2;
            int gr = r0 + r;
            float4 v = make_float4(0.f, 0.f, 0.f, 0.f);
            if (gr < MS) {
                int d = smp[gr];
                if (kk < 2) {
                    int gc = (kk << 6) + c4;
                    v = *reinterpret_cast<const float4*>(&y2[d * HD + gc]);
                    v.x = fmaxf(fmaf(tp2[gc],     v.x, tp2[128 + gc]),     0.f);
                    v.y = fmaxf(fmaf(tp2[gc + 1], v.y, tp2[128 + gc + 1]), 0.f);
                    v.z = fmaxf(fmaf(tp2[gc + 2], v.z, tp2[128 + gc + 2]), 0.f);
                    v.w = fmaxf(fmaf(tp2[gc + 3], v.w, tp2[128 + gc + 3]), 0.f);
                } else {
                    v = *reinterpret_cast<const float4*>(&aggX[inv[d] * HD + ((kk - 2) << 6) + c4]);
                }
            }
            *reinterpret_cast<float4*>(&As[r][c4]) = v;
        }
        for (int i = tid; i < 64 * 16; i += 256) {
            int k = i >> 4, c4 = (i & 15) << 2;
            *reinterpret_cast<float4*>(&Ws[k][c4]) =
                *reinterpret_cast<const float4*>(&WcWn[((kk << 6) + k) * 128 + (cb << 6) + c4]);
        }
        __syncthreads();
#pragma unroll 2
        for (int k = 0; k < 64; k += 4) {
            const float4 a0 = *reinterpret_cast<const float4*>(&As[tr3][k]);
            const float4 a1 = *reinterpret_cast<const float4*>(&As[tr3 + 1][k]);
            const float4 a2 = *reinterpret_cast<const float4*>(&As[tr3 + 2][k]);
            const float4 w0 = *reinterpret_cast<const float4*>(&Ws[k][tc << 2]);
            const float4 w1 = *reinterpret_cast<const float4*>(&Ws[k + 1][tc << 2]);
            const float4 w2 = *reinterpret_cast<const float4*>(&Ws[k + 2][tc << 2]);
            const float4 w3v = *reinterpret_cast<const float4*>(&Ws[k + 3][tc << 2]);
            FMA_BLOCK
        }
    }

    int c0 = (cb << 6) + (tc << 2);
    float4 bcv = *reinterpret_cast<const float4*>(&bc[c0]);
    float4 bnv = *reinterpret_cast<const float4*>(&bn_b[c0]);
#pragma unroll
    for (int i = 0; i < 3; ++i) {
        int gr = r0 + tr3 + i;
        if (gr < MS) {
            float f = hasE[inv[smp[gr]]];
            float v0 = fmaxf(acc[i][0] + bcv.x + f * bnv.x, 0.f);
            float v1 = fmaxf(acc[i][1] + bcv.y + f * bnv.y, 0.f);
            float v2 = fmaxf(acc[i][2] + bcv.z + f * bnv.z, 0.f);
            float v3 = fmaxf(acc[i][3] + bcv.w + f * bnv.w, 0.f);
            *reinterpret_cast<float4*>(&sx[gr * HD + c0]) = make_float4(v0, v1, v2, v3);
        }
    }
}

// ---------------- K8b: p3 = sx@Wco128, sp = pts[smp] ----------------
__launch_bounds__(256)
__global__ void p3_kernel(const float* __restrict__ sx, const float* __restrict__ Wco128,
                          const int* __restrict__ smp, const float* __restrict__ pts,
                          float* __restrict__ p3, float* __restrict__ sp) {
    int wid = threadIdx.x >> 6, lane = threadIdx.x & 63;
    int m = blockIdx.x * 4 + wid;
    if (m >= MS) return;
    int c0 = lane << 1;
    const float2 v = *reinterpret_cast<const float2*>(&sx[m * HD + c0]);
    float q0 = v.x * Wco128[c0 * 3]     + v.y * Wco128[(c0 + 1) * 3];
    float q1 = v.x * Wco128[c0 * 3 + 1] + v.y * Wco128[(c0 + 1) * 3 + 1];
    float q2 = v.x * Wco128[c0 * 3 + 2] + v.y * Wco128[(c0 + 1) * 3 + 2];
    q0 = wave_sum(q0); q1 = wave_sum(q1); q2 = wave_sum(q2);
    int d = smp[m];
    if (lane == 0) { p3[m * 3] = q0; p3[m * 3 + 1] = q1; p3[m * 3 + 2] = q2; }
    if (lane < 3) sp[m * 3 + lane] = pts[d * 3 + lane];
}

// ---------------- K9: attention + folded output tail ----------------
__launch_bounds__(256)
__global__ void attn_kernel(const float* __restrict__ qk, const int* __restrict__ nbr,
                            const float* __restrict__ p3, const float* __restrict__ sp,
                            const float* __restrict__ w3, const float* __restrict__ bco,
                            float* __restrict__ refined) {
    int wid = threadIdx.x >> 6, lane = threadIdx.x & 63;
    int m = blockIdx.x * 4 + wid;
    if (m >= MS) return;
    float ql = qk[m * HD + lane];
    int nbv[KN];
    float s[KN];
#pragma unroll
    for (int j = 0; j < KN; ++j) nbv[j] = nbr[m * KN + j];
#pragma unroll
    for (int j = 0; j < KN; ++j) {
        float t = ql * qk[nbv[j] * HD + 64 + lane];
        t = wave_sum(t);
        s[j] = (nbv[j] != 0) ? t * (1.f / 8.000001f) : 0.f;
    }
    float mx = s[0];
#pragma unroll
    for (int j = 1; j < KN; ++j) mx = fmaxf(mx, s[j]);
    float den = 0.f;
#pragma unroll
    for (int j = 0; j < KN; ++j) { s[j] = __expf(s[j] - mx); den += s[j]; }
    float invd = 1.f / den;
    float sp0 = sp[m * 3], sp1 = sp[m * 3 + 1], sp2 = sp[m * 3 + 2];
    float a0 = 0.f, a1 = 0.f, a2 = 0.f;
#pragma unroll
    for (int j = 0; j < KN; ++j) {
        int nb = nbv[j];
        float wgt = s[j] * invd;
        float r0 = sp[nb * 3] - sp0, r1 = sp[nb * 3 + 1] - sp1, r2 = sp[nb * 3 + 2] - sp2;
        float g0 = p3[nb * 3]     + r0 * w3[0] + r1 * w3[3] + r2 * w3[6];
        float g1 = p3[nb * 3 + 1] + r0 * w3[1] + r1 * w3[4] + r2 * w3[7];
        float g2 = p3[nb * 3 + 2] + r0 * w3[2] + r1 * w3[5] + r2 * w3[8];
        a0 = fmaf(wgt, g0, a0); a1 = fmaf(wgt, g1, a1); a2 = fmaf(wgt, g2, a2);
    }
    if (lane == 0) {
        refined[m * 3]     = sp0 + a0 + bco[0];
        refined[m * 3 + 1] = sp1 + a1 + bco[1];
        refined[m * 3 + 2] = sp2 + a2 + bco[2];
    }
}

// ---------------- launch ----------------
extern "C" void kernel_launch(void* const* d_in, const int* in_sizes, int n_in,
                              void* d_out, int out_size, void* d_ws, size_t ws_size,
                              hipStream_t stream) {
    const float* pts   = (const float*)d_in[0];
    const int*   ei    = (const int*)d_in[1];
    const int*   smp   = (const int*)d_in[2];
    const int*   nbr   = (const int*)d_in[3];
    const float* W1    = (const float*)d_in[4];
    const float* b1    = (const float*)d_in[5];
    const float* g1    = (const float*)d_in[6];
    const float* beta1 = (const float*)d_in[7];
    const float* W2    = (const float*)d_in[8];
    const float* b2    = (const float*)d_in[9];
    const float* g2    = (const float*)d_in[10];
    const float* beta2 = (const float*)d_in[11];
    const float* Wc    = (const float*)d_in[12];
    const float* bc    = (const float*)d_in[13];
    const float* Wn    = (const float*)d_in[14];
    const float* bn_b  = (const float*)d_in[15];
    const float* Wq    = (const float*)d_in[16];
    const float* bq    = (const float*)d_in[17];
    const float* Wk    = (const float*)d_in[18];
    const float* bk    = (const float*)d_in[19];
    const float* Wcat  = (const float*)d_in[20];
    const float* bcat  = (const float*)d_in[21];
    const float* Wout  = (const float*)d_in[22];
    const float* bout  = (const float*)d_in[23];
    (void)in_sizes; (void)n_in; (void)out_size; (void)ws_size;

    float* w = (float*)d_ws;
    size_t o = 0;
    float* y1     = w + o; o += 6400000;
    float* y2     = w + o; o += 6400000;
    float* aggX   = w + o; o += 3200000;
    float* qkb    = w + o; o += 3200000;
    float* psum   = w + o; o += 262144;
    float* psq    = w + o; o += 262144;
    float* tp1    = w + o; o += 256;
    float* tp2    = w + o; o += 256;
    float* Wqk    = w + o; o += 16384;
    float* biasQK = w + o; o += 128;
    float* WcWn   = w + o; o += 32768;
    float* Wco128 = w + o; o += 384;
    float* w3     = w + o; o += 16;
    float* bco    = w + o; o += 16;
    float* p3     = w + o; o += 75008;
    float* sp     = w + o; o += 75008;
    float* hasE   = w + o; o += 25008;
    int* ip    = (int*)(w + o);
    int* inv   = ip;            ip += NPTS;
    int* cnt   = ip;            ip += MS;
    int* cursor= ip;            ip += MS;
    int* offs  = ip;            ip += MS + 4;
    int* elist = ip;

    float* refined = (float*)d_out;
    float* sx      = (float*)d_out + 75000;

    prep_kernel<<<1, 256, 0, stream>>>(Wq, bq, Wk, bk, Wcat, bcat, Wout, bout, Wc, Wn,
                                       Wqk, biasQK, WcWn, Wco128, w3, bco);
    lin1_kernel<<<1000, 256, 0, stream>>>(pts, W1, b1, y1, psum, psq);
    bn_fin_par<<<128, 256, 0, stream>>>(psum, psq, 2000, g1, beta1, tp1);
    gemm_bn<true, true><<<2084, 256, 0, stream>>>(y1, NPTS, W2, b2, tp1, y2, psum, psq);
    bn_fin_par<<<128, 256, 0, stream>>>(psum, psq, 1042, g2, beta2, tp2);
    init_kernel<<<196, 256, 0, stream>>>(inv, cnt, cursor);
    invset_kernel<<<98, 256, 0, stream>>>(smp, inv);
    count_kernel<<<3125, 256, 0, stream>>>(ei, inv, cnt);
    scan_kernel<<<1, 1024, 0, stream>>>(cnt, offs);
    scatter_kernel<<<3125, 256, 0, stream>>>(ei, inv, offs, cursor, elist);
    agg_kernel<<<6250, 256, 0, stream>>>(smp, inv, offs, elist, y2, tp2, aggX, hasE);
    gemm_sx<<<1042, 256, 0, stream>>>(y2, aggX, hasE, smp, inv, WcWn, bc, bn_b, tp2, sx);
    p3_kernel<<<6250, 256, 0, stream>>>(sx, Wco128, smp, pts, p3, sp);
    gemm_bn<false, false><<<1042, 256, 0, stream>>>(sx, MS, Wqk, biasQK, nullptr, qkb,
                                                    nullptr, nullptr);
    attn_kernel<<<6250, 256, 0, stream>>>(qkb, nbr, p3, sp, w3, bco, refined);
}

// Round 5
// 337.640 us; speedup vs baseline: 2.7249x; 1.1692x over previous
//
#include <hip/hip_runtime.h>
#include <climits>

#define NPTS 50000
#define NE   800000
#define MS   25000
#define KN   15
#define HD   128

// ---------------- helpers ----------------
__device__ __forceinline__ float wave_sum(float v) {
#pragma unroll
    for (int o = 32; o > 0; o >>= 1) v += __shfl_xor(v, o, 64);
    return v;
}

// ---------------- K0: fold Wcat@Wout, pack Wq|Wk, pack [Wc;Wn] (parallel, 292 blocks) ----------------
__launch_bounds__(256)
__global__ void prep_kernel(const float* __restrict__ Wq, const float* __restrict__ bq,
                            const float* __restrict__ Wk, const float* __restrict__ bk,
                            const float* __restrict__ Wcat, const float* __restrict__ bcat,
                            const float* __restrict__ Wout, const float* __restrict__ bout,
                            const float* __restrict__ Wc, const float* __restrict__ Wn,
                            float* __restrict__ Wqk, float* __restrict__ biasQK,
                            float* __restrict__ WcWn,
                            float* __restrict__ Wco128, float* __restrict__ w3, float* __restrict__ bco) {
    int b = blockIdx.x, tid = threadIdx.x;
    if (b < 64) {                       // Wqk pack: 16384 elems
        int i = b * 256 + tid;
        int k = i >> 7, c = i & 127;
        Wqk[i] = (c < 64) ? Wq[k * 64 + c] : Wk[k * 64 + (c - 64)];
    } else if (b < 192) {               // WcWn pack: 32768 elems
        int i = (b - 64) * 256 + tid;
        int k = i >> 7, c = i & 127;
        WcWn[i] = (k < 128) ? Wc[k * 128 + c] : Wn[(k - 128) * 128 + c];
    } else if (b == 192) {
        if (tid < 128) biasQK[tid] = (tid < 64) ? bq[tid] : bk[tid - 64];
    } else {                            // fold: 396 waves, one output each
        int wid = tid >> 6, lane = tid & 63;
        int out = (b - 193) * 4 + wid;  // 0..395
        if (out < 396) {
            int r = out / 3, j = out - r * 3;   // r==131 -> bco row
            const float* src = (r < 131) ? &Wcat[r * 131] : bcat;
            float s = 0.f;
            s = fmaf(src[lane], Wout[lane * 3 + j], s);
            s = fmaf(src[lane + 64], Wout[(lane + 64) * 3 + j], s);
            if (lane < 3) s = fmaf(src[lane + 128], Wout[(lane + 128) * 3 + j], s);
            s = wave_sum(s);
            if (lane == 0) {
                if (r < 128) Wco128[r * 3 + j] = s;
                else if (r < 131) w3[(r - 128) * 3 + j] = s;
                else bco[j] = s + bout[j];
            }
        }
    }
}

// ---------------- K1: y1 = points@W1 + b1, with column stats partials ----------------
__launch_bounds__(256)
__global__ void lin1_kernel(const float* __restrict__ pts, const float* __restrict__ W1,
                            const float* __restrict__ b1, float* __restrict__ y1,
                            float* __restrict__ psum, float* __restrict__ psq) {
    int c = threadIdx.x & 127;
    int half = threadIdx.x >> 7;
    int part = blockIdx.x * 2 + half;   // 0..1999
    float w0 = W1[c], w1 = W1[128 + c], w2 = W1[256 + c], bb = b1[c];
    float s = 0.f, s2 = 0.f;
    int r0 = part * 25, r1 = r0 + 25; if (r1 > NPTS) r1 = NPTS;
    for (int r = r0; r < r1; ++r) {
        float p0 = pts[r * 3], p1 = pts[r * 3 + 1], p2 = pts[r * 3 + 2];
        float y = fmaf(p0, w0, fmaf(p1, w1, fmaf(p2, w2, bb)));
        y1[r * HD + c] = y;
        s += y; s2 = fmaf(y, y, s2);
    }
    psum[part * 128 + c] = s;
    psq[part * 128 + c] = s2;
}

// ---------------- BN finalize (parallel): one block per column ----------------
__launch_bounds__(256)
__global__ void bn_fin_par(const float* __restrict__ psum, const float* __restrict__ psq, int nb,
                           const float* __restrict__ g, const float* __restrict__ beta,
                           float* __restrict__ tp) {
    int c = blockIdx.x;
    int t = threadIdx.x;
    float S = 0.f, S2 = 0.f;
    for (int b = t; b < nb; b += 256) {
        S += psum[b * 128 + c];
        S2 += psq[b * 128 + c];
    }
    S = wave_sum(S); S2 = wave_sum(S2);
    __shared__ float sA[4], sB[4];
    int wid = t >> 6, lane = t & 63;
    if (lane == 0) { sA[wid] = S; sB[wid] = S2; }
    __syncthreads();
    if (t == 0) {
        float Sa = sA[0] + sA[1] + sA[2] + sA[3];
        float Sb = sB[0] + sB[1] + sB[2] + sB[3];
        const float invN = 1.f / (float)NPTS;
        float mean = Sa * invN;
        float var = Sb * invN - mean * mean;
        float a = g[c] * rsqrtf(var + 1e-5f);
        tp[c] = a;
        tp[128 + c] = beta[c] - mean * a;
    }
}

#define FMA_BLOCK \
        { float av = a0.x; FMA4(0, w0) } { float av = a0.y; FMA4(0, w1) } \
        { float av = a0.z; FMA4(0, w2) } { float av = a0.w; FMA4(0, w3v) } \
        { float av = a1.x; FMA4(1, w0) } { float av = a1.y; FMA4(1, w1) } \
        { float av = a1.z; FMA4(1, w2) } { float av = a1.w; FMA4(1, w3v) } \
        { float av = a2.x; FMA4(2, w0) } { float av = a2.y; FMA4(2, w1) } \
        { float av = a2.z; FMA4(2, w2) } { float av = a2.w; FMA4(2, w3v) }
#define FMA4(ai, wv) \
        acc[ai][0] = fmaf(av, wv.x, acc[ai][0]); acc[ai][1] = fmaf(av, wv.y, acc[ai][1]); \
        acc[ai][2] = fmaf(av, wv.z, acc[ai][2]); acc[ai][3] = fmaf(av, wv.w, acc[ai][3]);

// ---------------- GEMM [nrows,128]@[128,128], tile 48x64, K-chunk 64 (29 KB LDS) ----------------
template <bool TRANS, bool STATS>
__launch_bounds__(256)
__global__ void gemm_bn(const float* __restrict__ A, int nrows,
                        const float* __restrict__ W, const float* __restrict__ bias,
                        const float* __restrict__ tp,
                        float* __restrict__ Out,
                        float* __restrict__ psum, float* __restrict__ psq) {
    __shared__ float As[48][68];    // 13 KB
    __shared__ float Ws[64][64];    // 16 KB
    int tid = threadIdx.x;
    int cb = blockIdx.x & 1, rb = blockIdx.x >> 1;
    int r0 = rb * 48;
    int tc = tid & 15, tr = tid >> 4;
    int tr3 = tr * 3;
    float acc[3][4] = {};

    for (int k0 = 0; k0 < 128; k0 += 64) {
        if (k0) __syncthreads();
        for (int i = tid; i < 48 * 16; i += 256) {
            int r = i >> 4, c4 = (i & 15) << 2;
            int gr = r0 + r;
            float4 v = make_float4(0.f, 0.f, 0.f, 0.f);
            if (gr < nrows) {
                v = *reinterpret_cast<const float4*>(&A[gr * HD + k0 + c4]);
                if (TRANS) {
                    int gc = k0 + c4;
                    v.x = fmaxf(fmaf(tp[gc],     v.x, tp[128 + gc]),     0.f);
                    v.y = fmaxf(fmaf(tp[gc + 1], v.y, tp[128 + gc + 1]), 0.f);
                    v.z = fmaxf(fmaf(tp[gc + 2], v.z, tp[128 + gc + 2]), 0.f);
                    v.w = fmaxf(fmaf(tp[gc + 3], v.w, tp[128 + gc + 3]), 0.f);
                }
            }
            *reinterpret_cast<float4*>(&As[r][c4]) = v;
        }
        for (int i = tid; i < 64 * 16; i += 256) {
            int k = i >> 4, c4 = (i & 15) << 2;
            *reinterpret_cast<float4*>(&Ws[k][c4]) =
                *reinterpret_cast<const float4*>(&W[(k0 + k) * 128 + (cb << 6) + c4]);
        }
        __syncthreads();
#pragma unroll 2
        for (int k = 0; k < 64; k += 4) {
            const float4 a0 = *reinterpret_cast<const float4*>(&As[tr3][k]);
            const float4 a1 = *reinterpret_cast<const float4*>(&As[tr3 + 1][k]);
            const float4 a2 = *reinterpret_cast<const float4*>(&As[tr3 + 2][k]);
            const float4 w0 = *reinterpret_cast<const float4*>(&Ws[k][tc << 2]);
            const float4 w1 = *reinterpret_cast<const float4*>(&Ws[k + 1][tc << 2]);
            const float4 w2 = *reinterpret_cast<const float4*>(&Ws[k + 2][tc << 2]);
            const float4 w3v = *reinterpret_cast<const float4*>(&Ws[k + 3][tc << 2]);
            FMA_BLOCK
        }
    }

    int c0 = (cb << 6) + (tc << 2);
    float b0 = bias[c0], b1v = bias[c0 + 1], b2v = bias[c0 + 2], b3v = bias[c0 + 3];
    float cs[4] = {}, cq[4] = {};
#pragma unroll
    for (int i = 0; i < 3; ++i) {
        int gr = r0 + tr3 + i;
        float v0 = acc[i][0] + b0, v1 = acc[i][1] + b1v, v2 = acc[i][2] + b2v, v3 = acc[i][3] + b3v;
        if (gr < nrows) {
            *reinterpret_cast<float4*>(&Out[gr * HD + c0]) = make_float4(v0, v1, v2, v3);
            if (STATS) {
                cs[0] += v0; cs[1] += v1; cs[2] += v2; cs[3] += v3;
                cq[0] = fmaf(v0, v0, cq[0]); cq[1] = fmaf(v1, v1, cq[1]);
                cq[2] = fmaf(v2, v2, cq[2]); cq[3] = fmaf(v3, v3, cq[3]);
            }
        }
    }
    if (STATS) {
        float* red = &As[0][0];     // 4 KB scratch inside As
        __syncthreads();
        *reinterpret_cast<float4*>(&red[tr * 64 + (tc << 2)]) = make_float4(cs[0], cs[1], cs[2], cs[3]);
        __syncthreads();
        if (tid < 64) {
            float s = 0.f;
            for (int t = 0; t < 16; ++t) s += red[t * 64 + tid];
            psum[rb * 128 + (cb << 6) + tid] = s;
        }
        __syncthreads();
        *reinterpret_cast<float4*>(&red[tr * 64 + (tc << 2)]) = make_float4(cq[0], cq[1], cq[2], cq[3]);
        __syncthreads();
        if (tid < 64) {
            float s = 0.f;
            for (int t = 0; t < 16; ++t) s += red[t * 64 + tid];
            psq[rb * 128 + (cb << 6) + tid] = s;
        }
    }
}

// ---------------- CSR build ----------------
__launch_bounds__(256)
__global__ void init_kernel(int* __restrict__ inv, int* __restrict__ cnt, int* __restrict__ cursor) {
    int i = blockIdx.x * 256 + threadIdx.x;
    if (i < NPTS) inv[i] = INT_MAX;
    if (i < MS) { cnt[i] = 0; cursor[i] = 0; }
}

__launch_bounds__(256)
__global__ void invset_kernel(const int* __restrict__ smp, int* __restrict__ inv) {
    int m = blockIdx.x * 256 + threadIdx.x;
    if (m < MS) atomicMin(&inv[smp[m]], m);
}

__launch_bounds__(256)
__global__ void count_kernel(const int* __restrict__ ei, const int* __restrict__ inv,
                             int* __restrict__ cnt) {
    int e = blockIdx.x * 256 + threadIdx.x;
    if (e < NE) {
        int mr = inv[ei[NE + e]];
        if (mr < MS) atomicAdd(&cnt[mr], 1);
    }
}

__launch_bounds__(1024)
__global__ void scan_kernel(const int* __restrict__ cnt, int* __restrict__ offs) {
    const int C = 25;
    __shared__ int buf[1024];
    int tid = threadIdx.x;
    int loc[C];
    int run = 0;
    int base = tid * C;
#pragma unroll
    for (int i = 0; i < C; ++i) {
        int idx = base + i;
        int v = (idx < MS) ? cnt[idx] : 0;
        loc[i] = run; run += v;
    }
    buf[tid] = run;
    __syncthreads();
    for (int off = 1; off < 1024; off <<= 1) {
        int t = (tid >= off) ? buf[tid - off] : 0;
        __syncthreads();
        buf[tid] += t;
        __syncthreads();
    }
    int excl = buf[tid] - run;
#pragma unroll
    for (int i = 0; i < C; ++i) {
        int idx = base + i;
        if (idx < MS) offs[idx] = excl + loc[i];
    }
    if (tid == 1023) offs[MS] = buf[tid];
}

__launch_bounds__(256)
__global__ void scatter_kernel(const int* __restrict__ ei, const int* __restrict__ inv,
                               const int* __restrict__ offs, int* __restrict__ cursor,
                               int* __restrict__ elist) {
    int e = blockIdx.x * 256 + threadIdx.x;
    if (e < NE) {
        int mr = inv[ei[NE + e]];
        if (mr < MS) {
            int pos = atomicAdd(&cursor[mr], 1);
            elist[offs[mr] + pos] = ei[e];
        }
    }
}

// ---------------- K7: representative-only gather-mean, 1 rep/wave, 8-deep MLP ----------------
__launch_bounds__(256)
__global__ void agg_kernel(const int* __restrict__ smp, const int* __restrict__ inv,
                           const int* __restrict__ offs, const int* __restrict__ elist,
                           const float* __restrict__ y2, const float* __restrict__ tp2,
                           float* __restrict__ aggX, float* __restrict__ hasE) {
    int tid = threadIdx.x, wid = tid >> 6, lane = tid & 63;
    int m = blockIdx.x * 4 + wid;
    if (m >= MS) return;
    int d = smp[m];
    if (inv[d] != m) return;            // representatives only
    int c0 = lane << 1;
    float ta0 = tp2[c0], ta1 = tp2[c0 + 1];
    float tb0 = tp2[128 + c0], tb1 = tp2[128 + c0 + 1];
    int e0 = offs[m], e1 = offs[m + 1];
    float sx0[8] = {}, sx1[8] = {};
    int e = e0;
    for (; e + 7 < e1; e += 8) {        // 8 row-loads in flight
        float2 v[8];
#pragma unroll
        for (int j = 0; j < 8; ++j)
            v[j] = *reinterpret_cast<const float2*>(&y2[elist[e + j] * HD + c0]);
#pragma unroll
        for (int j = 0; j < 8; ++j) {
            sx0[j] += fmaxf(fmaf(ta0, v[j].x, tb0), 0.f);
            sx1[j] += fmaxf(fmaf(ta1, v[j].y, tb1), 0.f);
        }
    }
    for (; e < e1; ++e) {
        const float2 v = *reinterpret_cast<const float2*>(&y2[elist[e] * HD + c0]);
        sx0[0] += fmaxf(fmaf(ta0, v.x, tb0), 0.f);
        sx1[0] += fmaxf(fmaf(ta1, v.y, tb1), 0.f);
    }
    float s0 = ((sx0[0] + sx0[1]) + (sx0[2] + sx0[3])) + ((sx0[4] + sx0[5]) + (sx0[6] + sx0[7]));
    float s1 = ((sx1[0] + sx1[1]) + (sx1[2] + sx1[3])) + ((sx1[4] + sx1[5]) + (sx1[6] + sx1[7]));
    float rs = 1.f / fmaxf((float)(e1 - e0), 1.f);
    *reinterpret_cast<float2*>(&aggX[m * HD + c0]) = make_float2(s0 * rs, s1 * rs);
    if (lane == 0) hasE[m] = (e1 > e0) ? 1.f : 0.f;
}

// ---------------- K8: sx = relu([bnrelu(y2[smp]) | aggX[mr]] @ [Wc;Wn] + bc + f*bn_b) ----------------
__launch_bounds__(256)
__global__ void gemm_sx(const float* __restrict__ y2, const float* __restrict__ aggX,
                        const float* __restrict__ hasE,
                        const int* __restrict__ smp, const int* __restrict__ inv,
                        const float* __restrict__ WcWn,
                        const float* __restrict__ bc, const float* __restrict__ bn_b,
                        const float* __restrict__ tp2,
                        float* __restrict__ sx) {
    __shared__ float As[48][68];
    __shared__ float Ws[64][64];
    int tid = threadIdx.x;
    int cb = blockIdx.x & 1, rb = blockIdx.x >> 1;
    int r0 = rb * 48;
    int tc = tid & 15, tr = tid >> 4;
    int tr3 = tr * 3;
    float acc[3][4] = {};

    for (int kk = 0; kk < 4; ++kk) {    // K = 256 in chunks of 64
        if (kk) __syncthreads();
        for (int i = tid; i < 48 * 16; i += 256) {
            int r = i >> 4, c4 = (i & 15) << 2;
            int gr = r0 + r;
            float4 v = make_float4(0.f, 0.f, 0.f, 0.f);
            if (gr < MS) {
                int d = smp[gr];
                if (kk < 2) {
                    int gc = (kk << 6) + c4;
                    v = *reinterpret_cast<const float4*>(&y2[d * HD + gc]);
                    v.x = fmaxf(fmaf(tp2[gc],     v.x, tp2[128 + gc]),     0.f);
                    v.y = fmaxf(fmaf(tp2[gc + 1], v.y, tp2[128 + gc + 1]), 0.f);
                    v.z = fmaxf(fmaf(tp2[gc + 2], v.z, tp2[128 + gc + 2]), 0.f);
                    v.w = fmaxf(fmaf(tp2[gc + 3], v.w, tp2[128 + gc + 3]), 0.f);
                } else {
                    v = *reinterpret_cast<const float4*>(&aggX[inv[d] * HD + ((kk - 2) << 6) + c4]);
                }
            }
            *reinterpret_cast<float4*>(&As[r][c4]) = v;
        }
        for (int i = tid; i < 64 * 16; i += 256) {
            int k = i >> 4, c4 = (i & 15) << 2;
            *reinterpret_cast<float4*>(&Ws[k][c4]) =
                *reinterpret_cast<const float4*>(&WcWn[((kk << 6) + k) * 128 + (cb << 6) + c4]);
        }
        __syncthreads();
#pragma unroll 2
        for (int k = 0; k < 64; k += 4) {
            const float4 a0 = *reinterpret_cast<const float4*>(&As[tr3][k]);
            const float4 a1 = *reinterpret_cast<const float4*>(&As[tr3 + 1][k]);
            const float4 a2 = *reinterpret_cast<const float4*>(&As[tr3 + 2][k]);
            const float4 w0 = *reinterpret_cast<const float4*>(&Ws[k][tc << 2]);
            const float4 w1 = *reinterpret_cast<const float4*>(&Ws[k + 1][tc << 2]);
            const float4 w2 = *reinterpret_cast<const float4*>(&Ws[k + 2][tc << 2]);
            const float4 w3v = *reinterpret_cast<const float4*>(&Ws[k + 3][tc << 2]);
            FMA_BLOCK
        }
    }

    int c0 = (cb << 6) + (tc << 2);
    float4 bcv = *reinterpret_cast<const float4*>(&bc[c0]);
    float4 bnv = *reinterpret_cast<const float4*>(&bn_b[c0]);
#pragma unroll
    for (int i = 0; i < 3; ++i) {
        int gr = r0 + tr3 + i;
        if (gr < MS) {
            float f = hasE[inv[smp[gr]]];
            float v0 = fmaxf(acc[i][0] + bcv.x + f * bnv.x, 0.f);
            float v1 = fmaxf(acc[i][1] + bcv.y + f * bnv.y, 0.f);
            float v2 = fmaxf(acc[i][2] + bcv.z + f * bnv.z, 0.f);
            float v3 = fmaxf(acc[i][3] + bcv.w + f * bnv.w, 0.f);
            *reinterpret_cast<float4*>(&sx[gr * HD + c0]) = make_float4(v0, v1, v2, v3);
        }
    }
}

// ---------------- K8b: p3 = sx@Wco128, sp = pts[smp] ----------------
__launch_bounds__(256)
__global__ void p3_kernel(const float* __restrict__ sx, const float* __restrict__ Wco128,
                          const int* __restrict__ smp, const float* __restrict__ pts,
                          float* __restrict__ p3, float* __restrict__ sp) {
    int wid = threadIdx.x >> 6, lane = threadIdx.x & 63;
    int m = blockIdx.x * 4 + wid;
    if (m >= MS) return;
    int c0 = lane << 1;
    const float2 v = *reinterpret_cast<const float2*>(&sx[m * HD + c0]);
    float q0 = v.x * Wco128[c0 * 3]     + v.y * Wco128[(c0 + 1) * 3];
    float q1 = v.x * Wco128[c0 * 3 + 1] + v.y * Wco128[(c0 + 1) * 3 + 1];
    float q2 = v.x * Wco128[c0 * 3 + 2] + v.y * Wco128[(c0 + 1) * 3 + 2];
    q0 = wave_sum(q0); q1 = wave_sum(q1); q2 = wave_sum(q2);
    int d = smp[m];
    if (lane == 0) { p3[m * 3] = q0; p3[m * 3 + 1] = q1; p3[m * 3 + 2] = q2; }
    if (lane < 3) sp[m * 3 + lane] = pts[d * 3 + lane];
}

// ---------------- K9: attention + folded output tail ----------------
__launch_bounds__(256)
__global__ void attn_kernel(const float* __restrict__ qk, const int* __restrict__ nbr,
                            const float* __restrict__ p3, const float* __restrict__ sp,
                            const float* __restrict__ w3, const float* __restrict__ bco,
                            float* __restrict__ refined) {
    int wid = threadIdx.x >> 6, lane = threadIdx.x & 63;
    int m = blockIdx.x * 4 + wid;
    if (m >= MS) return;
    float ql = qk[m * HD + lane];
    int nbv[KN];
    float s[KN];
#pragma unroll
    for (int j = 0; j < KN; ++j) nbv[j] = nbr[m * KN + j];
#pragma unroll
    for (int j = 0; j < KN; ++j) {
        float t = ql * qk[nbv[j] * HD + 64 + lane];
        t = wave_sum(t);
        s[j] = (nbv[j] != 0) ? t * (1.f / 8.000001f) : 0.f;
    }
    float mx = s[0];
#pragma unroll
    for (int j = 1; j < KN; ++j) mx = fmaxf(mx, s[j]);
    float den = 0.f;
#pragma unroll
    for (int j = 0; j < KN; ++j) { s[j] = __expf(s[j] - mx); den += s[j]; }
    float invd = 1.f / den;
    float sp0 = sp[m * 3], sp1 = sp[m * 3 + 1], sp2 = sp[m * 3 + 2];
    float a0 = 0.f, a1 = 0.f, a2 = 0.f;
#pragma unroll
    for (int j = 0; j < KN; ++j) {
        int nb = nbv[j];
        float wgt = s[j] * invd;
        float r0 = sp[nb * 3] - sp0, r1 = sp[nb * 3 + 1] - sp1, r2 = sp[nb * 3 + 2] - sp2;
        float g0 = p3[nb * 3]     + r0 * w3[0] + r1 * w3[3] + r2 * w3[6];
        float g1 = p3[nb * 3 + 1] + r0 * w3[1] + r1 * w3[4] + r2 * w3[7];
        float g2 = p3[nb * 3 + 2] + r0 * w3[2] + r1 * w3[5] + r2 * w3[8];
        a0 = fmaf(wgt, g0, a0); a1 = fmaf(wgt, g1, a1); a2 = fmaf(wgt, g2, a2);
    }
    if (lane == 0) {
        refined[m * 3]     = sp0 + a0 + bco[0];
        refined[m * 3 + 1] = sp1 + a1 + bco[1];
        refined[m * 3 + 2] = sp2 + a2 + bco[2];
    }
}

// ---------------- launch ----------------
extern "C" void kernel_launch(void* const* d_in, const int* in_sizes, int n_in,
                              void* d_out, int out_size, void* d_ws, size_t ws_size,
                              hipStream_t stream) {
    const float* pts   = (const float*)d_in[0];
    const int*   ei    = (const int*)d_in[1];
    const int*   smp   = (const int*)d_in[2];
    const int*   nbr   = (const int*)d_in[3];
    const float* W1    = (const float*)d_in[4];
    const float* b1    = (const float*)d_in[5];
    const float* g1    = (const float*)d_in[6];
    const float* beta1 = (const float*)d_in[7];
    const float* W2    = (const float*)d_in[8];
    const float* b2    = (const float*)d_in[9];
    const float* g2    = (const float*)d_in[10];
    const float* beta2 = (const float*)d_in[11];
    const float* Wc    = (const float*)d_in[12];
    const float* bc    = (const float*)d_in[13];
    const float* Wn    = (const float*)d_in[14];
    const float* bn_b  = (const float*)d_in[15];
    const float* Wq    = (const float*)d_in[16];
    const float* bq    = (const float*)d_in[17];
    const float* Wk    = (const float*)d_in[18];
    const float* bk    = (const float*)d_in[19];
    const float* Wcat  = (const float*)d_in[20];
    const float* bcat  = (const float*)d_in[21];
    const float* Wout  = (const float*)d_in[22];
    const float* bout  = (const float*)d_in[23];
    (void)in_sizes; (void)n_in; (void)out_size; (void)ws_size;

    float* w = (float*)d_ws;
    size_t o = 0;
    float* y1     = w + o; o += 6400000;
    float* y2     = w + o; o += 6400000;
    float* aggX   = w + o; o += 3200000;
    float* qkb    = w + o; o += 3200000;
    float* psum   = w + o; o += 262144;
    float* psq    = w + o; o += 262144;
    float* tp1    = w + o; o += 256;
    float* tp2    = w + o; o += 256;
    float* Wqk    = w + o; o += 16384;
    float* biasQK = w + o; o += 128;
    float* WcWn   = w + o; o += 32768;
    float* Wco128 = w + o; o += 384;
    float* w3     = w + o; o += 16;
    float* bco    = w + o; o += 16;
    float* p3     = w + o; o += 75008;
    float* sp     = w + o; o += 75008;
    float* hasE   = w + o; o += 25008;
    int* ip    = (int*)(w + o);
    int* inv   = ip;            ip += NPTS;
    int* cnt   = ip;            ip += MS;
    int* cursor= ip;            ip += MS;
    int* offs  = ip;            ip += MS + 4;
    int* elist = ip;

    float* refined = (float*)d_out;
    float* sx      = (float*)d_out + 75000;

    prep_kernel<<<292, 256, 0, stream>>>(Wq, bq, Wk, bk, Wcat, bcat, Wout, bout, Wc, Wn,
                                         Wqk, biasQK, WcWn, Wco128, w3, bco);
    lin1_kernel<<<1000, 256, 0, stream>>>(pts, W1, b1, y1, psum, psq);
    bn_fin_par<<<128, 256, 0, stream>>>(psum, psq, 2000, g1, beta1, tp1);
    gemm_bn<true, true><<<2084, 256, 0, stream>>>(y1, NPTS, W2, b2, tp1, y2, psum, psq);
    bn_fin_par<<<128, 256, 0, stream>>>(psum, psq, 1042, g2, beta2, tp2);
    init_kernel<<<196, 256, 0, stream>>>(inv, cnt, cursor);
    invset_kernel<<<98, 256, 0, stream>>>(smp, inv);
    count_kernel<<<3125, 256, 0, stream>>>(ei, inv, cnt);
    scan_kernel<<<1, 1024, 0, stream>>>(cnt, offs);
    scatter_kernel<<<3125, 256, 0, stream>>>(ei, inv, offs, cursor, elist);
    agg_kernel<<<6250, 256, 0, stream>>>(smp, inv, offs, elist, y2, tp2, aggX, hasE);
    gemm_sx<<<1042, 256, 0, stream>>>(y2, aggX, hasE, smp, inv, WcWn, bc, bn_b, tp2, sx);
    p3_kernel<<<6250, 256, 0, stream>>>(sx, Wco128, smp, pts, p3, sp);
    gemm_bn<false, false><<<1042, 256, 0, stream>>>(sx, MS, Wqk, biasQK, nullptr, qkb,
                                                    nullptr, nullptr);
    attn_kernel<<<6250, 256, 0, stream>>>(qkb, nbr, p3, sp, w3, bco, refined);
}

// Round 7
// 334.553 us; speedup vs baseline: 2.7500x; 1.0092x over previous
//
#include <hip/hip_runtime.h>
#include <climits>

#define NPTS 50000
#define NE   800000
#define MS   25000
#define KN   15
#define HD   128

// ---------------- helpers ----------------
__device__ __forceinline__ float wave_sum(float v) {
#pragma unroll
    for (int o = 32; o > 0; o >>= 1) v += __shfl_xor(v, o, 64);
    return v;
}

// ---------------- K0: prep (weight packs + folds) + init of inv/cnt/cursor ----------------
// blocks [0,64): Wqk ; [64,192): WcWn ; 192: biasQK ; [193,293): Wcat@Wout fold ;
// [293,489): init inv/cnt/cursor
__launch_bounds__(256)
__global__ void prep_kernel(const float* __restrict__ Wq, const float* __restrict__ bq,
                            const float* __restrict__ Wk, const float* __restrict__ bk,
                            const float* __restrict__ Wcat, const float* __restrict__ bcat,
                            const float* __restrict__ Wout, const float* __restrict__ bout,
                            const float* __restrict__ Wc, const float* __restrict__ Wn,
                            float* __restrict__ Wqk, float* __restrict__ biasQK,
                            float* __restrict__ WcWn,
                            float* __restrict__ Wco128, float* __restrict__ w3, float* __restrict__ bco,
                            int* __restrict__ inv, int* __restrict__ cnt, int* __restrict__ cursor) {
    int b = blockIdx.x, tid = threadIdx.x;
    if (b < 64) {
        int i = b * 256 + tid;
        int k = i >> 7, c = i & 127;
        Wqk[i] = (c < 64) ? Wq[k * 64 + c] : Wk[k * 64 + (c - 64)];
    } else if (b < 192) {
        int i = (b - 64) * 256 + tid;
        int k = i >> 7, c = i & 127;
        WcWn[i] = (k < 128) ? Wc[k * 128 + c] : Wn[(k - 128) * 128 + c];
    } else if (b == 192) {
        if (tid < 128) biasQK[tid] = (tid < 64) ? bq[tid] : bk[tid - 64];
    } else if (b < 293) {               // fold: one output per wave
        int wid = tid >> 6, lane = tid & 63;
        int out = (b - 193) * 4 + wid;  // 0..399
        if (out < 396) {
            int r = out / 3, j = out - r * 3;   // r==131 -> bco row
            const float* src = (r < 131) ? &Wcat[r * 131] : bcat;
            float s = 0.f;
            s = fmaf(src[lane], Wout[lane * 3 + j], s);
            s = fmaf(src[lane + 64], Wout[(lane + 64) * 3 + j], s);
            if (lane < 3) s = fmaf(src[lane + 128], Wout[(lane + 128) * 3 + j], s);
            s = wave_sum(s);
            if (lane == 0) {
                if (r < 128) Wco128[r * 3 + j] = s;
                else if (r < 131) w3[(r - 128) * 3 + j] = s;
                else bco[j] = s + bout[j];
            }
        }
    } else {                            // init
        int i = (b - 293) * 256 + tid;
        if (i < NPTS) inv[i] = INT_MAX;
        if (i < MS) { cnt[i] = 0; cursor[i] = 0; }
    }
}

// ---------------- K1: y1 = points@W1 + b1 with stats partials; tail blocks do invset ----------------
__launch_bounds__(256)
__global__ void lin1_kernel(const float* __restrict__ pts, const float* __restrict__ W1,
                            const float* __restrict__ b1, float* __restrict__ y1,
                            float* __restrict__ psum, float* __restrict__ psq,
                            const int* __restrict__ smp, int* __restrict__ inv) {
    if (blockIdx.x >= 1000) {           // invset tail: representative map
        int m = (blockIdx.x - 1000) * 256 + threadIdx.x;
        if (m < MS) atomicMin(&inv[smp[m]], m);
        return;
    }
    int c = threadIdx.x & 127;
    int half = threadIdx.x >> 7;
    int part = blockIdx.x * 2 + half;   // 0..1999
    float w0 = W1[c], w1 = W1[128 + c], w2 = W1[256 + c], bb = b1[c];
    float s = 0.f, s2 = 0.f;
    int r0 = part * 25, r1 = r0 + 25; if (r1 > NPTS) r1 = NPTS;
    for (int r = r0; r < r1; ++r) {
        float p0 = pts[r * 3], p1 = pts[r * 3 + 1], p2 = pts[r * 3 + 2];
        float y = fmaf(p0, w0, fmaf(p1, w1, fmaf(p2, w2, bb)));
        y1[r * HD + c] = y;
        s += y; s2 = fmaf(y, y, s2);
    }
    psum[part * 128 + c] = s;
    psq[part * 128 + c] = s2;
}

// ---------------- BN finalize (parallel): one block per column ----------------
__launch_bounds__(256)
__global__ void bn_fin_par(const float* __restrict__ psum, const float* __restrict__ psq, int nb,
                           const float* __restrict__ g, const float* __restrict__ beta,
                           float* __restrict__ tp) {
    int c = blockIdx.x;
    int t = threadIdx.x;
    float S = 0.f, S2 = 0.f;
    for (int b = t; b < nb; b += 256) {
        S += psum[b * 128 + c];
        S2 += psq[b * 128 + c];
    }
    S = wave_sum(S); S2 = wave_sum(S2);
    __shared__ float sA[4], sB[4];
    int wid = t >> 6, lane = t & 63;
    if (lane == 0) { sA[wid] = S; sB[wid] = S2; }
    __syncthreads();
    if (t == 0) {
        float Sa = sA[0] + sA[1] + sA[2] + sA[3];
        float Sb = sB[0] + sB[1] + sB[2] + sB[3];
        const float invN = 1.f / (float)NPTS;
        float mean = Sa * invN;
        float var = Sb * invN - mean * mean;
        float a = g[c] * rsqrtf(var + 1e-5f);
        tp[c] = a;
        tp[128 + c] = beta[c] - mean * a;
    }
}

// ---------------- GEMM [nrows,128]@[128,128], tile 48x128, K-chunk 64 (45 KB LDS) ----------------
// optional tail blocks (bid >= gemmBlocks) run edge-count atomics (overlap with GEMM)
template <bool TRANS, bool STATS, bool COUNT>
__launch_bounds__(256)
__global__ void gemm_bn(const float* __restrict__ A, int nrows, int gemmBlocks,
                        const float* __restrict__ W, const float* __restrict__ bias,
                        const float* __restrict__ tp,
                        float* __restrict__ Out,
                        float* __restrict__ psum, float* __restrict__ psq,
                        const int* __restrict__ ei, const int* __restrict__ inv,
                        int* __restrict__ cnt) {
    if (COUNT && (int)blockIdx.x >= gemmBlocks) {
        int e = ((int)blockIdx.x - gemmBlocks) * 256 + threadIdx.x;
        if (e < NE) {
            int mr = inv[ei[NE + e]];
            if (mr < MS) atomicAdd(&cnt[mr], 1);
        }
        return;
    }
    __shared__ float As[48][68];     // 13 KB
    __shared__ float Ws[64][128];    // 32 KB
    int tid = threadIdx.x;
    int r0 = blockIdx.x * 48;
    int tc = tid & 15, tr = tid >> 4;
    int tr3 = tr * 3, tc8 = tc << 3;
    float accA[3][4] = {}, accB[3][4] = {};

    for (int k0 = 0; k0 < 128; k0 += 64) {
        if (k0) __syncthreads();
        for (int i = tid; i < 48 * 16; i += 256) {
            int r = i >> 4, c4 = (i & 15) << 2;
            int gr = r0 + r;
            float4 v = make_float4(0.f, 0.f, 0.f, 0.f);
            if (gr < nrows) {
                v = *reinterpret_cast<const float4*>(&A[gr * HD + k0 + c4]);
                if (TRANS) {
                    int gc = k0 + c4;
                    v.x = fmaxf(fmaf(tp[gc],     v.x, tp[128 + gc]),     0.f);
                    v.y = fmaxf(fmaf(tp[gc + 1], v.y, tp[128 + gc + 1]), 0.f);
                    v.z = fmaxf(fmaf(tp[gc + 2], v.z, tp[128 + gc + 2]), 0.f);
                    v.w = fmaxf(fmaf(tp[gc + 3], v.w, tp[128 + gc + 3]), 0.f);
                }
            }
            *reinterpret_cast<float4*>(&As[r][c4]) = v;
        }
        for (int i = tid; i < 64 * 32; i += 256) {
            int k = i >> 5, c4 = (i & 31) << 2;
            *reinterpret_cast<float4*>(&Ws[k][c4]) =
                *reinterpret_cast<const float4*>(&W[(k0 + k) * 128 + c4]);
        }
        __syncthreads();
#pragma unroll 2
        for (int k = 0; k < 64; k += 4) {
            const float4 a0 = *reinterpret_cast<const float4*>(&As[tr3][k]);
            const float4 a1 = *reinterpret_cast<const float4*>(&As[tr3 + 1][k]);
            const float4 a2 = *reinterpret_cast<const float4*>(&As[tr3 + 2][k]);
            float a0v[4] = {a0.x, a0.y, a0.z, a0.w};
            float a1v[4] = {a1.x, a1.y, a1.z, a1.w};
            float a2v[4] = {a2.x, a2.y, a2.z, a2.w};
#pragma unroll
            for (int kk = 0; kk < 4; ++kk) {
                const float4 wlo = *reinterpret_cast<const float4*>(&Ws[k + kk][tc8]);
                const float4 whi = *reinterpret_cast<const float4*>(&Ws[k + kk][tc8 + 4]);
                float v0 = a0v[kk], v1 = a1v[kk], v2 = a2v[kk];
                accA[0][0] = fmaf(v0, wlo.x, accA[0][0]); accA[0][1] = fmaf(v0, wlo.y, accA[0][1]);
                accA[0][2] = fmaf(v0, wlo.z, accA[0][2]); accA[0][3] = fmaf(v0, wlo.w, accA[0][3]);
                accB[0][0] = fmaf(v0, whi.x, accB[0][0]); accB[0][1] = fmaf(v0, whi.y, accB[0][1]);
                accB[0][2] = fmaf(v0, whi.z, accB[0][2]); accB[0][3] = fmaf(v0, whi.w, accB[0][3]);
                accA[1][0] = fmaf(v1, wlo.x, accA[1][0]); accA[1][1] = fmaf(v1, wlo.y, accA[1][1]);
                accA[1][2] = fmaf(v1, wlo.z, accA[1][2]); accA[1][3] = fmaf(v1, wlo.w, accA[1][3]);
                accB[1][0] = fmaf(v1, whi.x, accB[1][0]); accB[1][1] = fmaf(v1, whi.y, accB[1][1]);
                accB[1][2] = fmaf(v1, whi.z, accB[1][2]); accB[1][3] = fmaf(v1, whi.w, accB[1][3]);
                accA[2][0] = fmaf(v2, wlo.x, accA[2][0]); accA[2][1] = fmaf(v2, wlo.y, accA[2][1]);
                accA[2][2] = fmaf(v2, wlo.z, accA[2][2]); accA[2][3] = fmaf(v2, wlo.w, accA[2][3]);
                accB[2][0] = fmaf(v2, whi.x, accB[2][0]); accB[2][1] = fmaf(v2, whi.y, accB[2][1]);
                accB[2][2] = fmaf(v2, whi.z, accB[2][2]); accB[2][3] = fmaf(v2, whi.w, accB[2][3]);
            }
        }
    }

    const float4 blo = *reinterpret_cast<const float4*>(&bias[tc8]);
    const float4 bhi = *reinterpret_cast<const float4*>(&bias[tc8 + 4]);
    float cs[8] = {}, cq[8] = {};
#pragma unroll
    for (int i = 0; i < 3; ++i) {
        int gr = r0 + tr3 + i;
        float o0 = accA[i][0] + blo.x, o1 = accA[i][1] + blo.y;
        float o2 = accA[i][2] + blo.z, o3 = accA[i][3] + blo.w;
        float o4 = accB[i][0] + bhi.x, o5 = accB[i][1] + bhi.y;
        float o6 = accB[i][2] + bhi.z, o7 = accB[i][3] + bhi.w;
        if (gr < nrows) {
            *reinterpret_cast<float4*>(&Out[gr * HD + tc8])     = make_float4(o0, o1, o2, o3);
            *reinterpret_cast<float4*>(&Out[gr * HD + tc8 + 4]) = make_float4(o4, o5, o6, o7);
            if (STATS) {
                cs[0] += o0; cs[1] += o1; cs[2] += o2; cs[3] += o3;
                cs[4] += o4; cs[5] += o5; cs[6] += o6; cs[7] += o7;
                cq[0] = fmaf(o0, o0, cq[0]); cq[1] = fmaf(o1, o1, cq[1]);
                cq[2] = fmaf(o2, o2, cq[2]); cq[3] = fmaf(o3, o3, cq[3]);
                cq[4] = fmaf(o4, o4, cq[4]); cq[5] = fmaf(o5, o5, cq[5]);
                cq[6] = fmaf(o6, o6, cq[6]); cq[7] = fmaf(o7, o7, cq[7]);
            }
        }
    }
    if (STATS) {
        float* red = &As[0][0];     // 8 KB scratch inside As
        __syncthreads();
        *reinterpret_cast<float4*>(&red[tr * 128 + tc8])     = make_float4(cs[0], cs[1], cs[2], cs[3]);
        *reinterpret_cast<float4*>(&red[tr * 128 + tc8 + 4]) = make_float4(cs[4], cs[5], cs[6], cs[7]);
        __syncthreads();
        if (tid < 128) {
            float s = 0.f;
            for (int t = 0; t < 16; ++t) s += red[t * 128 + tid];
            psum[blockIdx.x * 128 + tid] = s;
        }
        __syncthreads();
        *reinterpret_cast<float4*>(&red[tr * 128 + tc8])     = make_float4(cq[0], cq[1], cq[2], cq[3]);
        *reinterpret_cast<float4*>(&red[tr * 128 + tc8 + 4]) = make_float4(cq[4], cq[5], cq[6], cq[7]);
        __syncthreads();
        if (tid < 128) {
            float s = 0.f;
            for (int t = 0; t < 16; ++t) s += red[t * 128 + tid];
            psq[blockIdx.x * 128 + tid] = s;
        }
    }
}

// ---------------- scan over cnt[MS] -> offs ----------------
__launch_bounds__(1024)
__global__ void scan_kernel(const int* __restrict__ cnt, int* __restrict__ offs) {
    const int C = 25;
    __shared__ int buf[1024];
    int tid = threadIdx.x;
    int loc[C];
    int run = 0;
    int base = tid * C;
#pragma unroll
    for (int i = 0; i < C; ++i) {
        int idx = base + i;
        int v = (idx < MS) ? cnt[idx] : 0;
        loc[i] = run; run += v;
    }
    buf[tid] = run;
    __syncthreads();
    for (int off = 1; off < 1024; off <<= 1) {
        int t = (tid >= off) ? buf[tid - off] : 0;
        __syncthreads();
        buf[tid] += t;
        __syncthreads();
    }
    int excl = buf[tid] - run;
#pragma unroll
    for (int i = 0; i < C; ++i) {
        int idx = base + i;
        if (idx < MS) offs[idx] = excl + loc[i];
    }
    if (tid == 1023) offs[MS] = buf[tid];
}

__launch_bounds__(256)
__global__ void scatter_kernel(const int* __restrict__ ei, const int* __restrict__ inv,
                               const int* __restrict__ offs, int* __restrict__ cursor,
                               int* __restrict__ elist) {
    int e = blockIdx.x * 256 + threadIdx.x;
    if (e < NE) {
        int mr = inv[ei[NE + e]];
        if (mr < MS) {
            int pos = atomicAdd(&cursor[mr], 1);
            elist[offs[mr] + pos] = ei[e];
        }
    }
}

// ---------------- K7: rep-only gather-mean; 2 rows per instr (half-wave split), float4 ----------------
__launch_bounds__(256)
__global__ void agg_kernel(const int* __restrict__ smp, const int* __restrict__ inv,
                           const int* __restrict__ offs, const int* __restrict__ elist,
                           const float* __restrict__ y2, const float* __restrict__ tp2,
                           float* __restrict__ aggX, float* __restrict__ hasE) {
    int tid = threadIdx.x, wid = tid >> 6, lane = tid & 63;
    int m = blockIdx.x * 4 + wid;
    if (m >= MS) return;
    int d = smp[m];
    if (inv[d] != m) return;            // representatives only
    int half = lane >> 5, c0 = (lane & 31) << 2;
    const float4 ta = *reinterpret_cast<const float4*>(&tp2[c0]);
    const float4 tb = *reinterpret_cast<const float4*>(&tp2[128 + c0]);
    int e0 = offs[m], e1 = offs[m + 1];
    float4 s0 = {0,0,0,0}, s1 = {0,0,0,0}, s2 = {0,0,0,0}, s3 = {0,0,0,0};
    int e = e0;
    for (; e + 7 < e1; e += 8) {        // 4 loads x 2 rows each in flight
        float4 v[4];
#pragma unroll
        for (int u = 0; u < 4; ++u)
            v[u] = *reinterpret_cast<const float4*>(&y2[elist[e + 2 * u + half] * HD + c0]);
        s0.x += fmaxf(fmaf(ta.x, v[0].x, tb.x), 0.f); s0.y += fmaxf(fmaf(ta.y, v[0].y, tb.y), 0.f);
        s0.z += fmaxf(fmaf(ta.z, v[0].z, tb.z), 0.f); s0.w += fmaxf(fmaf(ta.w, v[0].w, tb.w), 0.f);
        s1.x += fmaxf(fmaf(ta.x, v[1].x, tb.x), 0.f); s1.y += fmaxf(fmaf(ta.y, v[1].y, tb.y), 0.f);
        s1.z += fmaxf(fmaf(ta.z, v[1].z, tb.z), 0.f); s1.w += fmaxf(fmaf(ta.w, v[1].w, tb.w), 0.f);
        s2.x += fmaxf(fmaf(ta.x, v[2].x, tb.x), 0.f); s2.y += fmaxf(fmaf(ta.y, v[2].y, tb.y), 0.f);
        s2.z += fmaxf(fmaf(ta.z, v[2].z, tb.z), 0.f); s2.w += fmaxf(fmaf(ta.w, v[2].w, tb.w), 0.f);
        s3.x += fmaxf(fmaf(ta.x, v[3].x, tb.x), 0.f); s3.y += fmaxf(fmaf(ta.y, v[3].y, tb.y), 0.f);
        s3.z += fmaxf(fmaf(ta.z, v[3].z, tb.z), 0.f); s3.w += fmaxf(fmaf(ta.w, v[3].w, tb.w), 0.f);
    }
    for (; e + 1 < e1; e += 2) {
        const float4 v = *reinterpret_cast<const float4*>(&y2[elist[e + half] * HD + c0]);
        s0.x += fmaxf(fmaf(ta.x, v.x, tb.x), 0.f); s0.y += fmaxf(fmaf(ta.y, v.y, tb.y), 0.f);
        s0.z += fmaxf(fmaf(ta.z, v.z, tb.z), 0.f); s0.w += fmaxf(fmaf(ta.w, v.w, tb.w), 0.f);
    }
    if (e < e1 && half == 0) {          // odd tail: half0 only
        const float4 v = *reinterpret_cast<const float4*>(&y2[elist[e] * HD + c0]);
        s1.x += fmaxf(fmaf(ta.x, v.x, tb.x), 0.f); s1.y += fmaxf(fmaf(ta.y, v.y, tb.y), 0.f);
        s1.z += fmaxf(fmaf(ta.z, v.z, tb.z), 0.f); s1.w += fmaxf(fmaf(ta.w, v.w, tb.w), 0.f);
    }
    float tx = (s0.x + s1.x) + (s2.x + s3.x);
    float ty = (s0.y + s1.y) + (s2.y + s3.y);
    float tz = (s0.z + s1.z) + (s2.z + s3.z);
    float tw = (s0.w + s1.w) + (s2.w + s3.w);
    tx += __shfl_xor(tx, 32, 64); ty += __shfl_xor(ty, 32, 64);
    tz += __shfl_xor(tz, 32, 64); tw += __shfl_xor(tw, 32, 64);
    float rs = 1.f / fmaxf((float)(e1 - e0), 1.f);
    if (half == 0)
        *reinterpret_cast<float4*>(&aggX[m * HD + c0]) = make_float4(tx * rs, ty * rs, tz * rs, tw * rs);
    if (lane == 0) hasE[m] = (e1 > e0) ? 1.f : 0.f;
}

// ---------------- K8: sx = relu([bnrelu(y2[smp]) | aggX[mr]] @ [Wc;Wn] + bc + f*bn_b), 48x128 ----------------
__launch_bounds__(256)
__global__ void gemm_sx(const float* __restrict__ y2, const float* __restrict__ aggX,
                        const float* __restrict__ hasE,
                        const int* __restrict__ smp, const int* __restrict__ inv,
                        const float* __restrict__ WcWn,
                        const float* __restrict__ bc, const float* __restrict__ bn_b,
                        const float* __restrict__ tp2,
                        float* __restrict__ sx) {
    __shared__ float As[48][68];
    __shared__ float Ws[64][128];
    int tid = threadIdx.x;
    int r0 = blockIdx.x * 48;
    int tc = tid & 15, tr = tid >> 4;
    int tr3 = tr * 3, tc8 = tc << 3;
    float accA[3][4] = {}, accB[3][4] = {};

    for (int kk = 0; kk < 4; ++kk) {    // K = 256 in chunks of 64
        if (kk) __syncthreads();
        for (int i = tid; i < 48 * 16; i += 256) {
            int r = i >> 4, c4 = (i & 15) << 2;
            int gr = r0 + r;
            float4 v = make_float4(0.f, 0.f, 0.f, 0.f);
            if (gr < MS) {
                int d = smp[gr];
                if (kk < 2) {
                    int gc = (kk << 6) + c4;
                    v = *reinterpret_cast<const float4*>(&y2[d * HD + gc]);
                    v.x = fmaxf(fmaf(tp2[gc],     v.x, tp2[128 + gc]),     0.f);
                    v.y = fmaxf(fmaf(tp2[gc + 1], v.y, tp2[128 + gc + 1]), 0.f);
                    v.z = fmaxf(fmaf(tp2[gc + 2], v.z, tp2[128 + gc + 2]), 0.f);
                    v.w = fmaxf(fmaf(tp2[gc + 3], v.w, tp2[128 + gc + 3]), 0.f);
                } else {
                    v = *reinterpret_cast<const float4*>(&aggX[inv[d] * HD + ((kk - 2) << 6) + c4]);
                }
            }
            *reinterpret_cast<float4*>(&As[r][c4]) = v;
        }
        for (int i = tid; i < 64 * 32; i += 256) {
            int k = i >> 5, c4 = (i & 31) << 2;
            *reinterpret_cast<float4*>(&Ws[k][c4]) =
                *reinterpret_cast<const float4*>(&WcWn[((kk << 6) + k) * 128 + c4]);
        }
        __syncthreads();
#pragma unroll 2
        for (int k = 0; k < 64; k += 4) {
            const float4 a0 = *reinterpret_cast<const float4*>(&As[tr3][k]);
            const float4 a1 = *reinterpret_cast<const float4*>(&As[tr3 + 1][k]);
            const float4 a2 = *reinterpret_cast<const float4*>(&As[tr3 + 2][k]);
            float a0v[4] = {a0.x, a0.y, a0.z, a0.w};
            float a1v[4] = {a1.x, a1.y, a1.z, a1.w};
            float a2v[4] = {a2.x, a2.y, a2.z, a2.w};
#pragma unroll
            for (int kq = 0; kq < 4; ++kq) {
                const float4 wlo = *reinterpret_cast<const float4*>(&Ws[k + kq][tc8]);
                const float4 whi = *reinterpret_cast<const float4*>(&Ws[k + kq][tc8 + 4]);
                float v0 = a0v[kq], v1 = a1v[kq], v2 = a2v[kq];
                accA[0][0] = fmaf(v0, wlo.x, accA[0][0]); accA[0][1] = fmaf(v0, wlo.y, accA[0][1]);
                accA[0][2] = fmaf(v0, wlo.z, accA[0][2]); accA[0][3] = fmaf(v0, wlo.w, accA[0][3]);
                accB[0][0] = fmaf(v0, whi.x, accB[0][0]); accB[0][1] = fmaf(v0, whi.y, accB[0][1]);
                accB[0][2] = fmaf(v0, whi.z, accB[0][2]); accB[0][3] = fmaf(v0, whi.w, accB[0][3]);
                accA[1][0] = fmaf(v1, wlo.x, accA[1][0]); accA[1][1] = fmaf(v1, wlo.y, accA[1][1]);
                accA[1][2] = fmaf(v1, wlo.z, accA[1][2]); accA[1][3] = fmaf(v1, wlo.w, accA[1][3]);
                accB[1][0] = fmaf(v1, whi.x, accB[1][0]); accB[1][1] = fmaf(v1, whi.y, accB[1][1]);
                accB[1][2] = fmaf(v1, whi.z, accB[1][2]); accB[1][3] = fmaf(v1, whi.w, accB[1][3]);
                accA[2][0] = fmaf(v2, wlo.x, accA[2][0]); accA[2][1] = fmaf(v2, wlo.y, accA[2][1]);
                accA[2][2] = fmaf(v2, wlo.z, accA[2][2]); accA[2][3] = fmaf(v2, wlo.w, accA[2][3]);
                accB[2][0] = fmaf(v2, whi.x, accB[2][0]); accB[2][1] = fmaf(v2, whi.y, accB[2][1]);
                accB[2][2] = fmaf(v2, whi.z, accB[2][2]); accB[2][3] = fmaf(v2, whi.w, accB[2][3]);
            }
        }
    }

    const float4 bclo = *reinterpret_cast<const float4*>(&bc[tc8]);
    const float4 bchi = *reinterpret_cast<const float4*>(&bc[tc8 + 4]);
    const float4 bnlo = *reinterpret_cast<const float4*>(&bn_b[tc8]);
    const float4 bnhi = *reinterpret_cast<const float4*>(&bn_b[tc8 + 4]);
#pragma unroll
    for (int i = 0; i < 3; ++i) {
        int gr = r0 + tr3 + i;
        if (gr < MS) {
            float f = hasE[inv[smp[gr]]];
            float o0 = fmaxf(accA[i][0] + bclo.x + f * bnlo.x, 0.f);
            float o1 = fmaxf(accA[i][1] + bclo.y + f * bnlo.y, 0.f);
            float o2 = fmaxf(accA[i][2] + bclo.z + f * bnlo.z, 0.f);
            float o3 = fmaxf(accA[i][3] + bclo.w + f * bnlo.w, 0.f);
            float o4 = fmaxf(accB[i][0] + bchi.x + f * bnhi.x, 0.f);
            float o5 = fmaxf(accB[i][1] + bchi.y + f * bnhi.y, 0.f);
            float o6 = fmaxf(accB[i][2] + bchi.z + f * bnhi.z, 0.f);
            float o7 = fmaxf(accB[i][3] + bchi.w + f * bnhi.w, 0.f);
            *reinterpret_cast<float4*>(&sx[gr * HD + tc8])     = make_float4(o0, o1, o2, o3);
            *reinterpret_cast<float4*>(&sx[gr * HD + tc8 + 4]) = make_float4(o4, o5, o6, o7);
        }
    }
}

// ---------------- K8b: p3 = sx@Wco128, sp = pts[smp] ----------------
__launch_bounds__(256)
__global__ void p3_kernel(const float* __restrict__ sx, const float* __restrict__ Wco128,
                          const int* __restrict__ smp, const float* __restrict__ pts,
                          float* __restrict__ p3, float* __restrict__ sp) {
    int wid = threadIdx.x >> 6, lane = threadIdx.x & 63;
    int m = blockIdx.x * 4 + wid;
    if (m >= MS) return;
    int c0 = lane << 1;
    const float2 v = *reinterpret_cast<const float2*>(&sx[m * HD + c0]);
    float q0 = v.x * Wco128[c0 * 3]     + v.y * Wco128[(c0 + 1) * 3];
    float q1 = v.x * Wco128[c0 * 3 + 1] + v.y * Wco128[(c0 + 1) * 3 + 1];
    float q2 = v.x * Wco128[c0 * 3 + 2] + v.y * Wco128[(c0 + 1) * 3 + 2];
    q0 = wave_sum(q0); q1 = wave_sum(q1); q2 = wave_sum(q2);
    int d = smp[m];
    if (lane == 0) { p3[m * 3] = q0; p3[m * 3 + 1] = q1; p3[m * 3 + 2] = q2; }
    if (lane < 3) sp[m * 3 + lane] = pts[d * 3 + lane];
}

// ---------------- K9: attention + folded output tail ----------------
__launch_bounds__(256)
__global__ void attn_kernel(const float* __restrict__ qk, const int* __restrict__ nbr,
                            const float* __restrict__ p3, const float* __restrict__ sp,
                            const float* __restrict__ w3, const float* __restrict__ bco,
                            float* __restrict__ refined) {
    int wid = threadIdx.x >> 6, lane = threadIdx.x & 63;
    int m = blockIdx.x * 4 + wid;
    if (m >= MS) return;
    float ql = qk[m * HD + lane];
    int nbv[KN];
    float s[KN];
#pragma unroll
    for (int j = 0; j < KN; ++j) nbv[j] = nbr[m * KN + j];
#pragma unroll
    for (int j = 0; j < KN; ++j) {
        float t = ql * qk[nbv[j] * HD + 64 + lane];
        t = wave_sum(t);
        s[j] = (nbv[j] != 0) ? t * (1.f / 8.000001f) : 0.f;
    }
    float mx = s[0];
#pragma unroll
    for (int j = 1; j < KN; ++j) mx = fmaxf(mx, s[j]);
    float den = 0.f;
#pragma unroll
    for (int j = 0; j < KN; ++j) { s[j] = __expf(s[j] - mx); den += s[j]; }
    float invd = 1.f / den;
    float sp0 = sp[m * 3], sp1 = sp[m * 3 + 1], sp2 = sp[m * 3 + 2];
    float a0 = 0.f, a1 = 0.f, a2 = 0.f;
#pragma unroll
    for (int j = 0; j < KN; ++j) {
        int nb = nbv[j];
        float wgt = s[j] * invd;
        float r0 = sp[nb * 3] - sp0, r1 = sp[nb * 3 + 1] - sp1, r2 = sp[nb * 3 + 2] - sp2;
        float g0 = p3[nb * 3]     + r0 * w3[0] + r1 * w3[3] + r2 * w3[6];
        float g1 = p3[nb * 3 + 1] + r0 * w3[1] + r1 * w3[4] + r2 * w3[7];
        float g2 = p3[nb * 3 + 2] + r0 * w3[2] + r1 * w3[5] + r2 * w3[8];
        a0 = fmaf(wgt, g0, a0); a1 = fmaf(wgt, g1, a1); a2 = fmaf(wgt, g2, a2);
    }
    if (lane == 0) {
        refined[m * 3]     = sp0 + a0 + bco[0];
        refined[m * 3 + 1] = sp1 + a1 + bco[1];
        refined[m * 3 + 2] = sp2 + a2 + bco[2];
    }
}

// ---------------- launch ----------------
extern "C" void kernel_launch(void* const* d_in, const int* in_sizes, int n_in,
                              void* d_out, int out_size, void* d_ws, size_t ws_size,
                              hipStream_t stream) {
    const float* pts   = (const float*)d_in[0];
    const int*   ei    = (const int*)d_in[1];
    const int*   smp   = (const int*)d_in[2];
    const int*   nbr   = (const int*)d_in[3];
    const float* W1    = (const float*)d_in[4];
    const float* b1    = (const float*)d_in[5];
    const float* g1    = (const float*)d_in[6];
    const float* beta1 = (const float*)d_in[7];
    const float* W2    = (const float*)d_in[8];
    const float* b2    = (const float*)d_in[9];
    const float* g2    = (const float*)d_in[10];
    const float* beta2 = (const float*)d_in[11];
    const float* Wc    = (const float*)d_in[12];
    const float* bc    = (const float*)d_in[13];
    const float* Wn    = (const float*)d_in[14];
    const float* bn_b  = (const float*)d_in[15];
    const float* Wq    = (const float*)d_in[16];
    const float* bq    = (const float*)d_in[17];
    const float* Wk    = (const float*)d_in[18];
    const float* bk    = (const float*)d_in[19];
    const float* Wcat  = (const float*)d_in[20];
    const float* bcat  = (const float*)d_in[21];
    const float* Wout  = (const float*)d_in[22];
    const float* bout  = (const float*)d_in[23];
    (void)in_sizes; (void)n_in; (void)out_size; (void)ws_size;

    float* w = (float*)d_ws;
    size_t o = 0;
    float* y1     = w + o; o += 6400000;
    float* y2     = w + o; o += 6400000;
    float* aggX   = w + o; o += 3200000;
    float* qkb    = w + o; o += 3200000;
    float* psum   = w + o; o += 262144;
    float* psq    = w + o; o += 262144;
    float* tp1    = w + o; o += 256;
    float* tp2    = w + o; o += 256;
    float* Wqk    = w + o; o += 16384;
    float* biasQK = w + o; o += 128;
    float* WcWn   = w + o; o += 32768;
    float* Wco128 = w + o; o += 384;
    float* w3     = w + o; o += 16;
    float* bco    = w + o; o += 16;
    float* p3     = w + o; o += 75008;
    float* sp     = w + o; o += 75008;
    float* hasE   = w + o; o += 25008;
    int* ip    = (int*)(w + o);
    int* inv   = ip;            ip += NPTS;
    int* cnt   = ip;            ip += MS;
    int* cursor= ip;            ip += MS;
    int* offs  = ip;            ip += MS + 4;
    int* elist = ip;

    float* refined = (float*)d_out;
    float* sx      = (float*)d_out + 75000;

    prep_kernel<<<489, 256, 0, stream>>>(Wq, bq, Wk, bk, Wcat, bcat, Wout, bout, Wc, Wn,
                                         Wqk, biasQK, WcWn, Wco128, w3, bco,
                                         inv, cnt, cursor);
    lin1_kernel<<<1098, 256, 0, stream>>>(pts, W1, b1, y1, psum, psq, smp, inv);
    bn_fin_par<<<128, 256, 0, stream>>>(psum, psq, 2000, g1, beta1, tp1);
    gemm_bn<true, true, true><<<1042 + 3125, 256, 0, stream>>>(
        y1, NPTS, 1042, W2, b2, tp1, y2, psum, psq, ei, inv, cnt);
    bn_fin_par<<<128, 256, 0, stream>>>(psum, psq, 1042, g2, beta2, tp2);
    scan_kernel<<<1, 1024, 0, stream>>>(cnt, offs);
    scatter_kernel<<<3125, 256, 0, stream>>>(ei, inv, offs, cursor, elist);
    agg_kernel<<<6250, 256, 0, stream>>>(smp, inv, offs, elist, y2, tp2, aggX, hasE);
    gemm_sx<<<521, 256, 0, stream>>>(y2, aggX, hasE, smp, inv, WcWn, bc, bn_b, tp2, sx);
    p3_kernel<<<6250, 256, 0, stream>>>(sx, Wco128, smp, pts, p3, sp);
    gemm_bn<false, false, false><<<521, 256, 0, stream>>>(
        sx, MS, 521, Wqk, biasQK, nullptr, qkb, nullptr, nullptr, nullptr, nullptr, nullptr);
    attn_kernel<<<6250, 256, 0, stream>>>(qkb, nbr, p3, sp, w3, bco, refined);
}

// Round 8
// 326.639 us; speedup vs baseline: 2.8166x; 1.0242x over previous
//
#include <hip/hip_runtime.h>
#include <climits>

#define NPTS 50000
#define NE   800000
#define MS   25000
#define KN   15
#define HD   128

// ---------------- helpers ----------------
__device__ __forceinline__ float wave_sum(float v) {
#pragma unroll
    for (int o = 32; o > 0; o >>= 1) v += __shfl_xor(v, o, 64);
    return v;
}

// ---------------- K0: prep (weight packs + folds) + init of inv/cnt/cursor ----------------
__launch_bounds__(256)
__global__ void prep_kernel(const float* __restrict__ Wq, const float* __restrict__ bq,
                            const float* __restrict__ Wk, const float* __restrict__ bk,
                            const float* __restrict__ Wcat, const float* __restrict__ bcat,
                            const float* __restrict__ Wout, const float* __restrict__ bout,
                            const float* __restrict__ Wc, const float* __restrict__ Wn,
                            float* __restrict__ Wqk, float* __restrict__ biasQK,
                            float* __restrict__ WcWn,
                            float* __restrict__ Wco128, float* __restrict__ w3, float* __restrict__ bco,
                            int* __restrict__ inv, int* __restrict__ cnt, int* __restrict__ cursor) {
    int b = blockIdx.x, tid = threadIdx.x;
    if (b < 64) {
        int i = b * 256 + tid;
        int k = i >> 7, c = i & 127;
        Wqk[i] = (c < 64) ? Wq[k * 64 + c] : Wk[k * 64 + (c - 64)];
    } else if (b < 192) {
        int i = (b - 64) * 256 + tid;
        int k = i >> 7, c = i & 127;
        WcWn[i] = (k < 128) ? Wc[k * 128 + c] : Wn[(k - 128) * 128 + c];
    } else if (b == 192) {
        if (tid < 128) biasQK[tid] = (tid < 64) ? bq[tid] : bk[tid - 64];
    } else if (b < 293) {               // fold: one output per wave
        int wid = tid >> 6, lane = tid & 63;
        int out = (b - 193) * 4 + wid;  // 0..399
        if (out < 396) {
            int r = out / 3, j = out - r * 3;   // r==131 -> bco row
            const float* src = (r < 131) ? &Wcat[r * 131] : bcat;
            float s = 0.f;
            s = fmaf(src[lane], Wout[lane * 3 + j], s);
            s = fmaf(src[lane + 64], Wout[(lane + 64) * 3 + j], s);
            if (lane < 3) s = fmaf(src[lane + 128], Wout[(lane + 128) * 3 + j], s);
            s = wave_sum(s);
            if (lane == 0) {
                if (r < 128) Wco128[r * 3 + j] = s;
                else if (r < 131) w3[(r - 128) * 3 + j] = s;
                else bco[j] = s + bout[j];
            }
        }
    } else {                            // init
        int i = (b - 293) * 256 + tid;
        if (i < NPTS) inv[i] = INT_MAX;
        if (i < MS) { cnt[i] = 0; cursor[i] = 0; }
    }
}

// ---------------- K1: y1 = points@W1 + b1 with stats partials; tail blocks do invset ----------------
__launch_bounds__(256)
__global__ void lin1_kernel(const float* __restrict__ pts, const float* __restrict__ W1,
                            const float* __restrict__ b1, float* __restrict__ y1,
                            float* __restrict__ psum, float* __restrict__ psq,
                            const int* __restrict__ smp, int* __restrict__ inv) {
    if (blockIdx.x >= 1000) {           // invset tail: representative map
        int m = (blockIdx.x - 1000) * 256 + threadIdx.x;
        if (m < MS) atomicMin(&inv[smp[m]], m);
        return;
    }
    int c = threadIdx.x & 127;
    int half = threadIdx.x >> 7;
    int part = blockIdx.x * 2 + half;   // 0..1999
    float w0 = W1[c], w1 = W1[128 + c], w2 = W1[256 + c], bb = b1[c];
    float s = 0.f, s2 = 0.f;
    int r0 = part * 25, r1 = r0 + 25; if (r1 > NPTS) r1 = NPTS;
    for (int r = r0; r < r1; ++r) {
        float p0 = pts[r * 3], p1 = pts[r * 3 + 1], p2 = pts[r * 3 + 2];
        float y = fmaf(p0, w0, fmaf(p1, w1, fmaf(p2, w2, bb)));
        y1[r * HD + c] = y;
        s += y; s2 = fmaf(y, y, s2);
    }
    psum[part * 128 + c] = s;
    psq[part * 128 + c] = s2;
}

// ---------------- BN finalize (parallel): one block per column ----------------
__launch_bounds__(256)
__global__ void bn_fin_par(const float* __restrict__ psum, const float* __restrict__ psq, int nb,
                           const float* __restrict__ g, const float* __restrict__ beta,
                           float* __restrict__ tp) {
    int c = blockIdx.x;
    int t = threadIdx.x;
    float S = 0.f, S2 = 0.f;
    for (int b = t; b < nb; b += 256) {
        S += psum[b * 128 + c];
        S2 += psq[b * 128 + c];
    }
    S = wave_sum(S); S2 = wave_sum(S2);
    __shared__ float sA[4], sB[4];
    int wid = t >> 6, lane = t & 63;
    if (lane == 0) { sA[wid] = S; sB[wid] = S2; }
    __syncthreads();
    if (t == 0) {
        float Sa = sA[0] + sA[1] + sA[2] + sA[3];
        float Sb = sB[0] + sB[1] + sB[2] + sB[3];
        const float invN = 1.f / (float)NPTS;
        float mean = Sa * invN;
        float var = Sb * invN - mean * mean;
        float a = g[c] * rsqrtf(var + 1e-5f);
        tp[c] = a;
        tp[128 + c] = beta[c] - mean * a;
    }
}

// ---------------- GEMM [nrows,128]@[128,128], tile (8R)x128, conflict-free mapping ----------------
// tc = tid&31 owns cols 4tc..4tc+3 (stride-1 Ws reads, no bank conflict);
// tr = tid>>5 owns rows tr*R..tr*R+R-1.
// optional tail blocks (bid >= gemmBlocks) run edge-count atomics (overlap with GEMM)
template <int R, bool TRANS, bool STATS, bool COUNT>
__launch_bounds__(256)
__global__ void gemm_bn(const float* __restrict__ A, int nrows, int gemmBlocks,
                        const float* __restrict__ W, const float* __restrict__ bias,
                        const float* __restrict__ tp,
                        float* __restrict__ Out,
                        float* __restrict__ psum, float* __restrict__ psq,
                        const int* __restrict__ ei, const int* __restrict__ inv,
                        int* __restrict__ cnt) {
    if (COUNT && (int)blockIdx.x >= gemmBlocks) {
        int e = ((int)blockIdx.x - gemmBlocks) * 256 + threadIdx.x;
        if (e < NE) {
            int mr = inv[ei[NE + e]];
            if (mr < MS) atomicAdd(&cnt[mr], 1);
        }
        return;
    }
    const int ROWS = 8 * R;
    __shared__ float As[8 * R][68];
    __shared__ float Ws[64][128];    // 32 KB
    int tid = threadIdx.x;
    int r0 = blockIdx.x * ROWS;
    int tc = tid & 31, tr = tid >> 5;
    int trR = tr * R, c0 = tc << 2;
    float acc[R][4] = {};

    for (int k0 = 0; k0 < 128; k0 += 64) {
        if (k0) __syncthreads();
        for (int i = tid; i < ROWS * 16; i += 256) {
            int r = i >> 4, c4 = (i & 15) << 2;
            int gr = r0 + r;
            float4 v = make_float4(0.f, 0.f, 0.f, 0.f);
            if (gr < nrows) {
                v = *reinterpret_cast<const float4*>(&A[gr * HD + k0 + c4]);
                if (TRANS) {
                    int gc = k0 + c4;
                    v.x = fmaxf(fmaf(tp[gc],     v.x, tp[128 + gc]),     0.f);
                    v.y = fmaxf(fmaf(tp[gc + 1], v.y, tp[128 + gc + 1]), 0.f);
                    v.z = fmaxf(fmaf(tp[gc + 2], v.z, tp[128 + gc + 2]), 0.f);
                    v.w = fmaxf(fmaf(tp[gc + 3], v.w, tp[128 + gc + 3]), 0.f);
                }
            }
            *reinterpret_cast<float4*>(&As[r][c4]) = v;
        }
        for (int i = tid; i < 64 * 32; i += 256) {
            int k = i >> 5, c4 = (i & 31) << 2;
            *reinterpret_cast<float4*>(&Ws[k][c4]) =
                *reinterpret_cast<const float4*>(&W[(k0 + k) * 128 + c4]);
        }
        __syncthreads();
#pragma unroll 2
        for (int k = 0; k < 64; k += 4) {
            float4 a[R];
#pragma unroll
            for (int i = 0; i < R; ++i)
                a[i] = *reinterpret_cast<const float4*>(&As[trR + i][k]);
#pragma unroll
            for (int kk = 0; kk < 4; ++kk) {
                const float4 wv = *reinterpret_cast<const float4*>(&Ws[k + kk][c0]);
#pragma unroll
                for (int i = 0; i < R; ++i) {
                    float av = kk == 0 ? a[i].x : kk == 1 ? a[i].y : kk == 2 ? a[i].z : a[i].w;
                    acc[i][0] = fmaf(av, wv.x, acc[i][0]);
                    acc[i][1] = fmaf(av, wv.y, acc[i][1]);
                    acc[i][2] = fmaf(av, wv.z, acc[i][2]);
                    acc[i][3] = fmaf(av, wv.w, acc[i][3]);
                }
            }
        }
    }

    const float4 bv = *reinterpret_cast<const float4*>(&bias[c0]);
    float cs[4] = {}, cq[4] = {};
#pragma unroll
    for (int i = 0; i < R; ++i) {
        int gr = r0 + trR + i;
        float o0 = acc[i][0] + bv.x, o1 = acc[i][1] + bv.y;
        float o2 = acc[i][2] + bv.z, o3 = acc[i][3] + bv.w;
        if (gr < nrows) {
            *reinterpret_cast<float4*>(&Out[gr * HD + c0]) = make_float4(o0, o1, o2, o3);
            if (STATS) {
                cs[0] += o0; cs[1] += o1; cs[2] += o2; cs[3] += o3;
                cq[0] = fmaf(o0, o0, cq[0]); cq[1] = fmaf(o1, o1, cq[1]);
                cq[2] = fmaf(o2, o2, cq[2]); cq[3] = fmaf(o3, o3, cq[3]);
            }
        }
    }
    if (STATS) {
        float* red = &As[0][0];     // 4 KB scratch inside As
        __syncthreads();
        *reinterpret_cast<float4*>(&red[tr * 128 + c0]) = make_float4(cs[0], cs[1], cs[2], cs[3]);
        __syncthreads();
        if (tid < 128) {
            float s = 0.f;
#pragma unroll
            for (int t = 0; t < 8; ++t) s += red[t * 128 + tid];
            psum[blockIdx.x * 128 + tid] = s;
        }
        __syncthreads();
        *reinterpret_cast<float4*>(&red[tr * 128 + c0]) = make_float4(cq[0], cq[1], cq[2], cq[3]);
        __syncthreads();
        if (tid < 128) {
            float s = 0.f;
#pragma unroll
            for (int t = 0; t < 8; ++t) s += red[t * 128 + tid];
            psq[blockIdx.x * 128 + tid] = s;
        }
    }
}

// ---------------- scan over cnt[MS] -> offs ----------------
__launch_bounds__(1024)
__global__ void scan_kernel(const int* __restrict__ cnt, int* __restrict__ offs) {
    const int C = 25;
    __shared__ int buf[1024];
    int tid = threadIdx.x;
    int loc[C];
    int run = 0;
    int base = tid * C;
#pragma unroll
    for (int i = 0; i < C; ++i) {
        int idx = base + i;
        int v = (idx < MS) ? cnt[idx] : 0;
        loc[i] = run; run += v;
    }
    buf[tid] = run;
    __syncthreads();
    for (int off = 1; off < 1024; off <<= 1) {
        int t = (tid >= off) ? buf[tid - off] : 0;
        __syncthreads();
        buf[tid] += t;
        __syncthreads();
    }
    int excl = buf[tid] - run;
#pragma unroll
    for (int i = 0; i < C; ++i) {
        int idx = base + i;
        if (idx < MS) offs[idx] = excl + loc[i];
    }
    if (tid == 1023) offs[MS] = buf[tid];
}

__launch_bounds__(256)
__global__ void scatter_kernel(const int* __restrict__ ei, const int* __restrict__ inv,
                               const int* __restrict__ offs, int* __restrict__ cursor,
                               int* __restrict__ elist) {
    int e = blockIdx.x * 256 + threadIdx.x;
    if (e < NE) {
        int mr = inv[ei[NE + e]];
        if (mr < MS) {
            int pos = atomicAdd(&cursor[mr], 1);
            elist[offs[mr] + pos] = ei[e];
        }
    }
}

// ---------------- K7: rep-only gather-mean; 2 rows per instr (half-wave split), float4 ----------------
__launch_bounds__(256)
__global__ void agg_kernel(const int* __restrict__ smp, const int* __restrict__ inv,
                           const int* __restrict__ offs, const int* __restrict__ elist,
                           const float* __restrict__ y2, const float* __restrict__ tp2,
                           float* __restrict__ aggX, float* __restrict__ hasE) {
    int tid = threadIdx.x, wid = tid >> 6, lane = tid & 63;
    int m = blockIdx.x * 4 + wid;
    if (m >= MS) return;
    int d = smp[m];
    if (inv[d] != m) return;            // representatives only
    int half = lane >> 5, c0 = (lane & 31) << 2;
    const float4 ta = *reinterpret_cast<const float4*>(&tp2[c0]);
    const float4 tb = *reinterpret_cast<const float4*>(&tp2[128 + c0]);
    int e0 = offs[m], e1 = offs[m + 1];
    float4 s0 = {0,0,0,0}, s1 = {0,0,0,0}, s2 = {0,0,0,0}, s3 = {0,0,0,0};
    int e = e0;
    for (; e + 7 < e1; e += 8) {        // 4 loads x 2 rows each in flight
        float4 v[4];
#pragma unroll
        for (int u = 0; u < 4; ++u)
            v[u] = *reinterpret_cast<const float4*>(&y2[elist[e + 2 * u + half] * HD + c0]);
        s0.x += fmaxf(fmaf(ta.x, v[0].x, tb.x), 0.f); s0.y += fmaxf(fmaf(ta.y, v[0].y, tb.y), 0.f);
        s0.z += fmaxf(fmaf(ta.z, v[0].z, tb.z), 0.f); s0.w += fmaxf(fmaf(ta.w, v[0].w, tb.w), 0.f);
        s1.x += fmaxf(fmaf(ta.x, v[1].x, tb.x), 0.f); s1.y += fmaxf(fmaf(ta.y, v[1].y, tb.y), 0.f);
        s1.z += fmaxf(fmaf(ta.z, v[1].z, tb.z), 0.f); s1.w += fmaxf(fmaf(ta.w, v[1].w, tb.w), 0.f);
        s2.x += fmaxf(fmaf(ta.x, v[2].x, tb.x), 0.f); s2.y += fmaxf(fmaf(ta.y, v[2].y, tb.y), 0.f);
        s2.z += fmaxf(fmaf(ta.z, v[2].z, tb.z), 0.f); s2.w += fmaxf(fmaf(ta.w, v[2].w, tb.w), 0.f);
        s3.x += fmaxf(fmaf(ta.x, v[3].x, tb.x), 0.f); s3.y += fmaxf(fmaf(ta.y, v[3].y, tb.y), 0.f);
        s3.z += fmaxf(fmaf(ta.z, v[3].z, tb.z), 0.f); s3.w += fmaxf(fmaf(ta.w, v[3].w, tb.w), 0.f);
    }
    for (; e + 1 < e1; e += 2) {
        const float4 v = *reinterpret_cast<const float4*>(&y2[elist[e + half] * HD + c0]);
        s0.x += fmaxf(fmaf(ta.x, v.x, tb.x), 0.f); s0.y += fmaxf(fmaf(ta.y, v.y, tb.y), 0.f);
        s0.z += fmaxf(fmaf(ta.z, v.z, tb.z), 0.f); s0.w += fmaxf(fmaf(ta.w, v.w, tb.w), 0.f);
    }
    if (e < e1 && half == 0) {          // odd tail: half0 only
        const float4 v = *reinterpret_cast<const float4*>(&y2[elist[e] * HD + c0]);
        s1.x += fmaxf(fmaf(ta.x, v.x, tb.x), 0.f); s1.y += fmaxf(fmaf(ta.y, v.y, tb.y), 0.f);
        s1.z += fmaxf(fmaf(ta.z, v.z, tb.z), 0.f); s1.w += fmaxf(fmaf(ta.w, v.w, tb.w), 0.f);
    }
    float tx = (s0.x + s1.x) + (s2.x + s3.x);
    float ty = (s0.y + s1.y) + (s2.y + s3.y);
    float tz = (s0.z + s1.z) + (s2.z + s3.z);
    float tw = (s0.w + s1.w) + (s2.w + s3.w);
    tx += __shfl_xor(tx, 32, 64); ty += __shfl_xor(ty, 32, 64);
    tz += __shfl_xor(tz, 32, 64); tw += __shfl_xor(tw, 32, 64);
    float rs = 1.f / fmaxf((float)(e1 - e0), 1.f);
    if (half == 0)
        *reinterpret_cast<float4*>(&aggX[m * HD + c0]) = make_float4(tx * rs, ty * rs, tz * rs, tw * rs);
    if (lane == 0) hasE[m] = (e1 > e0) ? 1.f : 0.f;
}

// ---------------- K8: sx = relu([bnrelu(y2[smp]) | aggX[mr]] @ [Wc;Wn] + bc + f*bn_b), 24x128 ----------------
__launch_bounds__(256)
__global__ void gemm_sx(const float* __restrict__ y2, const float* __restrict__ aggX,
                        const float* __restrict__ hasE,
                        const int* __restrict__ smp, const int* __restrict__ inv,
                        const float* __restrict__ WcWn,
                        const float* __restrict__ bc, const float* __restrict__ bn_b,
                        const float* __restrict__ tp2,
                        float* __restrict__ sx) {
    const int R = 3;
    __shared__ float As[24][68];
    __shared__ float Ws[64][128];
    int tid = threadIdx.x;
    int r0 = blockIdx.x * 24;
    int tc = tid & 31, tr = tid >> 5;
    int trR = tr * R, c0 = tc << 2;
    float acc[R][4] = {};

    for (int kk = 0; kk < 4; ++kk) {    // K = 256 in chunks of 64
        if (kk) __syncthreads();
        for (int i = tid; i < 24 * 16; i += 256) {
            int r = i >> 4, c4 = (i & 15) << 2;
            int gr = r0 + r;
            float4 v = make_float4(0.f, 0.f, 0.f, 0.f);
            if (gr < MS) {
                int d = smp[gr];
                if (kk < 2) {
                    int gc = (kk << 6) + c4;
                    v = *reinterpret_cast<const float4*>(&y2[d * HD + gc]);
                    v.x = fmaxf(fmaf(tp2[gc],     v.x, tp2[128 + gc]),     0.f);
                    v.y = fmaxf(fmaf(tp2[gc + 1], v.y, tp2[128 + gc + 1]), 0.f);
                    v.z = fmaxf(fmaf(tp2[gc + 2], v.z, tp2[128 + gc + 2]), 0.f);
                    v.w = fmaxf(fmaf(tp2[gc + 3], v.w, tp2[128 + gc + 3]), 0.f);
                } else {
                    v = *reinterpret_cast<const float4*>(&aggX[inv[d] * HD + ((kk - 2) << 6) + c4]);
                }
            }
            *reinterpret_cast<float4*>(&As[r][c4]) = v;
        }
        for (int i = tid; i < 64 * 32; i += 256) {
            int k = i >> 5, c4 = (i & 31) << 2;
            *reinterpret_cast<float4*>(&Ws[k][c4]) =
                *reinterpret_cast<const float4*>(&WcWn[((kk << 6) + k) * 128 + c4]);
        }
        __syncthreads();
#pragma unroll 2
        for (int k = 0; k < 64; k += 4) {
            float4 a[R];
#pragma unroll
            for (int i = 0; i < R; ++i)
                a[i] = *reinterpret_cast<const float4*>(&As[trR + i][k]);
#pragma unroll
            for (int kq = 0; kq < 4; ++kq) {
                const float4 wv = *reinterpret_cast<const float4*>(&Ws[k + kq][c0]);
#pragma unroll
                for (int i = 0; i < R; ++i) {
                    float av = kq == 0 ? a[i].x : kq == 1 ? a[i].y : kq == 2 ? a[i].z : a[i].w;
                    acc[i][0] = fmaf(av, wv.x, acc[i][0]);
                    acc[i][1] = fmaf(av, wv.y, acc[i][1]);
                    acc[i][2] = fmaf(av, wv.z, acc[i][2]);
                    acc[i][3] = fmaf(av, wv.w, acc[i][3]);
                }
            }
        }
    }

    const float4 bcv = *reinterpret_cast<const float4*>(&bc[c0]);
    const float4 bnv = *reinterpret_cast<const float4*>(&bn_b[c0]);
#pragma unroll
    for (int i = 0; i < R; ++i) {
        int gr = r0 + trR + i;
        if (gr < MS) {
            float f = hasE[inv[smp[gr]]];
            float o0 = fmaxf(acc[i][0] + bcv.x + f * bnv.x, 0.f);
            float o1 = fmaxf(acc[i][1] + bcv.y + f * bnv.y, 0.f);
            float o2 = fmaxf(acc[i][2] + bcv.z + f * bnv.z, 0.f);
            float o3 = fmaxf(acc[i][3] + bcv.w + f * bnv.w, 0.f);
            *reinterpret_cast<float4*>(&sx[gr * HD + c0]) = make_float4(o0, o1, o2, o3);
        }
    }
}

// ---------------- K8b: p3 = sx@Wco128, sp = pts[smp] ----------------
__launch_bounds__(256)
__global__ void p3_kernel(const float* __restrict__ sx, const float* __restrict__ Wco128,
                          const int* __restrict__ smp, const float* __restrict__ pts,
                          float* __restrict__ p3, float* __restrict__ sp) {
    int wid = threadIdx.x >> 6, lane = threadIdx.x & 63;
    int m = blockIdx.x * 4 + wid;
    if (m >= MS) return;
    int c0 = lane << 1;
    const float2 v = *reinterpret_cast<const float2*>(&sx[m * HD + c0]);
    float q0 = v.x * Wco128[c0 * 3]     + v.y * Wco128[(c0 + 1) * 3];
    float q1 = v.x * Wco128[c0 * 3 + 1] + v.y * Wco128[(c0 + 1) * 3 + 1];
    float q2 = v.x * Wco128[c0 * 3 + 2] + v.y * Wco128[(c0 + 1) * 3 + 2];
    q0 = wave_sum(q0); q1 = wave_sum(q1); q2 = wave_sum(q2);
    int d = smp[m];
    if (lane == 0) { p3[m * 3] = q0; p3[m * 3 + 1] = q1; p3[m * 3 + 2] = q2; }
    if (lane < 3) sp[m * 3 + lane] = pts[d * 3 + lane];
}

// ---------------- K9: attention + folded output tail ----------------
__launch_bounds__(256)
__global__ void attn_kernel(const float* __restrict__ qk, const int* __restrict__ nbr,
                            const float* __restrict__ p3, const float* __restrict__ sp,
                            const float* __restrict__ w3, const float* __restrict__ bco,
                            float* __restrict__ refined) {
    int wid = threadIdx.x >> 6, lane = threadIdx.x & 63;
    int m = blockIdx.x * 4 + wid;
    if (m >= MS) return;
    float ql = qk[m * HD + lane];
    int nbv[KN];
    float s[KN];
#pragma unroll
    for (int j = 0; j < KN; ++j) nbv[j] = nbr[m * KN + j];
#pragma unroll
    for (int j = 0; j < KN; ++j) {
        float t = ql * qk[nbv[j] * HD + 64 + lane];
        t = wave_sum(t);
        s[j] = (nbv[j] != 0) ? t * (1.f / 8.000001f) : 0.f;
    }
    float mx = s[0];
#pragma unroll
    for (int j = 1; j < KN; ++j) mx = fmaxf(mx, s[j]);
    float den = 0.f;
#pragma unroll
    for (int j = 0; j < KN; ++j) { s[j] = __expf(s[j] - mx); den += s[j]; }
    float invd = 1.f / den;
    float sp0 = sp[m * 3], sp1 = sp[m * 3 + 1], sp2 = sp[m * 3 + 2];
    float a0 = 0.f, a1 = 0.f, a2 = 0.f;
#pragma unroll
    for (int j = 0; j < KN; ++j) {
        int nb = nbv[j];
        float wgt = s[j] * invd;
        float r0 = sp[nb * 3] - sp0, r1 = sp[nb * 3 + 1] - sp1, r2 = sp[nb * 3 + 2] - sp2;
        float g0 = p3[nb * 3]     + r0 * w3[0] + r1 * w3[3] + r2 * w3[6];
        float g1 = p3[nb * 3 + 1] + r0 * w3[1] + r1 * w3[4] + r2 * w3[7];
        float g2 = p3[nb * 3 + 2] + r0 * w3[2] + r1 * w3[5] + r2 * w3[8];
        a0 = fmaf(wgt, g0, a0); a1 = fmaf(wgt, g1, a1); a2 = fmaf(wgt, g2, a2);
    }
    if (lane == 0) {
        refined[m * 3]     = sp0 + a0 + bco[0];
        refined[m * 3 + 1] = sp1 + a1 + bco[1];
        refined[m * 3 + 2] = sp2 + a2 + bco[2];
    }
}

// ---------------- launch ----------------
extern "C" void kernel_launch(void* const* d_in, const int* in_sizes, int n_in,
                              void* d_out, int out_size, void* d_ws, size_t ws_size,
                              hipStream_t stream) {
    const float* pts   = (const float*)d_in[0];
    const int*   ei    = (const int*)d_in[1];
    const int*   smp   = (const int*)d_in[2];
    const int*   nbr   = (const int*)d_in[3];
    const float* W1    = (const float*)d_in[4];
    const float* b1    = (const float*)d_in[5];
    const float* g1    = (const float*)d_in[6];
    const float* beta1 = (const float*)d_in[7];
    const float* W2    = (const float*)d_in[8];
    const float* b2    = (const float*)d_in[9];
    const float* g2    = (const float*)d_in[10];
    const float* beta2 = (const float*)d_in[11];
    const float* Wc    = (const float*)d_in[12];
    const float* bc    = (const float*)d_in[13];
    const float* Wn    = (const float*)d_in[14];
    const float* bn_b  = (const float*)d_in[15];
    const float* Wq    = (const float*)d_in[16];
    const float* bq    = (const float*)d_in[17];
    const float* Wk    = (const float*)d_in[18];
    const float* bk    = (const float*)d_in[19];
    const float* Wcat  = (const float*)d_in[20];
    const float* bcat  = (const float*)d_in[21];
    const float* Wout  = (const float*)d_in[22];
    const float* bout  = (const float*)d_in[23];
    (void)in_sizes; (void)n_in; (void)out_size; (void)ws_size;

    float* w = (float*)d_ws;
    size_t o = 0;
    float* y1     = w + o; o += 6400000;
    float* y2     = w + o; o += 6400000;
    float* aggX   = w + o; o += 3200000;
    float* qkb    = w + o; o += 3200000;
    float* psum   = w + o; o += 262144;
    float* psq    = w + o; o += 262144;
    float* tp1    = w + o; o += 256;
    float* tp2    = w + o; o += 256;
    float* Wqk    = w + o; o += 16384;
    float* biasQK = w + o; o += 128;
    float* WcWn   = w + o; o += 32768;
    float* Wco128 = w + o; o += 384;
    float* w3     = w + o; o += 16;
    float* bco    = w + o; o += 16;
    float* p3     = w + o; o += 75008;
    float* sp     = w + o; o += 75008;
    float* hasE   = w + o; o += 25008;
    int* ip    = (int*)(w + o);
    int* inv   = ip;            ip += NPTS;
    int* cnt   = ip;            ip += MS;
    int* cursor= ip;            ip += MS;
    int* offs  = ip;            ip += MS + 4;
    int* elist = ip;

    float* refined = (float*)d_out;
    float* sx      = (float*)d_out + 75000;

    prep_kernel<<<489, 256, 0, stream>>>(Wq, bq, Wk, bk, Wcat, bcat, Wout, bout, Wc, Wn,
                                         Wqk, biasQK, WcWn, Wco128, w3, bco,
                                         inv, cnt, cursor);
    lin1_kernel<<<1098, 256, 0, stream>>>(pts, W1, b1, y1, psum, psq, smp, inv);
    bn_fin_par<<<128, 256, 0, stream>>>(psum, psq, 2000, g1, beta1, tp1);
    gemm_bn<6, true, true, true><<<1042 + 3125, 256, 0, stream>>>(
        y1, NPTS, 1042, W2, b2, tp1, y2, psum, psq, ei, inv, cnt);
    bn_fin_par<<<128, 256, 0, stream>>>(psum, psq, 1042, g2, beta2, tp2);
    scan_kernel<<<1, 1024, 0, stream>>>(cnt, offs);
    scatter_kernel<<<3125, 256, 0, stream>>>(ei, inv, offs, cursor, elist);
    agg_kernel<<<6250, 256, 0, stream>>>(smp, inv, offs, elist, y2, tp2, aggX, hasE);
    gemm_sx<<<1042, 256, 0, stream>>>(y2, aggX, hasE, smp, inv, WcWn, bc, bn_b, tp2, sx);
    p3_kernel<<<6250, 256, 0, stream>>>(sx, Wco128, smp, pts, p3, sp);
    gemm_bn<3, false, false, false><<<1042, 256, 0, stream>>>(
        sx, MS, 1042, Wqk, biasQK, nullptr, qkb, nullptr, nullptr, nullptr, nullptr, nullptr);
    attn_kernel<<<6250, 256, 0, stream>>>(qkb, nbr, p3, sp, w3, bco, refined);
}

// Round 9
// 321.622 us; speedup vs baseline: 2.8606x; 1.0156x over previous
//
#include <hip/hip_runtime.h>
#include <climits>

#define NPTS 50000
#define NE   800000
#define MS   25000
#define KN   15
#define HD   128

// ---------------- helpers ----------------
__device__ __forceinline__ float wave_sum(float v) {
#pragma unroll
    for (int o = 32; o > 0; o >>= 1) v += __shfl_xor(v, o, 64);
    return v;
}

// ---------------- K0: prep (weight packs + folds) + init of inv/cnt/cursor ----------------
__launch_bounds__(256)
__global__ void prep_kernel(const float* __restrict__ Wq, const float* __restrict__ bq,
                            const float* __restrict__ Wk, const float* __restrict__ bk,
                            const float* __restrict__ Wcat, const float* __restrict__ bcat,
                            const float* __restrict__ Wout, const float* __restrict__ bout,
                            const float* __restrict__ Wc, const float* __restrict__ Wn,
                            float* __restrict__ Wqk, float* __restrict__ biasQK,
                            float* __restrict__ WcWn,
                            float* __restrict__ Wco128, float* __restrict__ w3, float* __restrict__ bco,
                            int* __restrict__ inv, int* __restrict__ cnt, int* __restrict__ cursor) {
    int b = blockIdx.x, tid = threadIdx.x;
    if (b < 64) {
        int i = b * 256 + tid;
        int k = i >> 7, c = i & 127;
        Wqk[i] = (c < 64) ? Wq[k * 64 + c] : Wk[k * 64 + (c - 64)];
    } else if (b < 192) {
        int i = (b - 64) * 256 + tid;
        int k = i >> 7, c = i & 127;
        WcWn[i] = (k < 128) ? Wc[k * 128 + c] : Wn[(k - 128) * 128 + c];
    } else if (b == 192) {
        if (tid < 128) biasQK[tid] = (tid < 64) ? bq[tid] : bk[tid - 64];
    } else if (b < 293) {               // fold: one output per wave
        int wid = tid >> 6, lane = tid & 63;
        int out = (b - 193) * 4 + wid;  // 0..399
        if (out < 396) {
            int r = out / 3, j = out - r * 3;   // r==131 -> bco row
            const float* src = (r < 131) ? &Wcat[r * 131] : bcat;
            float s = 0.f;
            s = fmaf(src[lane], Wout[lane * 3 + j], s);
            s = fmaf(src[lane + 64], Wout[(lane + 64) * 3 + j], s);
            if (lane < 3) s = fmaf(src[lane + 128], Wout[(lane + 128) * 3 + j], s);
            s = wave_sum(s);
            if (lane == 0) {
                if (r < 128) Wco128[r * 3 + j] = s;
                else if (r < 131) w3[(r - 128) * 3 + j] = s;
                else bco[j] = s + bout[j];
            }
        }
    } else {                            // init
        int i = (b - 293) * 256 + tid;
        if (i < NPTS) inv[i] = INT_MAX;
        if (i < MS) { cnt[i] = 0; cursor[i] = 0; }
    }
}

// ---------------- K1: y1 = points@W1 + b1 with stats partials; tail blocks do invset ----------------
__launch_bounds__(256)
__global__ void lin1_kernel(const float* __restrict__ pts, const float* __restrict__ W1,
                            const float* __restrict__ b1, float* __restrict__ y1,
                            float* __restrict__ psum, float* __restrict__ psq,
                            const int* __restrict__ smp, int* __restrict__ inv) {
    if (blockIdx.x >= 1000) {           // invset tail: representative map
        int m = (blockIdx.x - 1000) * 256 + threadIdx.x;
        if (m < MS) atomicMin(&inv[smp[m]], m);
        return;
    }
    int c = threadIdx.x & 127;
    int half = threadIdx.x >> 7;
    int part = blockIdx.x * 2 + half;   // 0..1999
    float w0 = W1[c], w1 = W1[128 + c], w2 = W1[256 + c], bb = b1[c];
    float s = 0.f, s2 = 0.f;
    int r0 = part * 25, r1 = r0 + 25; if (r1 > NPTS) r1 = NPTS;
    for (int r = r0; r < r1; ++r) {
        float p0 = pts[r * 3], p1 = pts[r * 3 + 1], p2 = pts[r * 3 + 2];
        float y = fmaf(p0, w0, fmaf(p1, w1, fmaf(p2, w2, bb)));
        y1[r * HD + c] = y;
        s += y; s2 = fmaf(y, y, s2);
    }
    psum[part * 128 + c] = s;
    psq[part * 128 + c] = s2;
}

// ---------------- BN finalize (parallel): one block per column ----------------
__launch_bounds__(256)
__global__ void bn_fin_par(const float* __restrict__ psum, const float* __restrict__ psq, int nb,
                           const float* __restrict__ g, const float* __restrict__ beta,
                           float* __restrict__ tp) {
    int c = blockIdx.x;
    int t = threadIdx.x;
    float S = 0.f, S2 = 0.f;
    for (int b = t; b < nb; b += 256) {
        S += psum[b * 128 + c];
        S2 += psq[b * 128 + c];
    }
    S = wave_sum(S); S2 = wave_sum(S2);
    __shared__ float sA[4], sB[4];
    int wid = t >> 6, lane = t & 63;
    if (lane == 0) { sA[wid] = S; sB[wid] = S2; }
    __syncthreads();
    if (t == 0) {
        float Sa = sA[0] + sA[1] + sA[2] + sA[3];
        float Sb = sB[0] + sB[1] + sB[2] + sB[3];
        const float invN = 1.f / (float)NPTS;
        float mean = Sa * invN;
        float var = Sb * invN - mean * mean;
        float a = g[c] * rsqrtf(var + 1e-5f);
        tp[c] = a;
        tp[128 + c] = beta[c] - mean * a;
    }
}

// ---------------- GEMM [nrows,128]@[128,128], tile (8R)x128, conflict-free mapping ----------------
template <int R, bool TRANS, bool STATS, bool COUNT>
__launch_bounds__(256)
__global__ void gemm_bn(const float* __restrict__ A, int nrows, int gemmBlocks,
                        const float* __restrict__ W, const float* __restrict__ bias,
                        const float* __restrict__ tp,
                        float* __restrict__ Out,
                        float* __restrict__ psum, float* __restrict__ psq,
                        const int* __restrict__ ei, const int* __restrict__ inv,
                        int* __restrict__ cnt) {
    if (COUNT && (int)blockIdx.x >= gemmBlocks) {
        int e = ((int)blockIdx.x - gemmBlocks) * 256 + threadIdx.x;
        if (e < NE) {
            int mr = inv[ei[NE + e]];
            if (mr < MS) atomicAdd(&cnt[mr], 1);
        }
        return;
    }
    const int ROWS = 8 * R;
    __shared__ float As[8 * R][68];
    __shared__ float Ws[64][128];    // 32 KB
    int tid = threadIdx.x;
    int r0 = blockIdx.x * ROWS;
    int tc = tid & 31, tr = tid >> 5;
    int trR = tr * R, c0 = tc << 2;
    float acc[R][4] = {};

    for (int k0 = 0; k0 < 128; k0 += 64) {
        if (k0) __syncthreads();
        for (int i = tid; i < ROWS * 16; i += 256) {
            int r = i >> 4, c4 = (i & 15) << 2;
            int gr = r0 + r;
            float4 v = make_float4(0.f, 0.f, 0.f, 0.f);
            if (gr < nrows) {
                v = *reinterpret_cast<const float4*>(&A[gr * HD + k0 + c4]);
                if (TRANS) {
                    int gc = k0 + c4;
                    v.x = fmaxf(fmaf(tp[gc],     v.x, tp[128 + gc]),     0.f);
                    v.y = fmaxf(fmaf(tp[gc + 1], v.y, tp[128 + gc + 1]), 0.f);
                    v.z = fmaxf(fmaf(tp[gc + 2], v.z, tp[128 + gc + 2]), 0.f);
                    v.w = fmaxf(fmaf(tp[gc + 3], v.w, tp[128 + gc + 3]), 0.f);
                }
            }
            *reinterpret_cast<float4*>(&As[r][c4]) = v;
        }
        for (int i = tid; i < 64 * 32; i += 256) {
            int k = i >> 5, c4 = (i & 31) << 2;
            *reinterpret_cast<float4*>(&Ws[k][c4]) =
                *reinterpret_cast<const float4*>(&W[(k0 + k) * 128 + c4]);
        }
        __syncthreads();
#pragma unroll 2
        for (int k = 0; k < 64; k += 4) {
            float4 a[R];
#pragma unroll
            for (int i = 0; i < R; ++i)
                a[i] = *reinterpret_cast<const float4*>(&As[trR + i][k]);
#pragma unroll
            for (int kk = 0; kk < 4; ++kk) {
                const float4 wv = *reinterpret_cast<const float4*>(&Ws[k + kk][c0]);
#pragma unroll
                for (int i = 0; i < R; ++i) {
                    float av = kk == 0 ? a[i].x : kk == 1 ? a[i].y : kk == 2 ? a[i].z : a[i].w;
                    acc[i][0] = fmaf(av, wv.x, acc[i][0]);
                    acc[i][1] = fmaf(av, wv.y, acc[i][1]);
                    acc[i][2] = fmaf(av, wv.z, acc[i][2]);
                    acc[i][3] = fmaf(av, wv.w, acc[i][3]);
                }
            }
        }
    }

    const float4 bv = *reinterpret_cast<const float4*>(&bias[c0]);
    float cs[4] = {}, cq[4] = {};
#pragma unroll
    for (int i = 0; i < R; ++i) {
        int gr = r0 + trR + i;
        float o0 = acc[i][0] + bv.x, o1 = acc[i][1] + bv.y;
        float o2 = acc[i][2] + bv.z, o3 = acc[i][3] + bv.w;
        if (gr < nrows) {
            *reinterpret_cast<float4*>(&Out[gr * HD + c0]) = make_float4(o0, o1, o2, o3);
            if (STATS) {
                cs[0] += o0; cs[1] += o1; cs[2] += o2; cs[3] += o3;
                cq[0] = fmaf(o0, o0, cq[0]); cq[1] = fmaf(o1, o1, cq[1]);
                cq[2] = fmaf(o2, o2, cq[2]); cq[3] = fmaf(o3, o3, cq[3]);
            }
        }
    }
    if (STATS) {
        float* red = &As[0][0];     // 4 KB scratch inside As
        __syncthreads();
        *reinterpret_cast<float4*>(&red[tr * 128 + c0]) = make_float4(cs[0], cs[1], cs[2], cs[3]);
        __syncthreads();
        if (tid < 128) {
            float s = 0.f;
#pragma unroll
            for (int t = 0; t < 8; ++t) s += red[t * 128 + tid];
            psum[blockIdx.x * 128 + tid] = s;
        }
        __syncthreads();
        *reinterpret_cast<float4*>(&red[tr * 128 + c0]) = make_float4(cq[0], cq[1], cq[2], cq[3]);
        __syncthreads();
        if (tid < 128) {
            float s = 0.f;
#pragma unroll
            for (int t = 0; t < 8; ++t) s += red[t * 128 + tid];
            psq[blockIdx.x * 128 + tid] = s;
        }
    }
}

// ---------------- scan over cnt[MS] -> offs ----------------
__launch_bounds__(1024)
__global__ void scan_kernel(const int* __restrict__ cnt, int* __restrict__ offs) {
    const int C = 25;
    __shared__ int buf[1024];
    int tid = threadIdx.x;
    int loc[C];
    int run = 0;
    int base = tid * C;
#pragma unroll
    for (int i = 0; i < C; ++i) {
        int idx = base + i;
        int v = (idx < MS) ? cnt[idx] : 0;
        loc[i] = run; run += v;
    }
    buf[tid] = run;
    __syncthreads();
    for (int off = 1; off < 1024; off <<= 1) {
        int t = (tid >= off) ? buf[tid - off] : 0;
        __syncthreads();
        buf[tid] += t;
        __syncthreads();
    }
    int excl = buf[tid] - run;
#pragma unroll
    for (int i = 0; i < C; ++i) {
        int idx = base + i;
        if (idx < MS) offs[idx] = excl + loc[i];
    }
    if (tid == 1023) offs[MS] = buf[tid];
}

__launch_bounds__(256)
__global__ void scatter_kernel(const int* __restrict__ ei, const int* __restrict__ inv,
                               const int* __restrict__ offs, int* __restrict__ cursor,
                               int* __restrict__ elist) {
    int e = blockIdx.x * 256 + threadIdx.x;
    if (e < NE) {
        int mr = inv[ei[NE + e]];
        if (mr < MS) {
            int pos = atomicAdd(&cursor[mr], 1);
            elist[offs[mr] + pos] = ei[e];
        }
    }
}

// ---------------- K7: rep-only gather-mean; 2 rows per instr (half-wave split), float4 ----------------
__launch_bounds__(256)
__global__ void agg_kernel(const int* __restrict__ smp, const int* __restrict__ inv,
                           const int* __restrict__ offs, const int* __restrict__ elist,
                           const float* __restrict__ y2, const float* __restrict__ tp2,
                           float* __restrict__ aggX, float* __restrict__ hasE) {
    int tid = threadIdx.x, wid = tid >> 6, lane = tid & 63;
    int m = blockIdx.x * 4 + wid;
    if (m >= MS) return;
    int d = smp[m];
    if (inv[d] != m) return;            // representatives only
    int half = lane >> 5, c0 = (lane & 31) << 2;
    const float4 ta = *reinterpret_cast<const float4*>(&tp2[c0]);
    const float4 tb = *reinterpret_cast<const float4*>(&tp2[128 + c0]);
    int e0 = offs[m], e1 = offs[m + 1];
    float4 s0 = {0,0,0,0}, s1 = {0,0,0,0}, s2 = {0,0,0,0}, s3 = {0,0,0,0};
    int e = e0;
    for (; e + 7 < e1; e += 8) {        // 4 loads x 2 rows each in flight
        float4 v[4];
#pragma unroll
        for (int u = 0; u < 4; ++u)
            v[u] = *reinterpret_cast<const float4*>(&y2[elist[e + 2 * u + half] * HD + c0]);
        s0.x += fmaxf(fmaf(ta.x, v[0].x, tb.x), 0.f); s0.y += fmaxf(fmaf(ta.y, v[0].y, tb.y), 0.f);
        s0.z += fmaxf(fmaf(ta.z, v[0].z, tb.z), 0.f); s0.w += fmaxf(fmaf(ta.w, v[0].w, tb.w), 0.f);
        s1.x += fmaxf(fmaf(ta.x, v[1].x, tb.x), 0.f); s1.y += fmaxf(fmaf(ta.y, v[1].y, tb.y), 0.f);
        s1.z += fmaxf(fmaf(ta.z, v[1].z, tb.z), 0.f); s1.w += fmaxf(fmaf(ta.w, v[1].w, tb.w), 0.f);
        s2.x += fmaxf(fmaf(ta.x, v[2].x, tb.x), 0.f); s2.y += fmaxf(fmaf(ta.y, v[2].y, tb.y), 0.f);
        s2.z += fmaxf(fmaf(ta.z, v[2].z, tb.z), 0.f); s2.w += fmaxf(fmaf(ta.w, v[2].w, tb.w), 0.f);
        s3.x += fmaxf(fmaf(ta.x, v[3].x, tb.x), 0.f); s3.y += fmaxf(fmaf(ta.y, v[3].y, tb.y), 0.f);
        s3.z += fmaxf(fmaf(ta.z, v[3].z, tb.z), 0.f); s3.w += fmaxf(fmaf(ta.w, v[3].w, tb.w), 0.f);
    }
    for (; e + 1 < e1; e += 2) {
        const float4 v = *reinterpret_cast<const float4*>(&y2[elist[e + half] * HD + c0]);
        s0.x += fmaxf(fmaf(ta.x, v.x, tb.x), 0.f); s0.y += fmaxf(fmaf(ta.y, v.y, tb.y), 0.f);
        s0.z += fmaxf(fmaf(ta.z, v.z, tb.z), 0.f); s0.w += fmaxf(fmaf(ta.w, v.w, tb.w), 0.f);
    }
    if (e < e1 && half == 0) {          // odd tail: half0 only
        const float4 v = *reinterpret_cast<const float4*>(&y2[elist[e] * HD + c0]);
        s1.x += fmaxf(fmaf(ta.x, v.x, tb.x), 0.f); s1.y += fmaxf(fmaf(ta.y, v.y, tb.y), 0.f);
        s1.z += fmaxf(fmaf(ta.z, v.z, tb.z), 0.f); s1.w += fmaxf(fmaf(ta.w, v.w, tb.w), 0.f);
    }
    float tx = (s0.x + s1.x) + (s2.x + s3.x);
    float ty = (s0.y + s1.y) + (s2.y + s3.y);
    float tz = (s0.z + s1.z) + (s2.z + s3.z);
    float tw = (s0.w + s1.w) + (s2.w + s3.w);
    tx += __shfl_xor(tx, 32, 64); ty += __shfl_xor(ty, 32, 64);
    tz += __shfl_xor(tz, 32, 64); tw += __shfl_xor(tw, 32, 64);
    float rs = 1.f / fmaxf((float)(e1 - e0), 1.f);
    if (half == 0)
        *reinterpret_cast<float4*>(&aggX[m * HD + c0]) = make_float4(tx * rs, ty * rs, tz * rs, tw * rs);
    if (lane == 0) hasE[m] = (e1 > e0) ? 1.f : 0.f;
}

// ---------------- K8 (FUSED): sx GEMM + qk GEMM + p3/sp, 24 rows/block ----------------
// phase 1: sx = relu([bnrelu(y2[smp]) | aggX] @ [Wc;Wn] + bc + f*bn_b)  (K=256)
// phase 2: qk = sx @ Wqk + biasQK                                        (K=128, from LDS sxs)
// phase 3: p3 = sx @ Wco128 ; sp = pts[smp]
__launch_bounds__(256)
__global__ void gemm_sx_fused(const float* __restrict__ y2, const float* __restrict__ aggX,
                              const float* __restrict__ hasE,
                              const int* __restrict__ smp, const int* __restrict__ inv,
                              const float* __restrict__ WcWn,
                              const float* __restrict__ bc, const float* __restrict__ bn_b,
                              const float* __restrict__ tp2,
                              const float* __restrict__ Wqk, const float* __restrict__ biasQK,
                              const float* __restrict__ Wco128, const float* __restrict__ pts,
                              float* __restrict__ sx, float* __restrict__ qkb,
                              float* __restrict__ p3, float* __restrict__ sp) {
    const int R = 3;
    __shared__ float As[24][68];     // 6.5 KB
    __shared__ float Ws[64][128];    // 32 KB (WcWn chunks, then Wqk chunks)
    __shared__ float sxs[24][132];   // 12.7 KB (sx rows for phases 2/3)
    int tid = threadIdx.x;
    int r0 = blockIdx.x * 24;
    int tc = tid & 31, tr = tid >> 5;
    int trR = tr * R, c0 = tc << 2;
    float acc[R][4] = {};

    // ---- phase 1: K=256 GEMM ----
    for (int kk = 0; kk < 4; ++kk) {
        if (kk) __syncthreads();
        for (int i = tid; i < 24 * 16; i += 256) {
            int r = i >> 4, c4 = (i & 15) << 2;
            int gr = r0 + r;
            float4 v = make_float4(0.f, 0.f, 0.f, 0.f);
            if (gr < MS) {
                int d = smp[gr];
                if (kk < 2) {
                    int gc = (kk << 6) + c4;
                    v = *reinterpret_cast<const float4*>(&y2[d * HD + gc]);
                    v.x = fmaxf(fmaf(tp2[gc],     v.x, tp2[128 + gc]),     0.f);
                    v.y = fmaxf(fmaf(tp2[gc + 1], v.y, tp2[128 + gc + 1]), 0.f);
                    v.z = fmaxf(fmaf(tp2[gc + 2], v.z, tp2[128 + gc + 2]), 0.f);
                    v.w = fmaxf(fmaf(tp2[gc + 3], v.w, tp2[128 + gc + 3]), 0.f);
                } else {
                    v = *reinterpret_cast<const float4*>(&aggX[inv[d] * HD + ((kk - 2) << 6) + c4]);
                }
            }
            *reinterpret_cast<float4*>(&As[r][c4]) = v;
        }
        for (int i = tid; i < 64 * 32; i += 256) {
            int k = i >> 5, c4 = (i & 31) << 2;
            *reinterpret_cast<float4*>(&Ws[k][c4]) =
                *reinterpret_cast<const float4*>(&WcWn[((kk << 6) + k) * 128 + c4]);
        }
        __syncthreads();
#pragma unroll 2
        for (int k = 0; k < 64; k += 4) {
            float4 a[R];
#pragma unroll
            for (int i = 0; i < R; ++i)
                a[i] = *reinterpret_cast<const float4*>(&As[trR + i][k]);
#pragma unroll
            for (int kq = 0; kq < 4; ++kq) {
                const float4 wv = *reinterpret_cast<const float4*>(&Ws[k + kq][c0]);
#pragma unroll
                for (int i = 0; i < R; ++i) {
                    float av = kq == 0 ? a[i].x : kq == 1 ? a[i].y : kq == 2 ? a[i].z : a[i].w;
                    acc[i][0] = fmaf(av, wv.x, acc[i][0]);
                    acc[i][1] = fmaf(av, wv.y, acc[i][1]);
                    acc[i][2] = fmaf(av, wv.z, acc[i][2]);
                    acc[i][3] = fmaf(av, wv.w, acc[i][3]);
                }
            }
        }
    }

    // ---- epilogue 1: sx -> global + LDS ----
    {
        const float4 bcv = *reinterpret_cast<const float4*>(&bc[c0]);
        const float4 bnv = *reinterpret_cast<const float4*>(&bn_b[c0]);
#pragma unroll
        for (int i = 0; i < R; ++i) {
            int gr = r0 + trR + i;
            float4 ov = make_float4(0.f, 0.f, 0.f, 0.f);
            if (gr < MS) {
                float f = hasE[inv[smp[gr]]];
                ov.x = fmaxf(acc[i][0] + bcv.x + f * bnv.x, 0.f);
                ov.y = fmaxf(acc[i][1] + bcv.y + f * bnv.y, 0.f);
                ov.z = fmaxf(acc[i][2] + bcv.z + f * bnv.z, 0.f);
                ov.w = fmaxf(acc[i][3] + bcv.w + f * bnv.w, 0.f);
                *reinterpret_cast<float4*>(&sx[gr * HD + c0]) = ov;
            }
            *reinterpret_cast<float4*>(&sxs[trR + i][c0]) = ov;
        }
    }
    __syncthreads();

    // ---- phase 2: qk = sxs @ Wqk + biasQK (K=128, 2 chunks) ----
    float qacc[R][4] = {};
    for (int kk = 0; kk < 2; ++kk) {
        if (kk) __syncthreads();
        for (int i = tid; i < 64 * 32; i += 256) {
            int k = i >> 5, c4 = (i & 31) << 2;
            *reinterpret_cast<float4*>(&Ws[k][c4]) =
                *reinterpret_cast<const float4*>(&Wqk[((kk << 6) + k) * 128 + c4]);
        }
        __syncthreads();
        int kb = kk << 6;
#pragma unroll 2
        for (int k = 0; k < 64; k += 4) {
            float4 a[R];
#pragma unroll
            for (int i = 0; i < R; ++i)
                a[i] = *reinterpret_cast<const float4*>(&sxs[trR + i][kb + k]);
#pragma unroll
            for (int kq = 0; kq < 4; ++kq) {
                const float4 wv = *reinterpret_cast<const float4*>(&Ws[k + kq][c0]);
#pragma unroll
                for (int i = 0; i < R; ++i) {
                    float av = kq == 0 ? a[i].x : kq == 1 ? a[i].y : kq == 2 ? a[i].z : a[i].w;
                    qacc[i][0] = fmaf(av, wv.x, qacc[i][0]);
                    qacc[i][1] = fmaf(av, wv.y, qacc[i][1]);
                    qacc[i][2] = fmaf(av, wv.z, qacc[i][2]);
                    qacc[i][3] = fmaf(av, wv.w, qacc[i][3]);
                }
            }
        }
    }
    {
        const float4 bqv = *reinterpret_cast<const float4*>(&biasQK[c0]);
#pragma unroll
        for (int i = 0; i < R; ++i) {
            int gr = r0 + trR + i;
            if (gr < MS) {
                *reinterpret_cast<float4*>(&qkb[gr * HD + c0]) = make_float4(
                    qacc[i][0] + bqv.x, qacc[i][1] + bqv.y,
                    qacc[i][2] + bqv.z, qacc[i][3] + bqv.w);
            }
        }
    }

    // ---- phase 3: p3 = sxs @ Wco128, sp = pts[smp] (per-wave, 6 rows each) ----
    {
        int wid = tid >> 6, lane = tid & 63;
        int cc = lane << 1;
        float wa0 = Wco128[cc * 3],     wa1 = Wco128[cc * 3 + 1],     wa2 = Wco128[cc * 3 + 2];
        float wb0 = Wco128[(cc+1) * 3], wb1 = Wco128[(cc+1) * 3 + 1], wb2 = Wco128[(cc+1) * 3 + 2];
#pragma unroll
        for (int rr = wid * 6; rr < wid * 6 + 6; ++rr) {
            int m = r0 + rr;
            if (m >= MS) break;
            float vx = sxs[rr][cc], vy = sxs[rr][cc + 1];
            float q0 = fmaf(vx, wa0, vy * wb0);
            float q1 = fmaf(vx, wa1, vy * wb1);
            float q2 = fmaf(vx, wa2, vy * wb2);
            q0 = wave_sum(q0); q1 = wave_sum(q1); q2 = wave_sum(q2);
            if (lane == 0) { p3[m * 3] = q0; p3[m * 3 + 1] = q1; p3[m * 3 + 2] = q2; }
            if (lane < 3) sp[m * 3 + lane] = pts[smp[m] * 3 + lane];
        }
    }
}

// ---------------- K9: attention + folded output tail ----------------
__launch_bounds__(256)
__global__ void attn_kernel(const float* __restrict__ qk, const int* __restrict__ nbr,
                            const float* __restrict__ p3, const float* __restrict__ sp,
                            const float* __restrict__ w3, const float* __restrict__ bco,
                            float* __restrict__ refined) {
    int wid = threadIdx.x >> 6, lane = threadIdx.x & 63;
    int m = blockIdx.x * 4 + wid;
    if (m >= MS) return;
    float ql = qk[m * HD + lane];
    int nbv[KN];
    float s[KN];
#pragma unroll
    for (int j = 0; j < KN; ++j) nbv[j] = nbr[m * KN + j];
#pragma unroll
    for (int j = 0; j < KN; ++j) {
        float t = ql * qk[nbv[j] * HD + 64 + lane];
        t = wave_sum(t);
        s[j] = (nbv[j] != 0) ? t * (1.f / 8.000001f) : 0.f;
    }
    float mx = s[0];
#pragma unroll
    for (int j = 1; j < KN; ++j) mx = fmaxf(mx, s[j]);
    float den = 0.f;
#pragma unroll
    for (int j = 0; j < KN; ++j) { s[j] = __expf(s[j] - mx); den += s[j]; }
    float invd = 1.f / den;
    float sp0 = sp[m * 3], sp1 = sp[m * 3 + 1], sp2 = sp[m * 3 + 2];
    float a0 = 0.f, a1 = 0.f, a2 = 0.f;
#pragma unroll
    for (int j = 0; j < KN; ++j) {
        int nb = nbv[j];
        float wgt = s[j] * invd;
        float r0 = sp[nb * 3] - sp0, r1 = sp[nb * 3 + 1] - sp1, r2 = sp[nb * 3 + 2] - sp2;
        float g0 = p3[nb * 3]     + r0 * w3[0] + r1 * w3[3] + r2 * w3[6];
        float g1 = p3[nb * 3 + 1] + r0 * w3[1] + r1 * w3[4] + r2 * w3[7];
        float g2 = p3[nb * 3 + 2] + r0 * w3[2] + r1 * w3[5] + r2 * w3[8];
        a0 = fmaf(wgt, g0, a0); a1 = fmaf(wgt, g1, a1); a2 = fmaf(wgt, g2, a2);
    }
    if (lane == 0) {
        refined[m * 3]     = sp0 + a0 + bco[0];
        refined[m * 3 + 1] = sp1 + a1 + bco[1];
        refined[m * 3 + 2] = sp2 + a2 + bco[2];
    }
}

// ---------------- launch ----------------
extern "C" void kernel_launch(void* const* d_in, const int* in_sizes, int n_in,
                              void* d_out, int out_size, void* d_ws, size_t ws_size,
                              hipStream_t stream) {
    const float* pts   = (const float*)d_in[0];
    const int*   ei    = (const int*)d_in[1];
    const int*   smp   = (const int*)d_in[2];
    const int*   nbr   = (const int*)d_in[3];
    const float* W1    = (const float*)d_in[4];
    const float* b1    = (const float*)d_in[5];
    const float* g1    = (const float*)d_in[6];
    const float* beta1 = (const float*)d_in[7];
    const float* W2    = (const float*)d_in[8];
    const float* b2    = (const float*)d_in[9];
    const float* g2    = (const float*)d_in[10];
    const float* beta2 = (const float*)d_in[11];
    const float* Wc    = (const float*)d_in[12];
    const float* bc    = (const float*)d_in[13];
    const float* Wn    = (const float*)d_in[14];
    const float* bn_b  = (const float*)d_in[15];
    const float* Wq    = (const float*)d_in[16];
    const float* bq    = (const float*)d_in[17];
    const float* Wk    = (const float*)d_in[18];
    const float* bk    = (const float*)d_in[19];
    const float* Wcat  = (const float*)d_in[20];
    const float* bcat  = (const float*)d_in[21];
    const float* Wout  = (const float*)d_in[22];
    const float* bout  = (const float*)d_in[23];
    (void)in_sizes; (void)n_in; (void)out_size; (void)ws_size;

    float* w = (float*)d_ws;
    size_t o = 0;
    float* y1     = w + o; o += 6400000;
    float* y2     = w + o; o += 6400000;
    float* aggX   = w + o; o += 3200000;
    float* qkb    = w + o; o += 3200000;
    float* psum   = w + o; o += 262144;
    float* psq    = w + o; o += 262144;
    float* tp1    = w + o; o += 256;
    float* tp2    = w + o; o += 256;
    float* Wqk    = w + o; o += 16384;
    float* biasQK = w + o; o += 128;
    float* WcWn   = w + o; o += 32768;
    float* Wco128 = w + o; o += 384;
    float* w3     = w + o; o += 16;
    float* bco    = w + o; o += 16;
    float* p3     = w + o; o += 75008;
    float* sp     = w + o; o += 75008;
    float* hasE   = w + o; o += 25008;
    int* ip    = (int*)(w + o);
    int* inv   = ip;            ip += NPTS;
    int* cnt   = ip;            ip += MS;
    int* cursor= ip;            ip += MS;
    int* offs  = ip;            ip += MS + 4;
    int* elist = ip;

    float* refined = (float*)d_out;
    float* sx      = (float*)d_out + 75000;

    prep_kernel<<<489, 256, 0, stream>>>(Wq, bq, Wk, bk, Wcat, bcat, Wout, bout, Wc, Wn,
                                         Wqk, biasQK, WcWn, Wco128, w3, bco,
                                         inv, cnt, cursor);
    lin1_kernel<<<1098, 256, 0, stream>>>(pts, W1, b1, y1, psum, psq, smp, inv);
    bn_fin_par<<<128, 256, 0, stream>>>(psum, psq, 2000, g1, beta1, tp1);
    gemm_bn<6, true, true, true><<<1042 + 3125, 256, 0, stream>>>(
        y1, NPTS, 1042, W2, b2, tp1, y2, psum, psq, ei, inv, cnt);
    bn_fin_par<<<128, 256, 0, stream>>>(psum, psq, 1042, g2, beta2, tp2);
    scan_kernel<<<1, 1024, 0, stream>>>(cnt, offs);
    scatter_kernel<<<3125, 256, 0, stream>>>(ei, inv, offs, cursor, elist);
    agg_kernel<<<6250, 256, 0, stream>>>(smp, inv, offs, elist, y2, tp2, aggX, hasE);
    gemm_sx_fused<<<1042, 256, 0, stream>>>(y2, aggX, hasE, smp, inv, WcWn, bc, bn_b, tp2,
                                            Wqk, biasQK, Wco128, pts, sx, qkb, p3, sp);
    attn_kernel<<<6250, 256, 0, stream>>>(qkb, nbr, p3, sp, w3, bco, refined);
}